// Round 2
// baseline (333.820 us; speedup 1.0000x reference)
//
#include <hip/hip_runtime.h>
#include <cmath>

// ---------------------------------------------------------------------------
// Problem constants (B=8, H=W=64, C=192, 3 dilation branches of d=64, heads=64)
// ---------------------------------------------------------------------------
#define kB    8
#define kH    64
#define kW    64
#define kHW   4096          // H*W
#define kC    192
#define kD    64            // channels per dilation branch == head_dim
#define kM    (kB * kHW)    // 32768 total pixels
#define kNQKV 576           // 3*C

typedef unsigned short ushort_t;
typedef __attribute__((ext_vector_type(8))) short  s8v;   // 8 bf16 (4 VGPRs)
typedef __attribute__((ext_vector_type(4))) float  f4v;   // MFMA C/D frag

__device__ inline unsigned short bf16r(float f) {   // round-to-nearest-even
    union { float f; unsigned u; } v; v.f = f;
    unsigned u = v.u + 0x7FFFu + ((v.u >> 16) & 1u);
    return (unsigned short)(u >> 16);
}
__device__ inline float bfu(short s) {              // bf16 -> fp32
    union { unsigned u; float f; } v;
    v.u = ((unsigned)(unsigned short)s) << 16;
    return v.f;
}

// ---------------------------------------------------------------------------
// fp32 -> bf16 pairwise converter
// ---------------------------------------------------------------------------
__global__ void cvt_bf16(const float* __restrict__ src, unsigned* __restrict__ dst, int n2) {
    int i = blockIdx.x * 256 + threadIdx.x;
    if (i >= n2) return;
    float2 f = ((const float2*)src)[i];
    dst[i] = (unsigned)bf16r(f.x) | ((unsigned)bf16r(f.y) << 16);
}

// ---------------------------------------------------------------------------
// deform weights: dw (o,c,kk) fp32 -> dwtb[kk][o][c] bf16
// ---------------------------------------------------------------------------
__global__ void dw_tb(const float* __restrict__ dw, ushort_t* __restrict__ dwtb) {
    int l = blockIdx.x * 256 + threadIdx.x;   // 64*64*9 = 36864
    if (l >= kD * kD * 9) return;
    int o = l / 576;
    int c = (l / 9) % 64;
    int kk = l % 9;
    dwtb[(kk * 64 + o) * 64 + c] = bf16r(dw[l]);
}

// ---------------------------------------------------------------------------
// offset-conv weights: ow (18,64,3,3) fp32 -> owtb[kk][n=32 pad][c=64] bf16
// ---------------------------------------------------------------------------
__global__ void ow_tb(const float* __restrict__ ow, ushort_t* __restrict__ owtb) {
    int l = blockIdx.x * 256 + threadIdx.x;   // 9*32*64 = 18432
    if (l >= 9 * 32 * 64) return;
    int kk = l >> 11;
    int j  = (l >> 6) & 31;
    int c  = l & 63;
    owtb[l] = (j < 18) ? bf16r(ow[j * 576 + c * 9 + kk]) : (ushort_t)0;
}

// ---------------------------------------------------------------------------
// QKV weight pack: W fp32 [n=576][c=192] -> awb[strip s=36][kc=6][lane=64][8]
// ---------------------------------------------------------------------------
__global__ void qw_pack(const float* __restrict__ w, ushort_t* __restrict__ awb) {
    int idx = blockIdx.x * 256 + threadIdx.x;   // 36*6*64 = 13824
    if (idx >= 36 * 6 * 64) return;
    int lane = idx & 63;
    int kc   = (idx >> 6) % 6;
    int s    = idx / 384;
    int row  = s * 16 + (lane & 15);
    int k0   = kc * 32 + (lane >> 4) * 8;
    const float* src = w + (size_t)row * kC + k0;
    ushort_t* dst = awb + (size_t)idx * 8;
#pragma unroll
    for (int j = 0; j < 8; ++j) dst[j] = bf16r(src[j]);
}

// ---------------------------------------------------------------------------
// Kernel 1: QKV projection GEMM, LDS-staged (round-11, verified 68->~8us).
// ---------------------------------------------------------------------------
__global__ __launch_bounds__(256) void qkv_mfma3(const ushort_t* __restrict__ xb,
                                                 const ushort_t* __restrict__ awb,
                                                 ushort_t* __restrict__ qkvpx) {
    __shared__ ushort_t xs[64 * kC];            // 24576 B, swizzled rows of 384 B

    const int tid = threadIdx.x;
    const int bx  = blockIdx.x;
    const int lb  = (bx & 7) * 64 + (bx >> 3);  // XCD swizzle (G=512)
    const int m0  = lb * 64;
    const int ty3 = blockIdx.y;                 // tensor triple: channels [ty3*192, +192)

#pragma unroll
    for (int i = 0; i < 6; ++i) {
        int il = i * 256 + tid;                 // 16B chunk id, 0..1535
        int p  = il / 24;                       // pixel row in strip
        int cc = il % 24;                       // 16B chunk within row
        uint4 v = *(const uint4*)(xb + (size_t)(m0 + p) * kC + cc * 8);
        int dst = p * 384 + ((cc * 16) ^ ((p & 7) << 4));
        *(uint4*)((char*)xs + dst) = v;
    }
    __syncthreads();

    const int lane = tid & 63;
    const int wave = tid >> 6;
    const int l15  = lane & 15;
    const int q    = lane >> 4;
    const int sbase = ty3 * 12 + wave * 3;      // first of 3 N-strips for this wave

    f4v acc[3][4];
#pragma unroll
    for (int i = 0; i < 3; ++i)
#pragma unroll
        for (int m = 0; m < 4; ++m) acc[i][m] = (f4v){0.f, 0.f, 0.f, 0.f};

    const ushort_t* ap = awb + ((size_t)sbase * 6 * 64 + lane) * 8;

#pragma unroll
    for (int kc = 0; kc < 6; ++kc) {
        s8v bfr[4];
#pragma unroll
        for (int m = 0; m < 4; ++m) {
            int row = m * 16 + l15;
            int col = (kc * 64 + q * 16) ^ ((l15 & 7) << 4);
            bfr[m] = *(const s8v*)((const char*)xs + row * 384 + col);
        }
#pragma unroll
        for (int i = 0; i < 3; ++i) {
            s8v a = *(const s8v*)(ap + (size_t)(i * 6 + kc) * 64 * 8);
#pragma unroll
            for (int m = 0; m < 4; ++m)
                acc[i][m] = __builtin_amdgcn_mfma_f32_16x16x32_bf16(a, bfr[m], acc[i][m], 0, 0, 0);
        }
    }

#pragma unroll
    for (int i = 0; i < 3; ++i) {
        int s   = sbase + i;
        int ty  = s >> 2;                       // tensor 0..8
        int c64 = (s & 3) * 16 + q * 4;         // channel within tensor
        ushort_t* obase = qkvpx + (size_t)ty * kM * 64 + (size_t)m0 * 64 + c64;
#pragma unroll
        for (int m = 0; m < 4; ++m) {
            f4v v = acc[i][m];
            uint2 u;
            u.x = (unsigned)bf16r(v.x) | ((unsigned)bf16r(v.y) << 16);
            u.y = (unsigned)bf16r(v.z) | ((unsigned)bf16r(v.w) << 16);
            *(uint2*)(obase + (size_t)(m * 16 + l15) * 64) = u;
        }
    }
}

// ---------------------------------------------------------------------------
// Kernel 2: offsets conv via bf16 MFMA over pixel-major k.
// ---------------------------------------------------------------------------
__global__ __launch_bounds__(256) void off_conv_mfma(const ushort_t* __restrict__ kpx,
                                                     const ushort_t* __restrict__ owtb,
                                                     const float* __restrict__ obias,
                                                     float* __restrict__ offb,
                                                     int dil) {
    const int lb = (blockIdx.x & 7) * 64 + (blockIdx.x >> 3);   // XCD swizzle (G=512)
    const int b = lb >> 6;
    const int y = lb & 63;
    const int tid  = threadIdx.x;
    const int lane = tid & 63;
    const int wave = tid >> 6;
    const int l15  = lane & 15;
    const int q    = lane >> 4;
    const int px   = wave * 16 + l15;

    const ushort_t* inpx = kpx + (size_t)b * kHW * 64 + q * 8;

    f4v acc[2];
    acc[0] = (f4v){0.f, 0.f, 0.f, 0.f};
    acc[1] = (f4v){0.f, 0.f, 0.f, 0.f};

#pragma unroll
    for (int kk = 0; kk < 9; ++kk) {
        const int yy = y + (kk / 3 - 1) * dil;
        const int xx = px + (kk % 3 - 1) * dil;
        const bool valid = (yy >= 0) & (yy < kH) & (xx >= 0) & (xx < kW);
        const size_t idx = valid ? (size_t)(yy * kW + xx) * 64 : 0;
        s8v a0 = *(const s8v*)(inpx + idx);
        s8v a1 = *(const s8v*)(inpx + idx + 32);
        if (!valid) {
            a0 = (s8v){0, 0, 0, 0, 0, 0, 0, 0};
            a1 = (s8v){0, 0, 0, 0, 0, 0, 0, 0};
        }
        const ushort_t* wb = owtb + (size_t)kk * 2048 + l15 * 64 + q * 8;
#pragma unroll
        for (int nbk = 0; nbk < 2; ++nbk) {
            s8v b0 = *(const s8v*)(wb + nbk * 1024);
            s8v b1 = *(const s8v*)(wb + nbk * 1024 + 32);
            acc[nbk] = __builtin_amdgcn_mfma_f32_16x16x32_bf16(a0, b0, acc[nbk], 0, 0, 0);
            acc[nbk] = __builtin_amdgcn_mfma_f32_16x16x32_bf16(a1, b1, acc[nbk], 0, 0, 0);
        }
    }
#pragma unroll
    for (int nbk = 0; nbk < 2; ++nbk) {
        int n = nbk * 16 + l15;
        if (n < 18) {
            float bias = obias[n];
            f4v v = acc[nbk];
            v.x += bias; v.y += bias; v.z += bias; v.w += bias;
            *(f4v*)&offb[((size_t)b * 18 + n) * kHW + y * kW + wave * 16 + q * 4] = v;
        }
    }
}

// ---------------------------------------------------------------------------
// Kernel 3 (round-12 rewrite): deformable 3x3 conv via bf16 MFMA, TAP-SPLIT.
// Old: 1024 blocks x 4 waves = 16 waves/CU cap, 9-tap serial gather chain,
// latency-bound (MfmaUtil 2.6%, VALUBusy 17%, occ 33%, 67.6us).
// Now: block = 32 pixels (half-row), 4 waves: wave-group g=0 does taps 0-4,
// g=1 does taps 5-8; partial accumulators combined via 8KB LDS + 1 barrier.
// Grid 2048 x 256thr -> 8192 waves (2x supply, 32/CU potential), serial
// chain per wave halved (<=5 taps). Gather/bilinear/MFMA structure unchanged.
// ---------------------------------------------------------------------------
template<int T0, int NT>
__device__ __forceinline__ void deform_taps(const ushort_t* __restrict__ inpx,
                                            const float* offv,
                                            const ushort_t* __restrict__ dwtb,
                                            int y, int px, int dil, int l15, int q,
                                            f4v acc[4]) {
    s8v cur[8], nxt[8];
    float wcur[4], wnxt[4];

    auto sample = [&](int lt, s8v* c, float* w) {
        const int kk = T0 + lt;
        float oy = offv[lt * 2 + 0];
        float ox = offv[lt * 2 + 1];
        float py  = (float)y  + (float)((kk / 3 - 1) * dil) + oy;
        float pxf = (float)px + (float)((kk % 3 - 1) * dil) + ox;
        float fy = floorf(py), fx = floorf(pxf);
        float wy = py - fy, wx = pxf - fx;
        int y0 = (int)fy, x0 = (int)fx;
        int y1 = y0 + 1, x1 = x0 + 1;
        int y0c = min(max(y0, 0), kH - 1), x0c = min(max(x0, 0), kW - 1);
        int y1c = min(max(y1, 0), kH - 1), x1c = min(max(x1, 0), kW - 1);
        bool vy0 = (y0 >= 0) & (y0 < kH), vx0 = (x0 >= 0) & (x0 < kW);
        bool vy1 = (y1 >= 0) & (y1 < kH), vx1 = (x1 >= 0) & (x1 < kW);
        size_t i00 = (size_t)(y0c * kW + x0c) * 64;
        size_t i01 = (size_t)(y0c * kW + x1c) * 64;
        size_t i10 = (size_t)(y1c * kW + x0c) * 64;
        size_t i11 = (size_t)(y1c * kW + x1c) * 64;
        w[0] = (vy0 && vx0) ? (1.f - wy) * (1.f - wx) : 0.f;
        w[1] = (vy0 && vx1) ? (1.f - wy) * wx : 0.f;
        w[2] = (vy1 && vx0) ? wy * (1.f - wx) : 0.f;
        w[3] = (vy1 && vx1) ? wy * wx : 0.f;
        c[0] = *(const s8v*)(inpx + i00);
        c[1] = *(const s8v*)(inpx + i00 + 32);
        c[2] = *(const s8v*)(inpx + i01);
        c[3] = *(const s8v*)(inpx + i01 + 32);
        c[4] = *(const s8v*)(inpx + i10);
        c[5] = *(const s8v*)(inpx + i10 + 32);
        c[6] = *(const s8v*)(inpx + i11);
        c[7] = *(const s8v*)(inpx + i11 + 32);
    };

    sample(0, cur, wcur);
#pragma unroll
    for (int lt = 0; lt < NT; ++lt) {
        if (lt < NT - 1) sample(lt + 1, nxt, wnxt);   // prefetch next tap
        s8v b0, b1;
#pragma unroll
        for (int j = 0; j < 8; ++j) {
            float v0 = wcur[0] * bfu(cur[0][j]) + wcur[1] * bfu(cur[2][j]) +
                       wcur[2] * bfu(cur[4][j]) + wcur[3] * bfu(cur[6][j]);
            float v1 = wcur[0] * bfu(cur[1][j]) + wcur[1] * bfu(cur[3][j]) +
                       wcur[2] * bfu(cur[5][j]) + wcur[3] * bfu(cur[7][j]);
            b0[j] = (short)bf16r(v0);
            b1[j] = (short)bf16r(v1);
        }
        const int kk = T0 + lt;
        const ushort_t* wb = dwtb + (size_t)kk * 4096 + l15 * 64 + q * 8;
#pragma unroll
        for (int obb = 0; obb < 4; ++obb) {
            s8v a0w = *(const s8v*)(wb + obb * 1024);
            s8v a1w = *(const s8v*)(wb + obb * 1024 + 32);
            acc[obb] = __builtin_amdgcn_mfma_f32_16x16x32_bf16(a0w, b0, acc[obb], 0, 0, 0);
            acc[obb] = __builtin_amdgcn_mfma_f32_16x16x32_bf16(a1w, b1, acc[obb], 0, 0, 0);
        }
        if (lt < NT - 1) {
#pragma unroll
            for (int i = 0; i < 8; ++i) cur[i] = nxt[i];
#pragma unroll
            for (int i = 0; i < 4; ++i) wcur[i] = wnxt[i];
        }
    }
}

__global__ __launch_bounds__(256) void deform_mfma(const ushort_t* __restrict__ kpx,
                                                   const ushort_t* __restrict__ vpx,
                                                   const float* __restrict__ offb,
                                                   const ushort_t* __restrict__ dwtb,
                                                   const float* __restrict__ db,
                                                   ushort_t* __restrict__ outkpx,
                                                   ushort_t* __restrict__ outvpx,
                                                   int dil) {
    const int lb = (blockIdx.x & 7) * 256 + (blockIdx.x >> 3);  // XCD swizzle (G=2048)
    const int t    = lb >> 10;          // 0 = k, 1 = v
    const int b    = (lb >> 7) & 7;
    const int y    = (lb >> 1) & 63;
    const int half = lb & 1;
    const int tid  = threadIdx.x;
    const int lane = tid & 63;
    const int wave = tid >> 6;          // 0..3
    const int w4   = wave & 1;          // pixel half-of-half
    const int g    = wave >> 1;         // tap group: 0 -> taps 0-4, 1 -> taps 5-8
    const int l15  = lane & 15;
    const int q    = lane >> 4;
    const int px   = half * 32 + w4 * 16 + l15;   // B-operand pixel for this lane

    __shared__ f4v red[2][4][64];       // [w4][obb][lane] partials from group 1 (8 KB)

    const ushort_t* inpx = (t ? vpx : kpx) + (size_t)b * kHW * 64 + q * 8;
    ushort_t* outp = t ? outvpx : outkpx;

    f4v acc[4];
#pragma unroll
    for (int ob = 0; ob < 4; ++ob) acc[ob] = (f4v){0.f, 0.f, 0.f, 0.f};

    // prefetch this group's offset channels for my pixel
    const int t0 = g ? 5 : 0;
    const int n_off = g ? 8 : 10;
    const float* offrow = offb + (size_t)b * 18 * kHW + y * kW + px;
    float offv[10];
#pragma unroll
    for (int i = 0; i < 10; ++i)
        if (i < n_off) offv[i] = offrow[(size_t)(t0 * 2 + i) * kHW];

    if (g == 0)
        deform_taps<0, 5>(inpx, offv, dwtb, y, px, dil, l15, q, acc);
    else
        deform_taps<5, 4>(inpx, offv, dwtb, y, px, dil, l15, q, acc);

    if (g == 1) {
#pragma unroll
        for (int ob = 0; ob < 4; ++ob) red[w4][ob][lane] = acc[ob];
    }
    __syncthreads();
    if (g == 0) {
        ushort_t* orow = outp + ((size_t)b * kHW + y * kW + px) * 64 + q * 4;
#pragma unroll
        for (int obb = 0; obb < 4; ++obb) {
            f4v p = red[w4][obb][lane];
            float4 bias = *(const float4*)&db[obb * 16 + q * 4];
            f4v v = acc[obb];
            v.x += p.x; v.y += p.y; v.z += p.z; v.w += p.w;
            uint2 u;
            u.x = (unsigned)bf16r(v.x + bias.x) | ((unsigned)bf16r(v.y + bias.y) << 16);
            u.y = (unsigned)bf16r(v.z + bias.z) | ((unsigned)bf16r(v.w + bias.w) << 16);
            *(uint2*)(orow + obb * 16) = u;
        }
    }
}

// ---------------------------------------------------------------------------
// Kernel 4 (round-12): 9-tap local attention, bf16 pixel-major q/k/v.
// Was 512 blocks = 2048 waves = 8/CU, latency-bound gathers.
// Now: 8 lanes per pixel (8 ch each, shfl_xor 1/2/4 reduce), half-row blocks
// -> 1024 blocks = 4096 waves = 16/CU, per-lane load bytes halved.
// ---------------------------------------------------------------------------
__global__ __launch_bounds__(256) void attn_px(const ushort_t* __restrict__ qpx,
                                               const ushort_t* __restrict__ kpx,
                                               const ushort_t* __restrict__ vpx,
                                               ushort_t* __restrict__ aopx,
                                               int branch, int dil) {
    const int lb = (blockIdx.x & 7) * 128 + (blockIdx.x >> 3);  // XCD swizzle (G=1024)
    const int b    = lb >> 7;
    const int y    = (lb >> 1) & 63;
    const int half = lb & 1;
    const int tid  = threadIdx.x;
    const int wave = tid >> 6;
    const int l    = tid & 63;
    const int pxq  = l >> 3;          // 8 pixels per wave
    const int cg   = l & 7;           // 8 channel-groups of 8 ch
    const int x = half * 32 + wave * 8 + pxq;
    const int p = y * kW + x;
    const size_t pbase = (size_t)b * kHW;

    const ushort_t* qb = qpx + (pbase + p) * 64 + cg * 8;
    s8v q0 = *(const s8v*)qb;
    float qf[8];
#pragma unroll
    for (int j = 0; j < 8; ++j) qf[j] = bfu(q0[j]);

    int offs[9]; float msk[9];
#pragma unroll
    for (int kk = 0; kk < 9; ++kk) {
        int dy = (kk / 3 - 1) * dil, dx = (kk % 3 - 1) * dil;
        int yy = y + dy, xx = x + dx;
        bool v = (yy >= 0) & (yy < kH) & (xx >= 0) & (xx < kW);
        offs[kk] = v ? (p + dy * kW + dx) : p;
        msk[kk] = v ? 1.f : 0.f;
    }
    float e[9];
#pragma unroll
    for (int kk = 0; kk < 9; ++kk) {
        const ushort_t* kp = kpx + (pbase + offs[kk]) * 64 + cg * 8;
        s8v k0 = *(const s8v*)kp;
        float s = 0.f;
#pragma unroll
        for (int j = 0; j < 8; ++j) s += qf[j] * bfu(k0[j]);
        s += __shfl_xor(s, 1);
        s += __shfl_xor(s, 2);
        s += __shfl_xor(s, 4);
        e[kk] = s * 0.125f * msk[kk];
    }
    float mx = -1e30f;
#pragma unroll
    for (int kk = 0; kk < 9; ++kk) mx = fmaxf(mx, e[kk]);
    float ssum = 0.f;
#pragma unroll
    for (int kk = 0; kk < 9; ++kk) { e[kk] = __expf(e[kk] - mx); ssum += e[kk]; }
    float inv = 1.f / ssum;
#pragma unroll
    for (int kk = 0; kk < 9; ++kk) e[kk] = e[kk] * inv * msk[kk];

    float acc[8];
#pragma unroll
    for (int j = 0; j < 8; ++j) acc[j] = 0.f;
#pragma unroll
    for (int kk = 0; kk < 9; ++kk) {
        const ushort_t* vp = vpx + (pbase + offs[kk]) * 64 + cg * 8;
        s8v v0 = *(const s8v*)vp;
        float w = e[kk];
#pragma unroll
        for (int j = 0; j < 8; ++j) acc[j] += w * bfu(v0[j]);
    }
    unsigned u[4];
#pragma unroll
    for (int i = 0; i < 4; ++i)
        u[i] = (unsigned)bf16r(acc[2 * i]) | ((unsigned)bf16r(acc[2 * i + 1]) << 16);
    ushort_t* ob = aopx + (pbase + p) * kC + branch * 64 + cg * 8;
    *(uint4*)ob = make_uint4(u[0], u[1], u[2], u[3]);
}

// ---------------------------------------------------------------------------
// Kernel 5: output projection via bf16 MFMA on pixel-major ao.
// ---------------------------------------------------------------------------
__global__ __launch_bounds__(256) void proj_mfma(const ushort_t* __restrict__ aopx,
                                                 const ushort_t* __restrict__ pwb,
                                                 const float* __restrict__ pb,
                                                 float* __restrict__ out) {
    const int tid  = threadIdx.x;
    const int lane = tid & 63;
    const int wave = tid >> 6;
    const int l15  = lane & 15;
    const int q    = lane >> 4;
    const int m0   = blockIdx.x * 64;
    const int nb   = blockIdx.y * 64 + wave * 16;

    f4v acc[4];
#pragma unroll
    for (int ob = 0; ob < 4; ++ob) acc[ob] = (f4v){0.f, 0.f, 0.f, 0.f};

    const ushort_t* aw = pwb + (size_t)(nb + l15) * kC + q * 8;
    const ushort_t* bx = aopx + (size_t)(m0 + l15) * kC + q * 8;
#pragma unroll
    for (int kc = 0; kc < 6; ++kc) {
        s8v a = *(const s8v*)(aw + kc * 32);
#pragma unroll
        for (int ob = 0; ob < 4; ++ob) {
            s8v b = *(const s8v*)(bx + (size_t)(ob * 16) * kC + kc * 32);
            acc[ob] = __builtin_amdgcn_mfma_f32_16x16x32_bf16(a, b, acc[ob], 0, 0, 0);
        }
    }
    float4 bias = *(const float4*)&pb[nb + q * 4];
#pragma unroll
    for (int ob = 0; ob < 4; ++ob) {
        int m = m0 + ob * 16 + l15;
        f4v v = acc[ob];
        v.x += bias.x; v.y += bias.y; v.z += bias.z; v.w += bias.w;
        *(f4v*)&out[(size_t)m * kC + nb + q * 4] = v;
    }
}

// ---------------------------------------------------------------------------
// Host launcher.  Workspace (~63 MB, well under the proven 120 MB).
// ---------------------------------------------------------------------------
extern "C" void kernel_launch(void* const* d_in, const int* in_sizes, int n_in,
                              void* d_out, int out_size, void* d_ws, size_t ws_size,
                              hipStream_t stream) {
    const float* x      = (const float*)d_in[0];
    const float* qkv_w  = (const float*)d_in[1];
    const float* proj_w = (const float*)d_in[2];
    const float* proj_b = (const float*)d_in[3];
    const float* off_w2 = (const float*)d_in[4];
    const float* off_b2 = (const float*)d_in[5];
    const float* def_w2 = (const float*)d_in[6];
    const float* def_b2 = (const float*)d_in[7];
    const float* off_w3 = (const float*)d_in[8];
    const float* off_b3 = (const float*)d_in[9];
    const float* def_w3 = (const float*)d_in[10];
    const float* def_b3 = (const float*)d_in[11];
    float* out = (float*)d_out;

    float* ws   = (float*)d_ws;
    float* offb = ws;                               // 18 * M
    ushort_t* us = (ushort_t*)(offb + (size_t)18 * kM);
    ushort_t* xb     = us;  us += (size_t)kM * kC;
    ushort_t* qkvpx  = us;  us += (size_t)9 * kM * 64;
    ushort_t* kdpx   = us;  us += (size_t)kM * 64;
    ushort_t* vdpx   = us;  us += (size_t)kM * 64;
    ushort_t* aopx   = us;  us += (size_t)kM * kC;
    ushort_t* awb    = us;  us += (size_t)kNQKV * kC;   // 36*6*64*8 == 576*192
    ushort_t* pwb    = us;  us += (size_t)kC * kC;
    ushort_t* dwtb2  = us;  us += kD * kD * 9;
    ushort_t* dwtb3  = us;  us += kD * kD * 9;
    ushort_t* owtb2  = us;  us += 9 * 32 * 64;
    ushort_t* owtb3  = us;  us += 9 * 32 * 64;

    // 0. bf16 conversions and weight transposes/packs
    cvt_bf16<<<(kM * kC / 2 + 255) / 256, 256, 0, stream>>>(x, (unsigned*)xb, kM * kC / 2);
    qw_pack<<<54, 256, 0, stream>>>(qkv_w, awb);
    cvt_bf16<<<(kC * kC / 2 + 255) / 256, 256, 0, stream>>>(proj_w, (unsigned*)pwb, kC * kC / 2);
    dw_tb<<<144, 256, 0, stream>>>(def_w2, dwtb2);
    dw_tb<<<144, 256, 0, stream>>>(def_w3, dwtb3);
    ow_tb<<<72, 256, 0, stream>>>(off_w2, owtb2);
    ow_tb<<<72, 256, 0, stream>>>(off_w3, owtb3);

    // per-tensor pixel-major slices
    ushort_t* q0 = qkvpx;
    ushort_t* q1 = qkvpx + (size_t)1 * kM * 64;
    ushort_t* q2 = qkvpx + (size_t)2 * kM * 64;
    ushort_t* k0 = qkvpx + (size_t)3 * kM * 64;
    ushort_t* k1 = qkvpx + (size_t)4 * kM * 64;
    ushort_t* k2 = qkvpx + (size_t)5 * kM * 64;
    ushort_t* v0 = qkvpx + (size_t)6 * kM * 64;
    ushort_t* v1 = qkvpx + (size_t)7 * kM * 64;
    ushort_t* v2 = qkvpx + (size_t)8 * kM * 64;

    // 1. QKV projection -> 9 bf16 pixel-major tensors (LDS-staged GEMM)
    qkv_mfma3<<<dim3(kM / 64, 3), 256, 0, stream>>>(xb, awb, qkvpx);

    // 2. branch 0 (dil=1)
    attn_px<<<kB * kH * 2, 256, 0, stream>>>(q0, k0, v0, aopx, 0, 1);

    // 3. branch 1 (dil=2)
    off_conv_mfma<<<512, 256, 0, stream>>>(k1, owtb2, off_b2, offb, 2);
    deform_mfma<<<2048, 256, 0, stream>>>(k1, v1, offb, dwtb2, def_b2, kdpx, vdpx, 2);
    attn_px<<<kB * kH * 2, 256, 0, stream>>>(q1, kdpx, vdpx, aopx, 1, 2);

    // 4. branch 2 (dil=3)
    off_conv_mfma<<<512, 256, 0, stream>>>(k2, owtb3, off_b3, offb, 3);
    deform_mfma<<<2048, 256, 0, stream>>>(k2, v2, offb, dwtb3, def_b3, kdpx, vdpx, 3);
    attn_px<<<kB * kH * 2, 256, 0, stream>>>(q2, kdpx, vdpx, aopx, 2, 3);

    // 5. output projection (bf16 MFMA, fp32 out)
    proj_mfma<<<dim3(kM / 64, 3), 256, 0, stream>>>(aopx, pwb, proj_b, out);
}

// Round 3
// 300.160 us; speedup vs baseline: 1.1121x; 1.1121x over previous
//
#include <hip/hip_runtime.h>
#include <cmath>

// ---------------------------------------------------------------------------
// Problem constants (B=8, H=W=64, C=192, 3 dilation branches of d=64, heads=64)
// ---------------------------------------------------------------------------
#define kB    8
#define kH    64
#define kW    64
#define kHW   4096          // H*W
#define kC    192
#define kD    64            // channels per dilation branch == head_dim
#define kM    (kB * kHW)    // 32768 total pixels
#define kNQKV 576           // 3*C

typedef unsigned short ushort_t;
typedef __attribute__((ext_vector_type(8))) short  s8v;   // 8 bf16 (4 VGPRs)
typedef __attribute__((ext_vector_type(4))) float  f4v;   // MFMA C/D frag

__device__ inline unsigned short bf16r(float f) {   // round-to-nearest-even
    union { float f; unsigned u; } v; v.f = f;
    unsigned u = v.u + 0x7FFFu + ((v.u >> 16) & 1u);
    return (unsigned short)(u >> 16);
}
__device__ inline float bfu(short s) {              // bf16 -> fp32
    union { unsigned u; float f; } v;
    v.u = ((unsigned)(unsigned short)s) << 16;
    return v.f;
}

// ---------------------------------------------------------------------------
// fp32 -> bf16 pairwise converter
// ---------------------------------------------------------------------------
__global__ void cvt_bf16(const float* __restrict__ src, unsigned* __restrict__ dst, int n2) {
    int i = blockIdx.x * 256 + threadIdx.x;
    if (i >= n2) return;
    float2 f = ((const float2*)src)[i];
    dst[i] = (unsigned)bf16r(f.x) | ((unsigned)bf16r(f.y) << 16);
}

// ---------------------------------------------------------------------------
// deform weights: dw (o,c,kk) fp32 -> dwtb[kk][o][c] bf16
// ---------------------------------------------------------------------------
__global__ void dw_tb(const float* __restrict__ dw, ushort_t* __restrict__ dwtb) {
    int l = blockIdx.x * 256 + threadIdx.x;   // 64*64*9 = 36864
    if (l >= kD * kD * 9) return;
    int o = l / 576;
    int c = (l / 9) % 64;
    int kk = l % 9;
    dwtb[(kk * 64 + o) * 64 + c] = bf16r(dw[l]);
}

// ---------------------------------------------------------------------------
// offset-conv weights: ow (18,64,3,3) fp32 -> owtb[kk][n=32 pad][c=64] bf16
// ---------------------------------------------------------------------------
__global__ void ow_tb(const float* __restrict__ ow, ushort_t* __restrict__ owtb) {
    int l = blockIdx.x * 256 + threadIdx.x;   // 9*32*64 = 18432
    if (l >= 9 * 32 * 64) return;
    int kk = l >> 11;
    int j  = (l >> 6) & 31;
    int c  = l & 63;
    owtb[l] = (j < 18) ? bf16r(ow[j * 576 + c * 9 + kk]) : (ushort_t)0;
}

// ---------------------------------------------------------------------------
// QKV weight pack: W fp32 [n=576][c=192] -> awb[strip s=36][kc=6][lane=64][8]
// ---------------------------------------------------------------------------
__global__ void qw_pack(const float* __restrict__ w, ushort_t* __restrict__ awb) {
    int idx = blockIdx.x * 256 + threadIdx.x;   // 36*6*64 = 13824
    if (idx >= 36 * 6 * 64) return;
    int lane = idx & 63;
    int kc   = (idx >> 6) % 6;
    int s    = idx / 384;
    int row  = s * 16 + (lane & 15);
    int k0   = kc * 32 + (lane >> 4) * 8;
    const float* src = w + (size_t)row * kC + k0;
    ushort_t* dst = awb + (size_t)idx * 8;
#pragma unroll
    for (int j = 0; j < 8; ++j) dst[j] = bf16r(src[j]);
}

// ---------------------------------------------------------------------------
// Kernel 1: QKV projection GEMM, LDS-staged (round-11, verified).
// ---------------------------------------------------------------------------
__global__ __launch_bounds__(256) void qkv_mfma3(const ushort_t* __restrict__ xb,
                                                 const ushort_t* __restrict__ awb,
                                                 ushort_t* __restrict__ qkvpx) {
    __shared__ ushort_t xs[64 * kC];            // 24576 B, swizzled rows of 384 B

    const int tid = threadIdx.x;
    const int bx  = blockIdx.x;
    const int lb  = (bx & 7) * 64 + (bx >> 3);  // XCD swizzle (G=512)
    const int m0  = lb * 64;
    const int ty3 = blockIdx.y;                 // tensor triple: channels [ty3*192, +192)

#pragma unroll
    for (int i = 0; i < 6; ++i) {
        int il = i * 256 + tid;                 // 16B chunk id, 0..1535
        int p  = il / 24;                       // pixel row in strip
        int cc = il % 24;                       // 16B chunk within row
        uint4 v = *(const uint4*)(xb + (size_t)(m0 + p) * kC + cc * 8);
        int dst = p * 384 + ((cc * 16) ^ ((p & 7) << 4));
        *(uint4*)((char*)xs + dst) = v;
    }
    __syncthreads();

    const int lane = tid & 63;
    const int wave = tid >> 6;
    const int l15  = lane & 15;
    const int q    = lane >> 4;
    const int sbase = ty3 * 12 + wave * 3;      // first of 3 N-strips for this wave

    f4v acc[3][4];
#pragma unroll
    for (int i = 0; i < 3; ++i)
#pragma unroll
        for (int m = 0; m < 4; ++m) acc[i][m] = (f4v){0.f, 0.f, 0.f, 0.f};

    const ushort_t* ap = awb + ((size_t)sbase * 6 * 64 + lane) * 8;

#pragma unroll
    for (int kc = 0; kc < 6; ++kc) {
        s8v bfr[4];
#pragma unroll
        for (int m = 0; m < 4; ++m) {
            int row = m * 16 + l15;
            int col = (kc * 64 + q * 16) ^ ((l15 & 7) << 4);
            bfr[m] = *(const s8v*)((const char*)xs + row * 384 + col);
        }
#pragma unroll
        for (int i = 0; i < 3; ++i) {
            s8v a = *(const s8v*)(ap + (size_t)(i * 6 + kc) * 64 * 8);
#pragma unroll
            for (int m = 0; m < 4; ++m)
                acc[i][m] = __builtin_amdgcn_mfma_f32_16x16x32_bf16(a, bfr[m], acc[i][m], 0, 0, 0);
        }
    }

#pragma unroll
    for (int i = 0; i < 3; ++i) {
        int s   = sbase + i;
        int ty  = s >> 2;                       // tensor 0..8
        int c64 = (s & 3) * 16 + q * 4;         // channel within tensor
        ushort_t* obase = qkvpx + (size_t)ty * kM * 64 + (size_t)m0 * 64 + c64;
#pragma unroll
        for (int m = 0; m < 4; ++m) {
            f4v v = acc[i][m];
            uint2 u;
            u.x = (unsigned)bf16r(v.x) | ((unsigned)bf16r(v.y) << 16);
            u.y = (unsigned)bf16r(v.z) | ((unsigned)bf16r(v.w) << 16);
            *(uint2*)(obase + (size_t)(m * 16 + l15) * 64) = u;
        }
    }
}

// ---------------------------------------------------------------------------
// Kernel 2: offsets conv via bf16 MFMA over pixel-major k.
// ---------------------------------------------------------------------------
__global__ __launch_bounds__(256) void off_conv_mfma(const ushort_t* __restrict__ kpx,
                                                     const ushort_t* __restrict__ owtb,
                                                     const float* __restrict__ obias,
                                                     float* __restrict__ offb,
                                                     int dil) {
    const int lb = (blockIdx.x & 7) * 64 + (blockIdx.x >> 3);   // XCD swizzle (G=512)
    const int b = lb >> 6;
    const int y = lb & 63;
    const int tid  = threadIdx.x;
    const int lane = tid & 63;
    const int wave = tid >> 6;
    const int l15  = lane & 15;
    const int q    = lane >> 4;
    const int px   = wave * 16 + l15;

    const ushort_t* inpx = kpx + (size_t)b * kHW * 64 + q * 8;

    f4v acc[2];
    acc[0] = (f4v){0.f, 0.f, 0.f, 0.f};
    acc[1] = (f4v){0.f, 0.f, 0.f, 0.f};

#pragma unroll
    for (int kk = 0; kk < 9; ++kk) {
        const int yy = y + (kk / 3 - 1) * dil;
        const int xx = px + (kk % 3 - 1) * dil;
        const bool valid = (yy >= 0) & (yy < kH) & (xx >= 0) & (xx < kW);
        const size_t idx = valid ? (size_t)(yy * kW + xx) * 64 : 0;
        s8v a0 = *(const s8v*)(inpx + idx);
        s8v a1 = *(const s8v*)(inpx + idx + 32);
        if (!valid) {
            a0 = (s8v){0, 0, 0, 0, 0, 0, 0, 0};
            a1 = (s8v){0, 0, 0, 0, 0, 0, 0, 0};
        }
        const ushort_t* wb = owtb + (size_t)kk * 2048 + l15 * 64 + q * 8;
#pragma unroll
        for (int nbk = 0; nbk < 2; ++nbk) {
            s8v b0 = *(const s8v*)(wb + nbk * 1024);
            s8v b1 = *(const s8v*)(wb + nbk * 1024 + 32);
            acc[nbk] = __builtin_amdgcn_mfma_f32_16x16x32_bf16(a0, b0, acc[nbk], 0, 0, 0);
            acc[nbk] = __builtin_amdgcn_mfma_f32_16x16x32_bf16(a1, b1, acc[nbk], 0, 0, 0);
        }
    }
#pragma unroll
    for (int nbk = 0; nbk < 2; ++nbk) {
        int n = nbk * 16 + l15;
        if (n < 18) {
            float bias = obias[n];
            f4v v = acc[nbk];
            v.x += bias; v.y += bias; v.z += bias; v.w += bias;
            *(f4v*)&offb[((size_t)b * 18 + n) * kHW + y * kW + wave * 16 + q * 4] = v;
        }
    }
}

// ---------------------------------------------------------------------------
// Kernel 3 (round-13 rewrite): deformable 3x3 conv, LDS-STAGED gathers.
// Rounds 10-12 established: the gather path is wall-limited by scattered
// 64B line throughput per CU (TLP-invariant 68us, all pipes <18% busy).
// Fix: each source line was re-gathered ~36x from global (9 taps x 4
// corners across neighbor pixels). Now a block stages the full source
// window ONCE into LDS (coalesced, XOR-swizzled) and all bilinear gathers
// hit LDS.
//   block = 512 thr (8 waves = 2 output rows x 4 px-cols), one tensor
//   staged rows: [y0-DIL-2, y0+1+DIL+2] -> NR=2*DIL+6 (10 or 12 rows,
//     80/96 KB), covers any |offset|<2 (measured |off|max ~0.8); per-lane
//     |oy|>=2 falls back to the verified global-gather path (exact).
//   gather swizzle: byte ^= (x&7)<<4 -> uniform 8 lanes/bank-group =
//     b128 minimum (without: 16 lanes/group, 2x serialization).
// ---------------------------------------------------------------------------
template<int DIL>
__global__ __launch_bounds__(512) void deform_lds(const ushort_t* __restrict__ kpx,
                                                  const ushort_t* __restrict__ vpx,
                                                  const float* __restrict__ offb,
                                                  const ushort_t* __restrict__ dwtb,
                                                  const float* __restrict__ db,
                                                  ushort_t* __restrict__ outkpx,
                                                  ushort_t* __restrict__ outvpx) {
    constexpr int NR = 2 * DIL + 6;         // staged rows
    __shared__ ushort_t kv[NR * 4096];      // NR x (64 px x 64 ch), 8192 B/row, swizzled

    const int tid = threadIdx.x;
    const int bx  = blockIdx.x;
    const int lb  = (bx & 7) * 64 + (bx >> 3);  // XCD swizzle (G=512)
    const int t   = lb >> 8;                // 0 = k, 1 = v
    const int b   = (lb >> 5) & 7;
    const int y0  = (lb & 31) * 2;          // first of 2 output rows
    const int wlo = y0 - DIL - 2;           // staged window start (may be <0)

    const ushort_t* inb = (t ? vpx : kpx) + (size_t)b * kHW * 64;
    ushort_t* outp = t ? outvpx : outkpx;

    // ---- stage NR rows, coalesced 16B/thread, swizzled ----
#pragma unroll
    for (int r = 0; r < NR; ++r) {
        int gy = min(max(wlo + r, 0), kH - 1);
        uint4 v = *(const uint4*)(inb + (size_t)gy * 4096 + tid * 8);
        int x  = tid >> 3;
        int cc = tid & 7;
        int dst = r * 8192 + ((x * 128 + cc * 16) ^ ((x & 7) << 4));
        *(uint4*)((char*)kv + dst) = v;
    }
    __syncthreads();

    const int lane = tid & 63;
    const int wave = tid >> 6;          // 0..7
    const int ry   = wave >> 2;         // output row within pair
    const int wc   = wave & 3;          // px column
    const int l15  = lane & 15;
    const int q    = lane >> 4;
    const int y    = y0 + ry;
    const int px   = wc * 16 + l15;

    const ushort_t* inpx = inb + q * 8; // global fallback base

    f4v acc[4];
#pragma unroll
    for (int ob = 0; ob < 4; ++ob) acc[ob] = (f4v){0.f, 0.f, 0.f, 0.f};

    // prefetch all 18 offset channels for my pixel
    const float* offrow = offb + (size_t)b * 18 * kHW + y * kW + px;
    float offv[18];
#pragma unroll
    for (int i = 0; i < 18; ++i) offv[i] = offrow[(size_t)i * kHW];

#pragma unroll
    for (int kk = 0; kk < 9; ++kk) {
        float oy = offv[kk * 2 + 0];
        float ox = offv[kk * 2 + 1];
        float py  = (float)y  + (float)((kk / 3 - 1) * DIL) + oy;
        float pxf = (float)px + (float)((kk % 3 - 1) * DIL) + ox;
        float fy = floorf(py), fx = floorf(pxf);
        float wy = py - fy, wx = pxf - fx;
        int iy0 = (int)fy, ix0 = (int)fx;
        int iy1 = iy0 + 1, ix1 = ix0 + 1;
        int y0c = min(max(iy0, 0), kH - 1), x0c = min(max(ix0, 0), kW - 1);
        int y1c = min(max(iy1, 0), kH - 1), x1c = min(max(ix1, 0), kW - 1);
        bool vy0 = (iy0 >= 0) & (iy0 < kH), vx0 = (ix0 >= 0) & (ix0 < kW);
        bool vy1 = (iy1 >= 0) & (iy1 < kH), vx1 = (ix1 >= 0) & (ix1 < kW);
        float w0 = (vy0 && vx0) ? (1.f - wy) * (1.f - wx) : 0.f;
        float w1 = (vy0 && vx1) ? (1.f - wy) * wx : 0.f;
        float w2 = (vy1 && vx0) ? wy * (1.f - wx) : 0.f;
        float w3 = (vy1 && vx1) ? wy * wx : 0.f;

        s8v c[8];
        if (__builtin_expect(fabsf(oy) < 2.0f, 1)) {
            // LDS fast path: window guaranteed to contain valid corners
            int r0 = min(max(y0c - wlo, 0), NR - 1);
            int r1 = min(max(y1c - wlo, 0), NR - 1);
            int b00 = r0 * 8192 + ((x0c * 128 + q * 16) ^ ((x0c & 7) << 4));
            int b00h = r0 * 8192 + ((x0c * 128 + q * 16 + 64) ^ ((x0c & 7) << 4));
            int b01 = r0 * 8192 + ((x1c * 128 + q * 16) ^ ((x1c & 7) << 4));
            int b01h = r0 * 8192 + ((x1c * 128 + q * 16 + 64) ^ ((x1c & 7) << 4));
            int b10 = r1 * 8192 + ((x0c * 128 + q * 16) ^ ((x0c & 7) << 4));
            int b10h = r1 * 8192 + ((x0c * 128 + q * 16 + 64) ^ ((x0c & 7) << 4));
            int b11 = r1 * 8192 + ((x1c * 128 + q * 16) ^ ((x1c & 7) << 4));
            int b11h = r1 * 8192 + ((x1c * 128 + q * 16 + 64) ^ ((x1c & 7) << 4));
            c[0] = *(const s8v*)((const char*)kv + b00);
            c[1] = *(const s8v*)((const char*)kv + b00h);
            c[2] = *(const s8v*)((const char*)kv + b01);
            c[3] = *(const s8v*)((const char*)kv + b01h);
            c[4] = *(const s8v*)((const char*)kv + b10);
            c[5] = *(const s8v*)((const char*)kv + b10h);
            c[6] = *(const s8v*)((const char*)kv + b11);
            c[7] = *(const s8v*)((const char*)kv + b11h);
        } else {
            // exact global fallback (never taken for this data, kept for
            // correctness under arbitrary offsets)
            size_t i00 = (size_t)(y0c * kW + x0c) * 64;
            size_t i01 = (size_t)(y0c * kW + x1c) * 64;
            size_t i10 = (size_t)(y1c * kW + x0c) * 64;
            size_t i11 = (size_t)(y1c * kW + x1c) * 64;
            c[0] = *(const s8v*)(inpx + i00);
            c[1] = *(const s8v*)(inpx + i00 + 32);
            c[2] = *(const s8v*)(inpx + i01);
            c[3] = *(const s8v*)(inpx + i01 + 32);
            c[4] = *(const s8v*)(inpx + i10);
            c[5] = *(const s8v*)(inpx + i10 + 32);
            c[6] = *(const s8v*)(inpx + i11);
            c[7] = *(const s8v*)(inpx + i11 + 32);
        }

        s8v b0, b1;
#pragma unroll
        for (int j = 0; j < 8; ++j) {
            float v0 = w0 * bfu(c[0][j]) + w1 * bfu(c[2][j]) +
                       w2 * bfu(c[4][j]) + w3 * bfu(c[6][j]);
            float v1 = w0 * bfu(c[1][j]) + w1 * bfu(c[3][j]) +
                       w2 * bfu(c[5][j]) + w3 * bfu(c[7][j]);
            b0[j] = (short)bf16r(v0);
            b1[j] = (short)bf16r(v1);
        }
        const ushort_t* wb = dwtb + (size_t)kk * 4096 + l15 * 64 + q * 8;
#pragma unroll
        for (int obb = 0; obb < 4; ++obb) {
            s8v a0w = *(const s8v*)(wb + obb * 1024);
            s8v a1w = *(const s8v*)(wb + obb * 1024 + 32);
            acc[obb] = __builtin_amdgcn_mfma_f32_16x16x32_bf16(a0w, b0, acc[obb], 0, 0, 0);
            acc[obb] = __builtin_amdgcn_mfma_f32_16x16x32_bf16(a1w, b1, acc[obb], 0, 0, 0);
        }
    }

    // store: lane holds o = obb*16 + q*4 + reg at pixel px -> bf16 pixel-major
    ushort_t* orow = outp + ((size_t)b * kHW + y * kW + px) * 64 + q * 4;
#pragma unroll
    for (int obb = 0; obb < 4; ++obb) {
        float4 bias = *(const float4*)&db[obb * 16 + q * 4];
        f4v v = acc[obb];
        uint2 u;
        u.x = (unsigned)bf16r(v.x + bias.x) | ((unsigned)bf16r(v.y + bias.y) << 16);
        u.y = (unsigned)bf16r(v.z + bias.z) | ((unsigned)bf16r(v.w + bias.w) << 16);
        *(uint2*)(orow + obb * 16) = u;
    }
}

// ---------------------------------------------------------------------------
// Kernel 4: 9-tap local attention, bf16 pixel-major q/k/v (round-12 form).
// ---------------------------------------------------------------------------
__global__ __launch_bounds__(256) void attn_px(const ushort_t* __restrict__ qpx,
                                               const ushort_t* __restrict__ kpx,
                                               const ushort_t* __restrict__ vpx,
                                               ushort_t* __restrict__ aopx,
                                               int branch, int dil) {
    const int lb = (blockIdx.x & 7) * 128 + (blockIdx.x >> 3);  // XCD swizzle (G=1024)
    const int b    = lb >> 7;
    const int y    = (lb >> 1) & 63;
    const int half = lb & 1;
    const int tid  = threadIdx.x;
    const int wave = tid >> 6;
    const int l    = tid & 63;
    const int pxq  = l >> 3;          // 8 pixels per wave
    const int cg   = l & 7;           // 8 channel-groups of 8 ch
    const int x = half * 32 + wave * 8 + pxq;
    const int p = y * kW + x;
    const size_t pbase = (size_t)b * kHW;

    const ushort_t* qb = qpx + (pbase + p) * 64 + cg * 8;
    s8v q0 = *(const s8v*)qb;
    float qf[8];
#pragma unroll
    for (int j = 0; j < 8; ++j) qf[j] = bfu(q0[j]);

    int offs[9]; float msk[9];
#pragma unroll
    for (int kk = 0; kk < 9; ++kk) {
        int dy = (kk / 3 - 1) * dil, dx = (kk % 3 - 1) * dil;
        int yy = y + dy, xx = x + dx;
        bool v = (yy >= 0) & (yy < kH) & (xx >= 0) & (xx < kW);
        offs[kk] = v ? (p + dy * kW + dx) : p;
        msk[kk] = v ? 1.f : 0.f;
    }
    float e[9];
#pragma unroll
    for (int kk = 0; kk < 9; ++kk) {
        const ushort_t* kp = kpx + (pbase + offs[kk]) * 64 + cg * 8;
        s8v k0 = *(const s8v*)kp;
        float s = 0.f;
#pragma unroll
        for (int j = 0; j < 8; ++j) s += qf[j] * bfu(k0[j]);
        s += __shfl_xor(s, 1);
        s += __shfl_xor(s, 2);
        s += __shfl_xor(s, 4);
        e[kk] = s * 0.125f * msk[kk];
    }
    float mx = -1e30f;
#pragma unroll
    for (int kk = 0; kk < 9; ++kk) mx = fmaxf(mx, e[kk]);
    float ssum = 0.f;
#pragma unroll
    for (int kk = 0; kk < 9; ++kk) { e[kk] = __expf(e[kk] - mx); ssum += e[kk]; }
    float inv = 1.f / ssum;
#pragma unroll
    for (int kk = 0; kk < 9; ++kk) e[kk] = e[kk] * inv * msk[kk];

    float acc[8];
#pragma unroll
    for (int j = 0; j < 8; ++j) acc[j] = 0.f;
#pragma unroll
    for (int kk = 0; kk < 9; ++kk) {
        const ushort_t* vp = vpx + (pbase + offs[kk]) * 64 + cg * 8;
        s8v v0 = *(const s8v*)vp;
        float w = e[kk];
#pragma unroll
        for (int j = 0; j < 8; ++j) acc[j] += w * bfu(v0[j]);
    }
    unsigned u[4];
#pragma unroll
    for (int i = 0; i < 4; ++i)
        u[i] = (unsigned)bf16r(acc[2 * i]) | ((unsigned)bf16r(acc[2 * i + 1]) << 16);
    ushort_t* ob = aopx + (pbase + p) * kC + branch * 64 + cg * 8;
    *(uint4*)ob = make_uint4(u[0], u[1], u[2], u[3]);
}

// ---------------------------------------------------------------------------
// Kernel 5: output projection via bf16 MFMA on pixel-major ao.
// ---------------------------------------------------------------------------
__global__ __launch_bounds__(256) void proj_mfma(const ushort_t* __restrict__ aopx,
                                                 const ushort_t* __restrict__ pwb,
                                                 const float* __restrict__ pb,
                                                 float* __restrict__ out) {
    const int tid  = threadIdx.x;
    const int lane = tid & 63;
    const int wave = tid >> 6;
    const int l15  = lane & 15;
    const int q    = lane >> 4;
    const int m0   = blockIdx.x * 64;
    const int nb   = blockIdx.y * 64 + wave * 16;

    f4v acc[4];
#pragma unroll
    for (int ob = 0; ob < 4; ++ob) acc[ob] = (f4v){0.f, 0.f, 0.f, 0.f};

    const ushort_t* aw = pwb + (size_t)(nb + l15) * kC + q * 8;
    const ushort_t* bx = aopx + (size_t)(m0 + l15) * kC + q * 8;
#pragma unroll
    for (int kc = 0; kc < 6; ++kc) {
        s8v a = *(const s8v*)(aw + kc * 32);
#pragma unroll
        for (int ob = 0; ob < 4; ++ob) {
            s8v b = *(const s8v*)(bx + (size_t)(ob * 16) * kC + kc * 32);
            acc[ob] = __builtin_amdgcn_mfma_f32_16x16x32_bf16(a, b, acc[ob], 0, 0, 0);
        }
    }
    float4 bias = *(const float4*)&pb[nb + q * 4];
#pragma unroll
    for (int ob = 0; ob < 4; ++ob) {
        int m = m0 + ob * 16 + l15;
        f4v v = acc[ob];
        v.x += bias.x; v.y += bias.y; v.z += bias.z; v.w += bias.w;
        *(f4v*)&out[(size_t)m * kC + nb + q * 4] = v;
    }
}

// ---------------------------------------------------------------------------
// Host launcher.  Workspace (~63 MB, well under the proven 120 MB).
// ---------------------------------------------------------------------------
extern "C" void kernel_launch(void* const* d_in, const int* in_sizes, int n_in,
                              void* d_out, int out_size, void* d_ws, size_t ws_size,
                              hipStream_t stream) {
    const float* x      = (const float*)d_in[0];
    const float* qkv_w  = (const float*)d_in[1];
    const float* proj_w = (const float*)d_in[2];
    const float* proj_b = (const float*)d_in[3];
    const float* off_w2 = (const float*)d_in[4];
    const float* off_b2 = (const float*)d_in[5];
    const float* def_w2 = (const float*)d_in[6];
    const float* def_b2 = (const float*)d_in[7];
    const float* off_w3 = (const float*)d_in[8];
    const float* off_b3 = (const float*)d_in[9];
    const float* def_w3 = (const float*)d_in[10];
    const float* def_b3 = (const float*)d_in[11];
    float* out = (float*)d_out;

    float* ws   = (float*)d_ws;
    float* offb = ws;                               // 18 * M
    ushort_t* us = (ushort_t*)(offb + (size_t)18 * kM);
    ushort_t* xb     = us;  us += (size_t)kM * kC;
    ushort_t* qkvpx  = us;  us += (size_t)9 * kM * 64;
    ushort_t* kdpx   = us;  us += (size_t)kM * 64;
    ushort_t* vdpx   = us;  us += (size_t)kM * 64;
    ushort_t* aopx   = us;  us += (size_t)kM * kC;
    ushort_t* awb    = us;  us += (size_t)kNQKV * kC;   // 36*6*64*8 == 576*192
    ushort_t* pwb    = us;  us += (size_t)kC * kC;
    ushort_t* dwtb2  = us;  us += kD * kD * 9;
    ushort_t* dwtb3  = us;  us += kD * kD * 9;
    ushort_t* owtb2  = us;  us += 9 * 32 * 64;
    ushort_t* owtb3  = us;  us += 9 * 32 * 64;

    // 0. bf16 conversions and weight transposes/packs
    cvt_bf16<<<(kM * kC / 2 + 255) / 256, 256, 0, stream>>>(x, (unsigned*)xb, kM * kC / 2);
    qw_pack<<<54, 256, 0, stream>>>(qkv_w, awb);
    cvt_bf16<<<(kC * kC / 2 + 255) / 256, 256, 0, stream>>>(proj_w, (unsigned*)pwb, kC * kC / 2);
    dw_tb<<<144, 256, 0, stream>>>(def_w2, dwtb2);
    dw_tb<<<144, 256, 0, stream>>>(def_w3, dwtb3);
    ow_tb<<<72, 256, 0, stream>>>(off_w2, owtb2);
    ow_tb<<<72, 256, 0, stream>>>(off_w3, owtb3);

    // per-tensor pixel-major slices
    ushort_t* q0 = qkvpx;
    ushort_t* q1 = qkvpx + (size_t)1 * kM * 64;
    ushort_t* q2 = qkvpx + (size_t)2 * kM * 64;
    ushort_t* k0 = qkvpx + (size_t)3 * kM * 64;
    ushort_t* k1 = qkvpx + (size_t)4 * kM * 64;
    ushort_t* k2 = qkvpx + (size_t)5 * kM * 64;
    ushort_t* v0 = qkvpx + (size_t)6 * kM * 64;
    ushort_t* v1 = qkvpx + (size_t)7 * kM * 64;
    ushort_t* v2 = qkvpx + (size_t)8 * kM * 64;

    // 1. QKV projection -> 9 bf16 pixel-major tensors (LDS-staged GEMM)
    qkv_mfma3<<<dim3(kM / 64, 3), 256, 0, stream>>>(xb, awb, qkvpx);

    // 2. branch 0 (dil=1)
    attn_px<<<kB * kH * 2, 256, 0, stream>>>(q0, k0, v0, aopx, 0, 1);

    // 3. branch 1 (dil=2)
    off_conv_mfma<<<512, 256, 0, stream>>>(k1, owtb2, off_b2, offb, 2);
    deform_lds<2><<<512, 512, 0, stream>>>(k1, v1, offb, dwtb2, def_b2, kdpx, vdpx);
    attn_px<<<kB * kH * 2, 256, 0, stream>>>(q1, kdpx, vdpx, aopx, 1, 2);

    // 4. branch 2 (dil=3)
    off_conv_mfma<<<512, 256, 0, stream>>>(k2, owtb3, off_b3, offb, 3);
    deform_lds<3><<<512, 512, 0, stream>>>(k2, v2, offb, dwtb3, def_b3, kdpx, vdpx);
    attn_px<<<kB * kH * 2, 256, 0, stream>>>(q2, kdpx, vdpx, aopx, 2, 3);

    // 5. output projection (bf16 MFMA, fp32 out)
    proj_mfma<<<dim3(kM / 64, 3), 256, 0, stream>>>(aopx, pwb, proj_b, out);
}

// Round 6
// 255.125 us; speedup vs baseline: 1.3085x; 1.1765x over previous
//
#include <hip/hip_runtime.h>
#include <cmath>

// ---------------------------------------------------------------------------
// Problem constants (B=8, H=W=64, C=192, 3 dilation branches of d=64, heads=64)
// ---------------------------------------------------------------------------
#define kB    8
#define kH    64
#define kW    64
#define kHW   4096          // H*W
#define kC    192
#define kD    64            // channels per dilation branch == head_dim
#define kM    (kB * kHW)    // 32768 total pixels
#define kNQKV 576           // 3*C

typedef unsigned short ushort_t;
typedef __attribute__((ext_vector_type(8))) short  s8v;   // 8 bf16 (4 VGPRs)
typedef __attribute__((ext_vector_type(4))) float  f4v;   // MFMA C/D frag

__device__ inline unsigned short bf16r(float f) {   // round-to-nearest-even
    union { float f; unsigned u; } v; v.f = f;
    unsigned u = v.u + 0x7FFFu + ((v.u >> 16) & 1u);
    return (unsigned short)(u >> 16);
}
__device__ inline float bfu(short s) {              // bf16 -> fp32
    union { unsigned u; float f; } v;
    v.u = ((unsigned)(unsigned short)s) << 16;
    return v.f;
}

// ---------------------------------------------------------------------------
// fp32 -> bf16 pairwise converter
// ---------------------------------------------------------------------------
__global__ void cvt_bf16(const float* __restrict__ src, unsigned* __restrict__ dst, int n2) {
    int i = blockIdx.x * 256 + threadIdx.x;
    if (i >= n2) return;
    float2 f = ((const float2*)src)[i];
    dst[i] = (unsigned)bf16r(f.x) | ((unsigned)bf16r(f.y) << 16);
}

// ---------------------------------------------------------------------------
// deform weights: dw (o,c,kk) fp32 -> dwtb[kk][o][c] bf16
// ---------------------------------------------------------------------------
__global__ void dw_tb(const float* __restrict__ dw, ushort_t* __restrict__ dwtb) {
    int l = blockIdx.x * 256 + threadIdx.x;   // 64*64*9 = 36864
    if (l >= kD * kD * 9) return;
    int o = l / 576;
    int c = (l / 9) % 64;
    int kk = l % 9;
    dwtb[(kk * 64 + o) * 64 + c] = bf16r(dw[l]);
}

// ---------------------------------------------------------------------------
// offset-conv weights: ow (18,64,3,3) fp32 -> owtb[kk][n=32 pad][c=64] bf16
// ---------------------------------------------------------------------------
__global__ void ow_tb(const float* __restrict__ ow, ushort_t* __restrict__ owtb) {
    int l = blockIdx.x * 256 + threadIdx.x;   // 9*32*64 = 18432
    if (l >= 9 * 32 * 64) return;
    int kk = l >> 11;
    int j  = (l >> 6) & 31;
    int c  = l & 63;
    owtb[l] = (j < 18) ? bf16r(ow[j * 576 + c * 9 + kk]) : (ushort_t)0;
}

// ---------------------------------------------------------------------------
// QKV weight pack: W fp32 [n=576][c=192] -> awb[strip s=36][kc=6][lane=64][8]
// ---------------------------------------------------------------------------
__global__ void qw_pack(const float* __restrict__ w, ushort_t* __restrict__ awb) {
    int idx = blockIdx.x * 256 + threadIdx.x;   // 36*6*64 = 13824
    if (idx >= 36 * 6 * 64) return;
    int lane = idx & 63;
    int kc   = (idx >> 6) % 6;
    int s    = idx / 384;
    int row  = s * 16 + (lane & 15);
    int k0   = kc * 32 + (lane >> 4) * 8;
    const float* src = w + (size_t)row * kC + k0;
    ushort_t* dst = awb + (size_t)idx * 8;
#pragma unroll
    for (int j = 0; j < 8; ++j) dst[j] = bf16r(src[j]);
}

// ---------------------------------------------------------------------------
// Kernel 1: QKV projection GEMM, LDS-staged (round-11, verified).
// ---------------------------------------------------------------------------
__global__ __launch_bounds__(256) void qkv_mfma3(const ushort_t* __restrict__ xb,
                                                 const ushort_t* __restrict__ awb,
                                                 ushort_t* __restrict__ qkvpx) {
    __shared__ ushort_t xs[64 * kC];            // 24576 B, swizzled rows of 384 B

    const int tid = threadIdx.x;
    const int bx  = blockIdx.x;
    const int lb  = (bx & 7) * 64 + (bx >> 3);  // XCD swizzle (G=512)
    const int m0  = lb * 64;
    const int ty3 = blockIdx.y;                 // tensor triple: channels [ty3*192, +192)

#pragma unroll
    for (int i = 0; i < 6; ++i) {
        int il = i * 256 + tid;                 // 16B chunk id, 0..1535
        int p  = il / 24;                       // pixel row in strip
        int cc = il % 24;                       // 16B chunk within row
        uint4 v = *(const uint4*)(xb + (size_t)(m0 + p) * kC + cc * 8);
        int dst = p * 384 + ((cc * 16) ^ ((p & 7) << 4));
        *(uint4*)((char*)xs + dst) = v;
    }
    __syncthreads();

    const int lane = tid & 63;
    const int wave = tid >> 6;
    const int l15  = lane & 15;
    const int q    = lane >> 4;
    const int sbase = ty3 * 12 + wave * 3;      // first of 3 N-strips for this wave

    f4v acc[3][4];
#pragma unroll
    for (int i = 0; i < 3; ++i)
#pragma unroll
        for (int m = 0; m < 4; ++m) acc[i][m] = (f4v){0.f, 0.f, 0.f, 0.f};

    const ushort_t* ap = awb + ((size_t)sbase * 6 * 64 + lane) * 8;

#pragma unroll
    for (int kc = 0; kc < 6; ++kc) {
        s8v bfr[4];
#pragma unroll
        for (int m = 0; m < 4; ++m) {
            int row = m * 16 + l15;
            int col = (kc * 64 + q * 16) ^ ((l15 & 7) << 4);
            bfr[m] = *(const s8v*)((const char*)xs + row * 384 + col);
        }
#pragma unroll
        for (int i = 0; i < 3; ++i) {
            s8v a = *(const s8v*)(ap + (size_t)(i * 6 + kc) * 64 * 8);
#pragma unroll
            for (int m = 0; m < 4; ++m)
                acc[i][m] = __builtin_amdgcn_mfma_f32_16x16x32_bf16(a, bfr[m], acc[i][m], 0, 0, 0);
        }
    }

#pragma unroll
    for (int i = 0; i < 3; ++i) {
        int s   = sbase + i;
        int ty  = s >> 2;                       // tensor 0..8
        int c64 = (s & 3) * 16 + q * 4;         // channel within tensor
        ushort_t* obase = qkvpx + (size_t)ty * kM * 64 + (size_t)m0 * 64 + c64;
#pragma unroll
        for (int m = 0; m < 4; ++m) {
            f4v v = acc[i][m];
            uint2 u;
            u.x = (unsigned)bf16r(v.x) | ((unsigned)bf16r(v.y) << 16);
            u.y = (unsigned)bf16r(v.z) | ((unsigned)bf16r(v.w) << 16);
            *(uint2*)(obase + (size_t)(m * 16 + l15) * 64) = u;
        }
    }
}

// ---------------------------------------------------------------------------
// Kernel 2: offsets conv via bf16 MFMA over pixel-major k.
// ---------------------------------------------------------------------------
__global__ __launch_bounds__(256) void off_conv_mfma(const ushort_t* __restrict__ kpx,
                                                     const ushort_t* __restrict__ owtb,
                                                     const float* __restrict__ obias,
                                                     float* __restrict__ offb,
                                                     int dil) {
    const int lb = (blockIdx.x & 7) * 64 + (blockIdx.x >> 3);   // XCD swizzle (G=512)
    const int b = lb >> 6;
    const int y = lb & 63;
    const int tid  = threadIdx.x;
    const int lane = tid & 63;
    const int wave = tid >> 6;
    const int l15  = lane & 15;
    const int q    = lane >> 4;
    const int px   = wave * 16 + l15;

    const ushort_t* inpx = kpx + (size_t)b * kHW * 64 + q * 8;

    f4v acc[2];
    acc[0] = (f4v){0.f, 0.f, 0.f, 0.f};
    acc[1] = (f4v){0.f, 0.f, 0.f, 0.f};

#pragma unroll
    for (int kk = 0; kk < 9; ++kk) {
        const int yy = y + (kk / 3 - 1) * dil;
        const int xx = px + (kk % 3 - 1) * dil;
        const bool valid = (yy >= 0) & (yy < kH) & (xx >= 0) & (xx < kW);
        const size_t idx = valid ? (size_t)(yy * kW + xx) * 64 : 0;
        s8v a0 = *(const s8v*)(inpx + idx);
        s8v a1 = *(const s8v*)(inpx + idx + 32);
        if (!valid) {
            a0 = (s8v){0, 0, 0, 0, 0, 0, 0, 0};
            a1 = (s8v){0, 0, 0, 0, 0, 0, 0, 0};
        }
        const ushort_t* wb = owtb + (size_t)kk * 2048 + l15 * 64 + q * 8;
#pragma unroll
        for (int nbk = 0; nbk < 2; ++nbk) {
            s8v b0 = *(const s8v*)(wb + nbk * 1024);
            s8v b1 = *(const s8v*)(wb + nbk * 1024 + 32);
            acc[nbk] = __builtin_amdgcn_mfma_f32_16x16x32_bf16(a0, b0, acc[nbk], 0, 0, 0);
            acc[nbk] = __builtin_amdgcn_mfma_f32_16x16x32_bf16(a1, b1, acc[nbk], 0, 0, 0);
        }
    }
#pragma unroll
    for (int nbk = 0; nbk < 2; ++nbk) {
        int n = nbk * 16 + l15;
        if (n < 18) {
            float bias = obias[n];
            f4v v = acc[nbk];
            v.x += bias; v.y += bias; v.z += bias; v.w += bias;
            *(f4v*)&offb[((size_t)b * 18 + n) * kHW + y * kW + wave * 16 + q * 4] = v;
        }
    }
}

// ---------------------------------------------------------------------------
// Kernel 3 (round-15 = round-14 with the weight-read swizzle FIXED):
// deformable 3x3 conv, FULLY LDS-resident inner loop.
// Round-14 failed NaN: read side computed (obb*2048 ^ wsw) then ADDED a base
// already containing q*16 — bits 4-6 overlap, carries corrupted the row.
// Fix: col = (q*16 [+64]) ^ wsw computed as a pure XOR within bits 0-6, then
// added to kk*8192 + obb*2048 + l15*128 (bits >=7, no overlap).
// Theory (unchanged, untested): deform duration was invariant at ~69us across
// 3 memory designs; the shared invariant is the per-tap GLOBAL weight stream
// (576 VMEM instrs/block, 72KB set thrashing 32KB L1). Staging dwtb in LDS
// makes the tap loop zero-VMEM.
// ---------------------------------------------------------------------------
template<int DIL>
__global__ __launch_bounds__(512) void deform_lds(const ushort_t* __restrict__ kpx,
                                                  const ushort_t* __restrict__ vpx,
                                                  const float* __restrict__ offb,
                                                  const ushort_t* __restrict__ dwtb,
                                                  const float* __restrict__ db,
                                                  ushort_t* __restrict__ outkpx,
                                                  ushort_t* __restrict__ outvpx) {
    constexpr int NR = 2 * DIL + 4;         // staged rows (|oy|<1 window)
    __shared__ ushort_t kv[NR * 4096];      // NR x 8192 B, swizzled
    __shared__ ushort_t wlds[9 * 4096];     // 73728 B: dwtb copy, swizzled

    const int tid = threadIdx.x;
    const int bx  = blockIdx.x;
    const int lb  = (bx & 7) * 64 + (bx >> 3);  // XCD swizzle (G=512)
    const int t   = lb >> 8;                // 0 = k, 1 = v
    const int b   = (lb >> 5) & 7;
    const int y0  = (lb & 31) * 2;          // first of 2 output rows
    const int wlo = y0 - DIL - 1;           // staged window start (may be <0)

    const ushort_t* inb = (t ? vpx : kpx) + (size_t)b * kHW * 64;
    ushort_t* outp = t ? outvpx : outkpx;

    // ---- stage weights: 9 x 512 x 16B, linear->row-swizzled ----
    // element (kk, row, c_byte) lands at kk*8192 + row*128 + (c_byte ^ ((row&7)<<4))
#pragma unroll
    for (int i = 0; i < 9; ++i) {
        int g = (i * 512 + tid) * 16;            // linear byte offset
        uint4 v = *(const uint4*)((const char*)dwtb + g);
        int row = (g >> 7) & 63;                 // o-row within kk tile
        int dst = g ^ ((row & 7) << 4);
        *(uint4*)((char*)wlds + dst) = v;
    }
    // ---- stage NR kv rows, coalesced 16B/thread, swizzled ----
#pragma unroll
    for (int r = 0; r < NR; ++r) {
        int gy = min(max(wlo + r, 0), kH - 1);
        uint4 v = *(const uint4*)(inb + (size_t)gy * 4096 + tid * 8);
        int x  = tid >> 3;
        int cc = tid & 7;
        int dst = r * 8192 + ((x * 128 + cc * 16) ^ ((x & 7) << 4));
        *(uint4*)((char*)kv + dst) = v;
    }
    __syncthreads();

    const int lane = tid & 63;
    const int wave = tid >> 6;          // 0..7
    const int ry   = wave >> 2;         // output row within pair
    const int wc   = wave & 3;          // px column
    const int l15  = lane & 15;
    const int q    = lane >> 4;
    const int y    = y0 + ry;
    const int px   = wc * 16 + l15;
    const int wsw  = (l15 & 7) << 4;    // weight-read swizzle bits (row&7 == l15&7)
    const int wcol0 = (q * 16) ^ wsw;        // swizzled column, low half  (0..127)
    const int wcol1 = (q * 16 + 64) ^ wsw;   // swizzled column, high half (0..127)

    const ushort_t* inpx = inb + q * 8; // global fallback base

    f4v acc[4];
#pragma unroll
    for (int ob = 0; ob < 4; ++ob) acc[ob] = (f4v){0.f, 0.f, 0.f, 0.f};

    // prefetch all 18 offset channels for my pixel
    const float* offrow = offb + (size_t)b * 18 * kHW + y * kW + px;
    float offv[18];
#pragma unroll
    for (int i = 0; i < 18; ++i) offv[i] = offrow[(size_t)i * kHW];

#pragma unroll
    for (int kk = 0; kk < 9; ++kk) {
        float oy = offv[kk * 2 + 0];
        float ox = offv[kk * 2 + 1];
        float py  = (float)y  + (float)((kk / 3 - 1) * DIL) + oy;
        float pxf = (float)px + (float)((kk % 3 - 1) * DIL) + ox;
        float fy = floorf(py), fx = floorf(pxf);
        float wy = py - fy, wx = pxf - fx;
        int iy0 = (int)fy, ix0 = (int)fx;
        int iy1 = iy0 + 1, ix1 = ix0 + 1;
        int y0c = min(max(iy0, 0), kH - 1), x0c = min(max(ix0, 0), kW - 1);
        int y1c = min(max(iy1, 0), kH - 1), x1c = min(max(ix1, 0), kW - 1);
        bool vy0 = (iy0 >= 0) & (iy0 < kH), vx0 = (ix0 >= 0) & (ix0 < kW);
        bool vy1 = (iy1 >= 0) & (iy1 < kH), vx1 = (ix1 >= 0) & (ix1 < kW);
        float w0 = (vy0 && vx0) ? (1.f - wy) * (1.f - wx) : 0.f;
        float w1 = (vy0 && vx1) ? (1.f - wy) * wx : 0.f;
        float w2 = (vy1 && vx0) ? wy * (1.f - wx) : 0.f;
        float w3 = (vy1 && vx1) ? wy * wx : 0.f;

        s8v c[8];
        if (__builtin_expect(fabsf(oy) < 1.0f, 1)) {
            // LDS fast path: |oy|<1 guarantees rows inside the staged window
            int r0 = min(max(y0c - wlo, 0), NR - 1);
            int r1 = min(max(y1c - wlo, 0), NR - 1);
            int b00 = r0 * 8192 + ((x0c * 128 + q * 16) ^ ((x0c & 7) << 4));
            int b00h = r0 * 8192 + ((x0c * 128 + q * 16 + 64) ^ ((x0c & 7) << 4));
            int b01 = r0 * 8192 + ((x1c * 128 + q * 16) ^ ((x1c & 7) << 4));
            int b01h = r0 * 8192 + ((x1c * 128 + q * 16 + 64) ^ ((x1c & 7) << 4));
            int b10 = r1 * 8192 + ((x0c * 128 + q * 16) ^ ((x0c & 7) << 4));
            int b10h = r1 * 8192 + ((x0c * 128 + q * 16 + 64) ^ ((x0c & 7) << 4));
            int b11 = r1 * 8192 + ((x1c * 128 + q * 16) ^ ((x1c & 7) << 4));
            int b11h = r1 * 8192 + ((x1c * 128 + q * 16 + 64) ^ ((x1c & 7) << 4));
            c[0] = *(const s8v*)((const char*)kv + b00);
            c[1] = *(const s8v*)((const char*)kv + b00h);
            c[2] = *(const s8v*)((const char*)kv + b01);
            c[3] = *(const s8v*)((const char*)kv + b01h);
            c[4] = *(const s8v*)((const char*)kv + b10);
            c[5] = *(const s8v*)((const char*)kv + b10h);
            c[6] = *(const s8v*)((const char*)kv + b11);
            c[7] = *(const s8v*)((const char*)kv + b11h);
        } else {
            // exact global fallback (cold for this data, exact for any data)
            size_t i00 = (size_t)(y0c * kW + x0c) * 64;
            size_t i01 = (size_t)(y0c * kW + x1c) * 64;
            size_t i10 = (size_t)(y1c * kW + x0c) * 64;
            size_t i11 = (size_t)(y1c * kW + x1c) * 64;
            c[0] = *(const s8v*)(inpx + i00);
            c[1] = *(const s8v*)(inpx + i00 + 32);
            c[2] = *(const s8v*)(inpx + i01);
            c[3] = *(const s8v*)(inpx + i01 + 32);
            c[4] = *(const s8v*)(inpx + i10);
            c[5] = *(const s8v*)(inpx + i10 + 32);
            c[6] = *(const s8v*)(inpx + i11);
            c[7] = *(const s8v*)(inpx + i11 + 32);
        }

        s8v b0, b1;
#pragma unroll
        for (int j = 0; j < 8; ++j) {
            float v0 = w0 * bfu(c[0][j]) + w1 * bfu(c[2][j]) +
                       w2 * bfu(c[4][j]) + w3 * bfu(c[6][j]);
            float v1 = w0 * bfu(c[1][j]) + w1 * bfu(c[3][j]) +
                       w2 * bfu(c[5][j]) + w3 * bfu(c[7][j]);
            b0[j] = (short)bf16r(v0);
            b1[j] = (short)bf16r(v1);
        }
        // A-frags from LDS weights: row = obb*16 + l15, swizzled column
        const char* wkk = (const char*)wlds + kk * 8192 + l15 * 128;
#pragma unroll
        for (int obb = 0; obb < 4; ++obb) {
            s8v a0w = *(const s8v*)(wkk + obb * 2048 + wcol0);
            s8v a1w = *(const s8v*)(wkk + obb * 2048 + wcol1);
            acc[obb] = __builtin_amdgcn_mfma_f32_16x16x32_bf16(a0w, b0, acc[obb], 0, 0, 0);
            acc[obb] = __builtin_amdgcn_mfma_f32_16x16x32_bf16(a1w, b1, acc[obb], 0, 0, 0);
        }
    }

    // store: lane holds o = obb*16 + q*4 + reg at pixel px -> bf16 pixel-major
    ushort_t* orow = outp + ((size_t)b * kHW + y * kW + px) * 64 + q * 4;
#pragma unroll
    for (int obb = 0; obb < 4; ++obb) {
        float4 bias = *(const float4*)&db[obb * 16 + q * 4];
        f4v v = acc[obb];
        uint2 u;
        u.x = (unsigned)bf16r(v.x + bias.x) | ((unsigned)bf16r(v.y + bias.y) << 16);
        u.y = (unsigned)bf16r(v.z + bias.z) | ((unsigned)bf16r(v.w + bias.w) << 16);
        *(uint2*)(orow + obb * 16) = u;
    }
}

// ---------------------------------------------------------------------------
// Kernel 4: 9-tap local attention, bf16 pixel-major q/k/v (round-12 form).
// ---------------------------------------------------------------------------
__global__ __launch_bounds__(256) void attn_px(const ushort_t* __restrict__ qpx,
                                               const ushort_t* __restrict__ kpx,
                                               const ushort_t* __restrict__ vpx,
                                               ushort_t* __restrict__ aopx,
                                               int branch, int dil) {
    const int lb = (blockIdx.x & 7) * 128 + (blockIdx.x >> 3);  // XCD swizzle (G=1024)
    const int b    = lb >> 7;
    const int y    = (lb >> 1) & 63;
    const int half = lb & 1;
    const int tid  = threadIdx.x;
    const int wave = tid >> 6;
    const int l    = tid & 63;
    const int pxq  = l >> 3;          // 8 pixels per wave
    const int cg   = l & 7;           // 8 channel-groups of 8 ch
    const int x = half * 32 + wave * 8 + pxq;
    const int p = y * kW + x;
    const size_t pbase = (size_t)b * kHW;

    const ushort_t* qb = qpx + (pbase + p) * 64 + cg * 8;
    s8v q0 = *(const s8v*)qb;
    float qf[8];
#pragma unroll
    for (int j = 0; j < 8; ++j) qf[j] = bfu(q0[j]);

    int offs[9]; float msk[9];
#pragma unroll
    for (int kk = 0; kk < 9; ++kk) {
        int dy = (kk / 3 - 1) * dil, dx = (kk % 3 - 1) * dil;
        int yy = y + dy, xx = x + dx;
        bool v = (yy >= 0) & (yy < kH) & (xx >= 0) & (xx < kW);
        offs[kk] = v ? (p + dy * kW + dx) : p;
        msk[kk] = v ? 1.f : 0.f;
    }
    float e[9];
#pragma unroll
    for (int kk = 0; kk < 9; ++kk) {
        const ushort_t* kp = kpx + (pbase + offs[kk]) * 64 + cg * 8;
        s8v k0 = *(const s8v*)kp;
        float s = 0.f;
#pragma unroll
        for (int j = 0; j < 8; ++j) s += qf[j] * bfu(k0[j]);
        s += __shfl_xor(s, 1);
        s += __shfl_xor(s, 2);
        s += __shfl_xor(s, 4);
        e[kk] = s * 0.125f * msk[kk];
    }
    float mx = -1e30f;
#pragma unroll
    for (int kk = 0; kk < 9; ++kk) mx = fmaxf(mx, e[kk]);
    float ssum = 0.f;
#pragma unroll
    for (int kk = 0; kk < 9; ++kk) { e[kk] = __expf(e[kk] - mx); ssum += e[kk]; }
    float inv = 1.f / ssum;
#pragma unroll
    for (int kk = 0; kk < 9; ++kk) e[kk] = e[kk] * inv * msk[kk];

    float acc[8];
#pragma unroll
    for (int j = 0; j < 8; ++j) acc[j] = 0.f;
#pragma unroll
    for (int kk = 0; kk < 9; ++kk) {
        const ushort_t* vp = vpx + (pbase + offs[kk]) * 64 + cg * 8;
        s8v v0 = *(const s8v*)vp;
        float w = e[kk];
#pragma unroll
        for (int j = 0; j < 8; ++j) acc[j] += w * bfu(v0[j]);
    }
    unsigned u[4];
#pragma unroll
    for (int i = 0; i < 4; ++i)
        u[i] = (unsigned)bf16r(acc[2 * i]) | ((unsigned)bf16r(acc[2 * i + 1]) << 16);
    ushort_t* ob = aopx + (pbase + p) * kC + branch * 64 + cg * 8;
    *(uint4*)ob = make_uint4(u[0], u[1], u[2], u[3]);
}

// ---------------------------------------------------------------------------
// Kernel 5: output projection via bf16 MFMA on pixel-major ao.
// ---------------------------------------------------------------------------
__global__ __launch_bounds__(256) void proj_mfma(const ushort_t* __restrict__ aopx,
                                                 const ushort_t* __restrict__ pwb,
                                                 const float* __restrict__ pb,
                                                 float* __restrict__ out) {
    const int tid  = threadIdx.x;
    const int lane = tid & 63;
    const int wave = tid >> 6;
    const int l15  = lane & 15;
    const int q    = lane >> 4;
    const int m0   = blockIdx.x * 64;
    const int nb   = blockIdx.y * 64 + wave * 16;

    f4v acc[4];
#pragma unroll
    for (int ob = 0; ob < 4; ++ob) acc[ob] = (f4v){0.f, 0.f, 0.f, 0.f};

    const ushort_t* aw = pwb + (size_t)(nb + l15) * kC + q * 8;
    const ushort_t* bx = aopx + (size_t)(m0 + l15) * kC + q * 8;
#pragma unroll
    for (int kc = 0; kc < 6; ++kc) {
        s8v a = *(const s8v*)(aw + kc * 32);
#pragma unroll
        for (int ob = 0; ob < 4; ++ob) {
            s8v b = *(const s8v*)(bx + (size_t)(ob * 16) * kC + kc * 32);
            acc[ob] = __builtin_amdgcn_mfma_f32_16x16x32_bf16(a, b, acc[ob], 0, 0, 0);
        }
    }
    float4 bias = *(const float4*)&pb[nb + q * 4];
#pragma unroll
    for (int ob = 0; ob < 4; ++ob) {
        int m = m0 + ob * 16 + l15;
        f4v v = acc[ob];
        v.x += bias.x; v.y += bias.y; v.z += bias.z; v.w += bias.w;
        *(f4v*)&out[(size_t)m * kC + nb + q * 4] = v;
    }
}

// ---------------------------------------------------------------------------
// Host launcher.  Workspace (~63 MB, well under the proven 120 MB).
// ---------------------------------------------------------------------------
extern "C" void kernel_launch(void* const* d_in, const int* in_sizes, int n_in,
                              void* d_out, int out_size, void* d_ws, size_t ws_size,
                              hipStream_t stream) {
    const float* x      = (const float*)d_in[0];
    const float* qkv_w  = (const float*)d_in[1];
    const float* proj_w = (const float*)d_in[2];
    const float* proj_b = (const float*)d_in[3];
    const float* off_w2 = (const float*)d_in[4];
    const float* off_b2 = (const float*)d_in[5];
    const float* def_w2 = (const float*)d_in[6];
    const float* def_b2 = (const float*)d_in[7];
    const float* off_w3 = (const float*)d_in[8];
    const float* off_b3 = (const float*)d_in[9];
    const float* def_w3 = (const float*)d_in[10];
    const float* def_b3 = (const float*)d_in[11];
    float* out = (float*)d_out;

    float* ws   = (float*)d_ws;
    float* offb = ws;                               // 18 * M
    ushort_t* us = (ushort_t*)(offb + (size_t)18 * kM);
    ushort_t* xb     = us;  us += (size_t)kM * kC;
    ushort_t* qkvpx  = us;  us += (size_t)9 * kM * 64;
    ushort_t* kdpx   = us;  us += (size_t)kM * 64;
    ushort_t* vdpx   = us;  us += (size_t)kM * 64;
    ushort_t* aopx   = us;  us += (size_t)kM * kC;
    ushort_t* awb    = us;  us += (size_t)kNQKV * kC;   // 36*6*64*8 == 576*192
    ushort_t* pwb    = us;  us += (size_t)kC * kC;
    ushort_t* dwtb2  = us;  us += kD * kD * 9;
    ushort_t* dwtb3  = us;  us += kD * kD * 9;
    ushort_t* owtb2  = us;  us += 9 * 32 * 64;
    ushort_t* owtb3  = us;  us += 9 * 32 * 64;

    // 0. bf16 conversions and weight transposes/packs
    cvt_bf16<<<(kM * kC / 2 + 255) / 256, 256, 0, stream>>>(x, (unsigned*)xb, kM * kC / 2);
    qw_pack<<<54, 256, 0, stream>>>(qkv_w, awb);
    cvt_bf16<<<(kC * kC / 2 + 255) / 256, 256, 0, stream>>>(proj_w, (unsigned*)pwb, kC * kC / 2);
    dw_tb<<<144, 256, 0, stream>>>(def_w2, dwtb2);
    dw_tb<<<144, 256, 0, stream>>>(def_w3, dwtb3);
    ow_tb<<<72, 256, 0, stream>>>(off_w2, owtb2);
    ow_tb<<<72, 256, 0, stream>>>(off_w3, owtb3);

    // per-tensor pixel-major slices
    ushort_t* q0 = qkvpx;
    ushort_t* q1 = qkvpx + (size_t)1 * kM * 64;
    ushort_t* q2 = qkvpx + (size_t)2 * kM * 64;
    ushort_t* k0 = qkvpx + (size_t)3 * kM * 64;
    ushort_t* k1 = qkvpx + (size_t)4 * kM * 64;
    ushort_t* k2 = qkvpx + (size_t)5 * kM * 64;
    ushort_t* v0 = qkvpx + (size_t)6 * kM * 64;
    ushort_t* v1 = qkvpx + (size_t)7 * kM * 64;
    ushort_t* v2 = qkvpx + (size_t)8 * kM * 64;

    // 1. QKV projection -> 9 bf16 pixel-major tensors (LDS-staged GEMM)
    qkv_mfma3<<<dim3(kM / 64, 3), 256, 0, stream>>>(xb, awb, qkvpx);

    // 2. branch 0 (dil=1)
    attn_px<<<kB * kH * 2, 256, 0, stream>>>(q0, k0, v0, aopx, 0, 1);

    // 3. branch 1 (dil=2)
    off_conv_mfma<<<512, 256, 0, stream>>>(k1, owtb2, off_b2, offb, 2);
    deform_lds<2><<<512, 512, 0, stream>>>(k1, v1, offb, dwtb2, def_b2, kdpx, vdpx);
    attn_px<<<kB * kH * 2, 256, 0, stream>>>(q1, kdpx, vdpx, aopx, 1, 2);

    // 4. branch 2 (dil=3)
    off_conv_mfma<<<512, 256, 0, stream>>>(k2, owtb3, off_b3, offb, 3);
    deform_lds<3><<<512, 512, 0, stream>>>(k2, v2, offb, dwtb3, def_b3, kdpx, vdpx);
    attn_px<<<kB * kH * 2, 256, 0, stream>>>(q2, kdpx, vdpx, aopx, 2, 3);

    // 5. output projection (bf16 MFMA, fp32 out)
    proj_mfma<<<dim3(kM / 64, 3), 256, 0, stream>>>(aopx, pwb, proj_b, out);
}

// Round 7
// 231.077 us; speedup vs baseline: 1.4446x; 1.1041x over previous
//
#include <hip/hip_runtime.h>
#include <cmath>

// ---------------------------------------------------------------------------
// Problem constants (B=8, H=W=64, C=192, 3 dilation branches of d=64, heads=64)
// ---------------------------------------------------------------------------
#define kB    8
#define kH    64
#define kW    64
#define kHW   4096          // H*W
#define kC    192
#define kD    64            // channels per dilation branch == head_dim
#define kM    (kB * kHW)    // 32768 total pixels
#define kNQKV 576           // 3*C

typedef unsigned short ushort_t;
typedef __attribute__((ext_vector_type(8))) short  s8v;   // 8 bf16 (4 VGPRs)
typedef __attribute__((ext_vector_type(4))) float  f4v;   // MFMA C/D frag

__device__ inline unsigned short bf16r(float f) {   // round-to-nearest-even
    union { float f; unsigned u; } v; v.f = f;
    unsigned u = v.u + 0x7FFFu + ((v.u >> 16) & 1u);
    return (unsigned short)(u >> 16);
}
__device__ inline float bfu(short s) {              // bf16 -> fp32
    union { unsigned u; float f; } v;
    v.u = ((unsigned)(unsigned short)s) << 16;
    return v.f;
}

// ---------------------------------------------------------------------------
// fp32 -> bf16 pairwise converter (x only; weight packs are fused below)
// ---------------------------------------------------------------------------
__global__ void cvt_bf16(const float* __restrict__ src, unsigned* __restrict__ dst, int n2) {
    int i = blockIdx.x * 256 + threadIdx.x;
    if (i >= n2) return;
    float2 f = ((const float2*)src)[i];
    dst[i] = (unsigned)bf16r(f.x) | ((unsigned)bf16r(f.y) << 16);
}

// ---------------------------------------------------------------------------
// prep_all (round-16): all weight conversions/packs in ONE dispatch.
// Segments by blockIdx.x:
//   [  0, 54): qw_pack   qkv_w   -> awb  [s=36][kc=6][lane][8]
//   [ 54, 72): pw_pack   proj_w  -> pwbp [s=12][kc=6][lane][8]
//   [ 72,216): dw_tb     def_w2  -> dwtb2[kk][o][c]
//   [216,360): dw_tb     def_w3  -> dwtb3[kk][o][c]
//   [360,432): ow_tb     off_w2  -> owtb2[kk][n32][c]
//   [432,504): ow_tb     off_w3  -> owtb3[kk][n32][c]
// ---------------------------------------------------------------------------
__global__ void prep_all(const float* __restrict__ qkv_w,
                         const float* __restrict__ proj_w,
                         const float* __restrict__ def_w2,
                         const float* __restrict__ def_w3,
                         const float* __restrict__ off_w2,
                         const float* __restrict__ off_w3,
                         ushort_t* __restrict__ awb,
                         ushort_t* __restrict__ pwbp,
                         ushort_t* __restrict__ dwtb2,
                         ushort_t* __restrict__ dwtb3,
                         ushort_t* __restrict__ owtb2,
                         ushort_t* __restrict__ owtb3) {
    const int bid = blockIdx.x;
    const int tid = threadIdx.x;
    if (bid < 54) {                       // qw_pack
        int idx = bid * 256 + tid;        // 36*6*64 = 13824
        if (idx >= 36 * 6 * 64) return;
        int lane = idx & 63;
        int kc   = (idx >> 6) % 6;
        int s    = idx / 384;
        int row  = s * 16 + (lane & 15);
        int k0   = kc * 32 + (lane >> 4) * 8;
        const float* src = qkv_w + (size_t)row * kC + k0;
        ushort_t* dst = awb + (size_t)idx * 8;
#pragma unroll
        for (int j = 0; j < 8; ++j) dst[j] = bf16r(src[j]);
    } else if (bid < 72) {                // pw_pack
        int idx = (bid - 54) * 256 + tid; // 12*6*64 = 4608
        if (idx >= 12 * 6 * 64) return;
        int lane = idx & 63;
        int kc   = (idx >> 6) % 6;
        int s    = idx / 384;
        int row  = s * 16 + (lane & 15);
        int k0   = kc * 32 + (lane >> 4) * 8;
        const float* src = proj_w + (size_t)row * kC + k0;
        ushort_t* dst = pwbp + (size_t)idx * 8;
#pragma unroll
        for (int j = 0; j < 8; ++j) dst[j] = bf16r(src[j]);
    } else if (bid < 360) {               // dw_tb x2
        const float* dw = (bid < 216) ? def_w2 : def_w3;
        ushort_t* dwtb  = (bid < 216) ? dwtb2 : dwtb3;
        int l = ((bid < 216) ? (bid - 72) : (bid - 216)) * 256 + tid;  // 36864
        if (l >= kD * kD * 9) return;
        int o = l / 576;
        int c = (l / 9) % 64;
        int kk = l % 9;
        dwtb[(kk * 64 + o) * 64 + c] = bf16r(dw[l]);
    } else {                              // ow_tb x2
        const float* ow = (bid < 432) ? off_w2 : off_w3;
        ushort_t* owtb  = (bid < 432) ? owtb2 : owtb3;
        int l = ((bid < 432) ? (bid - 360) : (bid - 432)) * 256 + tid; // 18432
        if (l >= 9 * 32 * 64) return;
        int kk = l >> 11;
        int j  = (l >> 6) & 31;
        int c  = l & 63;
        owtb[l] = (j < 18) ? bf16r(ow[j * 576 + c * 9 + kk]) : (ushort_t)0;
    }
}

// ---------------------------------------------------------------------------
// Kernel 1: QKV projection GEMM, LDS-staged (round-11, verified).
// ---------------------------------------------------------------------------
__global__ __launch_bounds__(256) void qkv_mfma3(const ushort_t* __restrict__ xb,
                                                 const ushort_t* __restrict__ awb,
                                                 ushort_t* __restrict__ qkvpx) {
    __shared__ ushort_t xs[64 * kC];            // 24576 B, swizzled rows of 384 B

    const int tid = threadIdx.x;
    const int bx  = blockIdx.x;
    const int lb  = (bx & 7) * 64 + (bx >> 3);  // XCD swizzle (G=512)
    const int m0  = lb * 64;
    const int ty3 = blockIdx.y;                 // tensor triple: channels [ty3*192, +192)

#pragma unroll
    for (int i = 0; i < 6; ++i) {
        int il = i * 256 + tid;                 // 16B chunk id, 0..1535
        int p  = il / 24;                       // pixel row in strip
        int cc = il % 24;                       // 16B chunk within row
        uint4 v = *(const uint4*)(xb + (size_t)(m0 + p) * kC + cc * 8);
        int dst = p * 384 + ((cc * 16) ^ ((p & 7) << 4));
        *(uint4*)((char*)xs + dst) = v;
    }
    __syncthreads();

    const int lane = tid & 63;
    const int wave = tid >> 6;
    const int l15  = lane & 15;
    const int q    = lane >> 4;
    const int sbase = ty3 * 12 + wave * 3;      // first of 3 N-strips for this wave

    f4v acc[3][4];
#pragma unroll
    for (int i = 0; i < 3; ++i)
#pragma unroll
        for (int m = 0; m < 4; ++m) acc[i][m] = (f4v){0.f, 0.f, 0.f, 0.f};

    const ushort_t* ap = awb + ((size_t)sbase * 6 * 64 + lane) * 8;

#pragma unroll
    for (int kc = 0; kc < 6; ++kc) {
        s8v bfr[4];
#pragma unroll
        for (int m = 0; m < 4; ++m) {
            int row = m * 16 + l15;
            int col = (kc * 64 + q * 16) ^ ((l15 & 7) << 4);
            bfr[m] = *(const s8v*)((const char*)xs + row * 384 + col);
        }
#pragma unroll
        for (int i = 0; i < 3; ++i) {
            s8v a = *(const s8v*)(ap + (size_t)(i * 6 + kc) * 64 * 8);
#pragma unroll
            for (int m = 0; m < 4; ++m)
                acc[i][m] = __builtin_amdgcn_mfma_f32_16x16x32_bf16(a, bfr[m], acc[i][m], 0, 0, 0);
        }
    }

#pragma unroll
    for (int i = 0; i < 3; ++i) {
        int s   = sbase + i;
        int ty  = s >> 2;                       // tensor 0..8
        int c64 = (s & 3) * 16 + q * 4;         // channel within tensor
        ushort_t* obase = qkvpx + (size_t)ty * kM * 64 + (size_t)m0 * 64 + c64;
#pragma unroll
        for (int m = 0; m < 4; ++m) {
            f4v v = acc[i][m];
            uint2 u;
            u.x = (unsigned)bf16r(v.x) | ((unsigned)bf16r(v.y) << 16);
            u.y = (unsigned)bf16r(v.z) | ((unsigned)bf16r(v.w) << 16);
            *(uint2*)(obase + (size_t)(m * 16 + l15) * 64) = u;
        }
    }
}

// ---------------------------------------------------------------------------
// Kernel 2: offsets conv via bf16 MFMA over pixel-major k.
// ---------------------------------------------------------------------------
__global__ __launch_bounds__(256) void off_conv_mfma(const ushort_t* __restrict__ kpx,
                                                     const ushort_t* __restrict__ owtb,
                                                     const float* __restrict__ obias,
                                                     float* __restrict__ offb,
                                                     int dil) {
    const int lb = (blockIdx.x & 7) * 64 + (blockIdx.x >> 3);   // XCD swizzle (G=512)
    const int b = lb >> 6;
    const int y = lb & 63;
    const int tid  = threadIdx.x;
    const int lane = tid & 63;
    const int wave = tid >> 6;
    const int l15  = lane & 15;
    const int q    = lane >> 4;
    const int px   = wave * 16 + l15;

    const ushort_t* inpx = kpx + (size_t)b * kHW * 64 + q * 8;

    f4v acc[2];
    acc[0] = (f4v){0.f, 0.f, 0.f, 0.f};
    acc[1] = (f4v){0.f, 0.f, 0.f, 0.f};

#pragma unroll
    for (int kk = 0; kk < 9; ++kk) {
        const int yy = y + (kk / 3 - 1) * dil;
        const int xx = px + (kk % 3 - 1) * dil;
        const bool valid = (yy >= 0) & (yy < kH) & (xx >= 0) & (xx < kW);
        const size_t idx = valid ? (size_t)(yy * kW + xx) * 64 : 0;
        s8v a0 = *(const s8v*)(inpx + idx);
        s8v a1 = *(const s8v*)(inpx + idx + 32);
        if (!valid) {
            a0 = (s8v){0, 0, 0, 0, 0, 0, 0, 0};
            a1 = (s8v){0, 0, 0, 0, 0, 0, 0, 0};
        }
        const ushort_t* wb = owtb + (size_t)kk * 2048 + l15 * 64 + q * 8;
#pragma unroll
        for (int nbk = 0; nbk < 2; ++nbk) {
            s8v b0 = *(const s8v*)(wb + nbk * 1024);
            s8v b1 = *(const s8v*)(wb + nbk * 1024 + 32);
            acc[nbk] = __builtin_amdgcn_mfma_f32_16x16x32_bf16(a0, b0, acc[nbk], 0, 0, 0);
            acc[nbk] = __builtin_amdgcn_mfma_f32_16x16x32_bf16(a1, b1, acc[nbk], 0, 0, 0);
        }
    }
#pragma unroll
    for (int nbk = 0; nbk < 2; ++nbk) {
        int n = nbk * 16 + l15;
        if (n < 18) {
            float bias = obias[n];
            f4v v = acc[nbk];
            v.x += bias; v.y += bias; v.z += bias; v.w += bias;
            *(f4v*)&offb[((size_t)b * 18 + n) * kHW + y * kW + wave * 16 + q * 4] = v;
        }
    }
}

// ---------------------------------------------------------------------------
// Kernel 3 (round-15, verified PASS at 255us total): deformable 3x3 conv,
// fully LDS-resident inner loop (kv window + weights staged, zero VMEM in
// tap loop). UNCHANGED this round (control).
// ---------------------------------------------------------------------------
template<int DIL>
__global__ __launch_bounds__(512) void deform_lds(const ushort_t* __restrict__ kpx,
                                                  const ushort_t* __restrict__ vpx,
                                                  const float* __restrict__ offb,
                                                  const ushort_t* __restrict__ dwtb,
                                                  const float* __restrict__ db,
                                                  ushort_t* __restrict__ outkpx,
                                                  ushort_t* __restrict__ outvpx) {
    constexpr int NR = 2 * DIL + 4;         // staged rows (|oy|<1 window)
    __shared__ ushort_t kv[NR * 4096];      // NR x 8192 B, swizzled
    __shared__ ushort_t wlds[9 * 4096];     // 73728 B: dwtb copy, swizzled

    const int tid = threadIdx.x;
    const int bx  = blockIdx.x;
    const int lb  = (bx & 7) * 64 + (bx >> 3);  // XCD swizzle (G=512)
    const int t   = lb >> 8;                // 0 = k, 1 = v
    const int b   = (lb >> 5) & 7;
    const int y0  = (lb & 31) * 2;          // first of 2 output rows
    const int wlo = y0 - DIL - 1;           // staged window start (may be <0)

    const ushort_t* inb = (t ? vpx : kpx) + (size_t)b * kHW * 64;
    ushort_t* outp = t ? outvpx : outkpx;

    // ---- stage weights: 9 x 512 x 16B, linear->row-swizzled ----
#pragma unroll
    for (int i = 0; i < 9; ++i) {
        int g = (i * 512 + tid) * 16;            // linear byte offset
        uint4 v = *(const uint4*)((const char*)dwtb + g);
        int row = (g >> 7) & 63;                 // o-row within kk tile
        int dst = g ^ ((row & 7) << 4);
        *(uint4*)((char*)wlds + dst) = v;
    }
    // ---- stage NR kv rows, coalesced 16B/thread, swizzled ----
#pragma unroll
    for (int r = 0; r < NR; ++r) {
        int gy = min(max(wlo + r, 0), kH - 1);
        uint4 v = *(const uint4*)(inb + (size_t)gy * 4096 + tid * 8);
        int x  = tid >> 3;
        int cc = tid & 7;
        int dst = r * 8192 + ((x * 128 + cc * 16) ^ ((x & 7) << 4));
        *(uint4*)((char*)kv + dst) = v;
    }
    __syncthreads();

    const int lane = tid & 63;
    const int wave = tid >> 6;          // 0..7
    const int ry   = wave >> 2;         // output row within pair
    const int wc   = wave & 3;          // px column
    const int l15  = lane & 15;
    const int q    = lane >> 4;
    const int y    = y0 + ry;
    const int px   = wc * 16 + l15;
    const int wsw  = (l15 & 7) << 4;    // weight-read swizzle bits (row&7 == l15&7)
    const int wcol0 = (q * 16) ^ wsw;        // swizzled column, low half  (0..127)
    const int wcol1 = (q * 16 + 64) ^ wsw;   // swizzled column, high half (0..127)

    const ushort_t* inpx = inb + q * 8; // global fallback base

    f4v acc[4];
#pragma unroll
    for (int ob = 0; ob < 4; ++ob) acc[ob] = (f4v){0.f, 0.f, 0.f, 0.f};

    // prefetch all 18 offset channels for my pixel
    const float* offrow = offb + (size_t)b * 18 * kHW + y * kW + px;
    float offv[18];
#pragma unroll
    for (int i = 0; i < 18; ++i) offv[i] = offrow[(size_t)i * kHW];

#pragma unroll
    for (int kk = 0; kk < 9; ++kk) {
        float oy = offv[kk * 2 + 0];
        float ox = offv[kk * 2 + 1];
        float py  = (float)y  + (float)((kk / 3 - 1) * DIL) + oy;
        float pxf = (float)px + (float)((kk % 3 - 1) * DIL) + ox;
        float fy = floorf(py), fx = floorf(pxf);
        float wy = py - fy, wx = pxf - fx;
        int iy0 = (int)fy, ix0 = (int)fx;
        int iy1 = iy0 + 1, ix1 = ix0 + 1;
        int y0c = min(max(iy0, 0), kH - 1), x0c = min(max(ix0, 0), kW - 1);
        int y1c = min(max(iy1, 0), kH - 1), x1c = min(max(ix1, 0), kW - 1);
        bool vy0 = (iy0 >= 0) & (iy0 < kH), vx0 = (ix0 >= 0) & (ix0 < kW);
        bool vy1 = (iy1 >= 0) & (iy1 < kH), vx1 = (ix1 >= 0) & (ix1 < kW);
        float w0 = (vy0 && vx0) ? (1.f - wy) * (1.f - wx) : 0.f;
        float w1 = (vy0 && vx1) ? (1.f - wy) * wx : 0.f;
        float w2 = (vy1 && vx0) ? wy * (1.f - wx) : 0.f;
        float w3 = (vy1 && vx1) ? wy * wx : 0.f;

        s8v c[8];
        if (__builtin_expect(fabsf(oy) < 1.0f, 1)) {
            // LDS fast path: |oy|<1 guarantees rows inside the staged window
            int r0 = min(max(y0c - wlo, 0), NR - 1);
            int r1 = min(max(y1c - wlo, 0), NR - 1);
            int b00 = r0 * 8192 + ((x0c * 128 + q * 16) ^ ((x0c & 7) << 4));
            int b00h = r0 * 8192 + ((x0c * 128 + q * 16 + 64) ^ ((x0c & 7) << 4));
            int b01 = r0 * 8192 + ((x1c * 128 + q * 16) ^ ((x1c & 7) << 4));
            int b01h = r0 * 8192 + ((x1c * 128 + q * 16 + 64) ^ ((x1c & 7) << 4));
            int b10 = r1 * 8192 + ((x0c * 128 + q * 16) ^ ((x0c & 7) << 4));
            int b10h = r1 * 8192 + ((x0c * 128 + q * 16 + 64) ^ ((x0c & 7) << 4));
            int b11 = r1 * 8192 + ((x1c * 128 + q * 16) ^ ((x1c & 7) << 4));
            int b11h = r1 * 8192 + ((x1c * 128 + q * 16 + 64) ^ ((x1c & 7) << 4));
            c[0] = *(const s8v*)((const char*)kv + b00);
            c[1] = *(const s8v*)((const char*)kv + b00h);
            c[2] = *(const s8v*)((const char*)kv + b01);
            c[3] = *(const s8v*)((const char*)kv + b01h);
            c[4] = *(const s8v*)((const char*)kv + b10);
            c[5] = *(const s8v*)((const char*)kv + b10h);
            c[6] = *(const s8v*)((const char*)kv + b11);
            c[7] = *(const s8v*)((const char*)kv + b11h);
        } else {
            // exact global fallback (cold for this data, exact for any data)
            size_t i00 = (size_t)(y0c * kW + x0c) * 64;
            size_t i01 = (size_t)(y0c * kW + x1c) * 64;
            size_t i10 = (size_t)(y1c * kW + x0c) * 64;
            size_t i11 = (size_t)(y1c * kW + x1c) * 64;
            c[0] = *(const s8v*)(inpx + i00);
            c[1] = *(const s8v*)(inpx + i00 + 32);
            c[2] = *(const s8v*)(inpx + i01);
            c[3] = *(const s8v*)(inpx + i01 + 32);
            c[4] = *(const s8v*)(inpx + i10);
            c[5] = *(const s8v*)(inpx + i10 + 32);
            c[6] = *(const s8v*)(inpx + i11);
            c[7] = *(const s8v*)(inpx + i11 + 32);
        }

        s8v b0, b1;
#pragma unroll
        for (int j = 0; j < 8; ++j) {
            float v0 = w0 * bfu(c[0][j]) + w1 * bfu(c[2][j]) +
                       w2 * bfu(c[4][j]) + w3 * bfu(c[6][j]);
            float v1 = w0 * bfu(c[1][j]) + w1 * bfu(c[3][j]) +
                       w2 * bfu(c[5][j]) + w3 * bfu(c[7][j]);
            b0[j] = (short)bf16r(v0);
            b1[j] = (short)bf16r(v1);
        }
        // A-frags from LDS weights: row = obb*16 + l15, swizzled column
        const char* wkk = (const char*)wlds + kk * 8192 + l15 * 128;
#pragma unroll
        for (int obb = 0; obb < 4; ++obb) {
            s8v a0w = *(const s8v*)(wkk + obb * 2048 + wcol0);
            s8v a1w = *(const s8v*)(wkk + obb * 2048 + wcol1);
            acc[obb] = __builtin_amdgcn_mfma_f32_16x16x32_bf16(a0w, b0, acc[obb], 0, 0, 0);
            acc[obb] = __builtin_amdgcn_mfma_f32_16x16x32_bf16(a1w, b1, acc[obb], 0, 0, 0);
        }
    }

    // store: lane holds o = obb*16 + q*4 + reg at pixel px -> bf16 pixel-major
    ushort_t* orow = outp + ((size_t)b * kHW + y * kW + px) * 64 + q * 4;
#pragma unroll
    for (int obb = 0; obb < 4; ++obb) {
        float4 bias = *(const float4*)&db[obb * 16 + q * 4];
        f4v v = acc[obb];
        uint2 u;
        u.x = (unsigned)bf16r(v.x + bias.x) | ((unsigned)bf16r(v.y + bias.y) << 16);
        u.y = (unsigned)bf16r(v.z + bias.z) | ((unsigned)bf16r(v.w + bias.w) << 16);
        *(uint2*)(orow + obb * 16) = u;
    }
}

// ---------------------------------------------------------------------------
// Kernel 4: 9-tap local attention, bf16 pixel-major q/k/v (round-12 form).
// UNCHANGED this round (control).
// ---------------------------------------------------------------------------
__global__ __launch_bounds__(256) void attn_px(const ushort_t* __restrict__ qpx,
                                               const ushort_t* __restrict__ kpx,
                                               const ushort_t* __restrict__ vpx,
                                               ushort_t* __restrict__ aopx,
                                               int branch, int dil) {
    const int lb = (blockIdx.x & 7) * 128 + (blockIdx.x >> 3);  // XCD swizzle (G=1024)
    const int b    = lb >> 7;
    const int y    = (lb >> 1) & 63;
    const int half = lb & 1;
    const int tid  = threadIdx.x;
    const int wave = tid >> 6;
    const int l    = tid & 63;
    const int pxq  = l >> 3;          // 8 pixels per wave
    const int cg   = l & 7;           // 8 channel-groups of 8 ch
    const int x = half * 32 + wave * 8 + pxq;
    const int p = y * kW + x;
    const size_t pbase = (size_t)b * kHW;

    const ushort_t* qb = qpx + (pbase + p) * 64 + cg * 8;
    s8v q0 = *(const s8v*)qb;
    float qf[8];
#pragma unroll
    for (int j = 0; j < 8; ++j) qf[j] = bfu(q0[j]);

    int offs[9]; float msk[9];
#pragma unroll
    for (int kk = 0; kk < 9; ++kk) {
        int dy = (kk / 3 - 1) * dil, dx = (kk % 3 - 1) * dil;
        int yy = y + dy, xx = x + dx;
        bool v = (yy >= 0) & (yy < kH) & (xx >= 0) & (xx < kW);
        offs[kk] = v ? (p + dy * kW + dx) : p;
        msk[kk] = v ? 1.f : 0.f;
    }
    float e[9];
#pragma unroll
    for (int kk = 0; kk < 9; ++kk) {
        const ushort_t* kp = kpx + (pbase + offs[kk]) * 64 + cg * 8;
        s8v k0 = *(const s8v*)kp;
        float s = 0.f;
#pragma unroll
        for (int j = 0; j < 8; ++j) s += qf[j] * bfu(k0[j]);
        s += __shfl_xor(s, 1);
        s += __shfl_xor(s, 2);
        s += __shfl_xor(s, 4);
        e[kk] = s * 0.125f * msk[kk];
    }
    float mx = -1e30f;
#pragma unroll
    for (int kk = 0; kk < 9; ++kk) mx = fmaxf(mx, e[kk]);
    float ssum = 0.f;
#pragma unroll
    for (int kk = 0; kk < 9; ++kk) { e[kk] = __expf(e[kk] - mx); ssum += e[kk]; }
    float inv = 1.f / ssum;
#pragma unroll
    for (int kk = 0; kk < 9; ++kk) e[kk] = e[kk] * inv * msk[kk];

    float acc[8];
#pragma unroll
    for (int j = 0; j < 8; ++j) acc[j] = 0.f;
#pragma unroll
    for (int kk = 0; kk < 9; ++kk) {
        const ushort_t* vp = vpx + (pbase + offs[kk]) * 64 + cg * 8;
        s8v v0 = *(const s8v*)vp;
        float w = e[kk];
#pragma unroll
        for (int j = 0; j < 8; ++j) acc[j] += w * bfu(v0[j]);
    }
    unsigned u[4];
#pragma unroll
    for (int i = 0; i < 4; ++i)
        u[i] = (unsigned)bf16r(acc[2 * i]) | ((unsigned)bf16r(acc[2 * i + 1]) << 16);
    ushort_t* ob = aopx + (pbase + p) * kC + branch * 64 + cg * 8;
    *(uint4*)ob = make_uint4(u[0], u[1], u[2], u[3]);
}

// ---------------------------------------------------------------------------
// Kernel 5 (round-16 rewrite): output projection, LDS-staged GEMM.
// Old proj_mfma was the round-0 scattered-gather form (est ~23us, same
// pathology as the verified 68us qkv case). Same verified fix: stage the
// 64-px ao strip in LDS (identical 24.6KB swizzled layout: aopx stride is
// also 192ch), A-frags from pw_pack'd weights (12 strips), 3 strips/wave.
// ---------------------------------------------------------------------------
__global__ __launch_bounds__(256) void proj_mfma3(const ushort_t* __restrict__ aopx,
                                                  const ushort_t* __restrict__ pwbp,
                                                  const float* __restrict__ pb,
                                                  float* __restrict__ out) {
    __shared__ ushort_t xs[64 * kC];            // 24576 B, swizzled rows of 384 B

    const int tid = threadIdx.x;
    const int bx  = blockIdx.x;
    const int lb  = (bx & 7) * 64 + (bx >> 3);  // XCD swizzle (G=512)
    const int m0  = lb * 64;

#pragma unroll
    for (int i = 0; i < 6; ++i) {
        int il = i * 256 + tid;                 // 16B chunk id, 0..1535
        int p  = il / 24;                       // pixel row in strip
        int cc = il % 24;                       // 16B chunk within row
        uint4 v = *(const uint4*)(aopx + (size_t)(m0 + p) * kC + cc * 8);
        int dst = p * 384 + ((cc * 16) ^ ((p & 7) << 4));
        *(uint4*)((char*)xs + dst) = v;
    }
    __syncthreads();

    const int lane = tid & 63;
    const int wave = tid >> 6;
    const int l15  = lane & 15;
    const int q    = lane >> 4;
    const int sbase = wave * 3;                 // strips 0..11, 3 per wave

    f4v acc[3][4];
#pragma unroll
    for (int i = 0; i < 3; ++i)
#pragma unroll
        for (int m = 0; m < 4; ++m) acc[i][m] = (f4v){0.f, 0.f, 0.f, 0.f};

    const ushort_t* ap = pwbp + ((size_t)sbase * 6 * 64 + lane) * 8;

#pragma unroll
    for (int kc = 0; kc < 6; ++kc) {
        s8v bfr[4];
#pragma unroll
        for (int m = 0; m < 4; ++m) {
            int row = m * 16 + l15;
            int col = (kc * 64 + q * 16) ^ ((l15 & 7) << 4);
            bfr[m] = *(const s8v*)((const char*)xs + row * 384 + col);
        }
#pragma unroll
        for (int i = 0; i < 3; ++i) {
            s8v a = *(const s8v*)(ap + (size_t)(i * 6 + kc) * 64 * 8);
#pragma unroll
            for (int m = 0; m < 4; ++m)
                acc[i][m] = __builtin_amdgcn_mfma_f32_16x16x32_bf16(a, bfr[m], acc[i][m], 0, 0, 0);
        }
    }

    // store: D col = pixel (l15), row = n-in-strip (q*4+reg); out fp32 [m][192]
#pragma unroll
    for (int i = 0; i < 3; ++i) {
        int s  = sbase + i;
        int n0 = s * 16 + q * 4;
        float4 bias = *(const float4*)&pb[n0];
#pragma unroll
        for (int m = 0; m < 4; ++m) {
            f4v v = acc[i][m];
            v.x += bias.x; v.y += bias.y; v.z += bias.z; v.w += bias.w;
            *(f4v*)&out[(size_t)(m0 + m * 16 + l15) * kC + n0] = v;
        }
    }
}

// ---------------------------------------------------------------------------
// Host launcher.  Workspace (~63 MB, well under the proven 120 MB).
// ---------------------------------------------------------------------------
extern "C" void kernel_launch(void* const* d_in, const int* in_sizes, int n_in,
                              void* d_out, int out_size, void* d_ws, size_t ws_size,
                              hipStream_t stream) {
    const float* x      = (const float*)d_in[0];
    const float* qkv_w  = (const float*)d_in[1];
    const float* proj_w = (const float*)d_in[2];
    const float* proj_b = (const float*)d_in[3];
    const float* off_w2 = (const float*)d_in[4];
    const float* off_b2 = (const float*)d_in[5];
    const float* def_w2 = (const float*)d_in[6];
    const float* def_b2 = (const float*)d_in[7];
    const float* off_w3 = (const float*)d_in[8];
    const float* off_b3 = (const float*)d_in[9];
    const float* def_w3 = (const float*)d_in[10];
    const float* def_b3 = (const float*)d_in[11];
    float* out = (float*)d_out;

    float* ws   = (float*)d_ws;
    float* offb = ws;                               // 18 * M
    ushort_t* us = (ushort_t*)(offb + (size_t)18 * kM);
    ushort_t* xb     = us;  us += (size_t)kM * kC;
    ushort_t* qkvpx  = us;  us += (size_t)9 * kM * 64;
    ushort_t* kdpx   = us;  us += (size_t)kM * 64;
    ushort_t* vdpx   = us;  us += (size_t)kM * 64;
    ushort_t* aopx   = us;  us += (size_t)kM * kC;
    ushort_t* awb    = us;  us += (size_t)kNQKV * kC;   // 36*6*64*8 == 576*192
    ushort_t* pwbp   = us;  us += (size_t)kC * kC;      // 12*6*64*8 == 192*192
    ushort_t* dwtb2  = us;  us += kD * kD * 9;
    ushort_t* dwtb3  = us;  us += kD * kD * 9;
    ushort_t* owtb2  = us;  us += 9 * 32 * 64;
    ushort_t* owtb3  = us;  us += 9 * 32 * 64;

    // 0. bf16 conversion of x + ALL weight packs in one dispatch
    cvt_bf16<<<(kM * kC / 2 + 255) / 256, 256, 0, stream>>>(x, (unsigned*)xb, kM * kC / 2);
    prep_all<<<504, 256, 0, stream>>>(qkv_w, proj_w, def_w2, def_w3, off_w2, off_w3,
                                      awb, pwbp, dwtb2, dwtb3, owtb2, owtb3);

    // per-tensor pixel-major slices
    ushort_t* q0 = qkvpx;
    ushort_t* q1 = qkvpx + (size_t)1 * kM * 64;
    ushort_t* q2 = qkvpx + (size_t)2 * kM * 64;
    ushort_t* k0 = qkvpx + (size_t)3 * kM * 64;
    ushort_t* k1 = qkvpx + (size_t)4 * kM * 64;
    ushort_t* k2 = qkvpx + (size_t)5 * kM * 64;
    ushort_t* v0 = qkvpx + (size_t)6 * kM * 64;
    ushort_t* v1 = qkvpx + (size_t)7 * kM * 64;
    ushort_t* v2 = qkvpx + (size_t)8 * kM * 64;

    // 1. QKV projection -> 9 bf16 pixel-major tensors (LDS-staged GEMM)
    qkv_mfma3<<<dim3(kM / 64, 3), 256, 0, stream>>>(xb, awb, qkvpx);

    // 2. branch 0 (dil=1)
    attn_px<<<kB * kH * 2, 256, 0, stream>>>(q0, k0, v0, aopx, 0, 1);

    // 3. branch 1 (dil=2)
    off_conv_mfma<<<512, 256, 0, stream>>>(k1, owtb2, off_b2, offb, 2);
    deform_lds<2><<<512, 512, 0, stream>>>(k1, v1, offb, dwtb2, def_b2, kdpx, vdpx);
    attn_px<<<kB * kH * 2, 256, 0, stream>>>(q1, kdpx, vdpx, aopx, 1, 2);

    // 4. branch 2 (dil=3)
    off_conv_mfma<<<512, 256, 0, stream>>>(k2, owtb3, off_b3, offb, 3);
    deform_lds<3><<<512, 512, 0, stream>>>(k2, v2, offb, dwtb3, def_b3, kdpx, vdpx);
    attn_px<<<kB * kH * 2, 256, 0, stream>>>(q2, kdpx, vdpx, aopx, 2, 3);

    // 5. output projection (LDS-staged bf16 MFMA, fp32 out)
    proj_mfma3<<<512, 256, 0, stream>>>(aopx, pwbp, proj_b, out);
}

// Round 8
// 229.472 us; speedup vs baseline: 1.4547x; 1.0070x over previous
//
#include <hip/hip_runtime.h>
#include <cmath>

// ---------------------------------------------------------------------------
// Problem constants (B=8, H=W=64, C=192, 3 dilation branches of d=64, heads=64)
// ---------------------------------------------------------------------------
#define kB    8
#define kH    64
#define kW    64
#define kHW   4096          // H*W
#define kC    192
#define kD    64            // channels per dilation branch == head_dim
#define kM    (kB * kHW)    // 32768 total pixels
#define kNQKV 576           // 3*C

typedef unsigned short ushort_t;
typedef __attribute__((ext_vector_type(8))) short  s8v;   // 8 bf16 (4 VGPRs)
typedef __attribute__((ext_vector_type(4))) float  f4v;   // MFMA C/D frag

__device__ inline unsigned short bf16r(float f) {   // round-to-nearest-even
    union { float f; unsigned u; } v; v.f = f;
    unsigned u = v.u + 0x7FFFu + ((v.u >> 16) & 1u);
    return (unsigned short)(u >> 16);
}
__device__ inline float bfu(short s) {              // bf16 -> fp32
    union { unsigned u; float f; } v;
    v.u = ((unsigned)(unsigned short)s) << 16;
    return v.f;
}

// ---------------------------------------------------------------------------
// fp32 -> bf16 pairwise converter (x only; weight packs are fused below)
// ---------------------------------------------------------------------------
__global__ void cvt_bf16(const float* __restrict__ src, unsigned* __restrict__ dst, int n2) {
    int i = blockIdx.x * 256 + threadIdx.x;
    if (i >= n2) return;
    float2 f = ((const float2*)src)[i];
    dst[i] = (unsigned)bf16r(f.x) | ((unsigned)bf16r(f.y) << 16);
}

// ---------------------------------------------------------------------------
// prep_all: all weight conversions/packs in ONE dispatch (round-16, verified).
// ---------------------------------------------------------------------------
__global__ void prep_all(const float* __restrict__ qkv_w,
                         const float* __restrict__ proj_w,
                         const float* __restrict__ def_w2,
                         const float* __restrict__ def_w3,
                         const float* __restrict__ off_w2,
                         const float* __restrict__ off_w3,
                         ushort_t* __restrict__ awb,
                         ushort_t* __restrict__ pwbp,
                         ushort_t* __restrict__ dwtb2,
                         ushort_t* __restrict__ dwtb3,
                         ushort_t* __restrict__ owtb2,
                         ushort_t* __restrict__ owtb3) {
    const int bid = blockIdx.x;
    const int tid = threadIdx.x;
    if (bid < 54) {                       // qw_pack
        int idx = bid * 256 + tid;        // 36*6*64 = 13824
        if (idx >= 36 * 6 * 64) return;
        int lane = idx & 63;
        int kc   = (idx >> 6) % 6;
        int s    = idx / 384;
        int row  = s * 16 + (lane & 15);
        int k0   = kc * 32 + (lane >> 4) * 8;
        const float* src = qkv_w + (size_t)row * kC + k0;
        ushort_t* dst = awb + (size_t)idx * 8;
#pragma unroll
        for (int j = 0; j < 8; ++j) dst[j] = bf16r(src[j]);
    } else if (bid < 72) {                // pw_pack
        int idx = (bid - 54) * 256 + tid; // 12*6*64 = 4608
        if (idx >= 12 * 6 * 64) return;
        int lane = idx & 63;
        int kc   = (idx >> 6) % 6;
        int s    = idx / 384;
        int row  = s * 16 + (lane & 15);
        int k0   = kc * 32 + (lane >> 4) * 8;
        const float* src = proj_w + (size_t)row * kC + k0;
        ushort_t* dst = pwbp + (size_t)idx * 8;
#pragma unroll
        for (int j = 0; j < 8; ++j) dst[j] = bf16r(src[j]);
    } else if (bid < 360) {               // dw_tb x2
        const float* dw = (bid < 216) ? def_w2 : def_w3;
        ushort_t* dwtb  = (bid < 216) ? dwtb2 : dwtb3;
        int l = ((bid < 216) ? (bid - 72) : (bid - 216)) * 256 + tid;  // 36864
        if (l >= kD * kD * 9) return;
        int o = l / 576;
        int c = (l / 9) % 64;
        int kk = l % 9;
        dwtb[(kk * 64 + o) * 64 + c] = bf16r(dw[l]);
    } else {                              // ow_tb x2
        const float* ow = (bid < 432) ? off_w2 : off_w3;
        ushort_t* owtb  = (bid < 432) ? owtb2 : owtb3;
        int l = ((bid < 432) ? (bid - 360) : (bid - 432)) * 256 + tid; // 18432
        if (l >= 9 * 32 * 64) return;
        int kk = l >> 11;
        int j  = (l >> 6) & 31;
        int c  = l & 63;
        owtb[l] = (j < 18) ? bf16r(ow[j * 576 + c * 9 + kk]) : (ushort_t)0;
    }
}

// ---------------------------------------------------------------------------
// Kernel 1: QKV projection GEMM, LDS-staged (round-11, verified). UNCHANGED.
// ---------------------------------------------------------------------------
__global__ __launch_bounds__(256) void qkv_mfma3(const ushort_t* __restrict__ xb,
                                                 const ushort_t* __restrict__ awb,
                                                 ushort_t* __restrict__ qkvpx) {
    __shared__ ushort_t xs[64 * kC];            // 24576 B, swizzled rows of 384 B

    const int tid = threadIdx.x;
    const int bx  = blockIdx.x;
    const int lb  = (bx & 7) * 64 + (bx >> 3);  // XCD swizzle (G=512)
    const int m0  = lb * 64;
    const int ty3 = blockIdx.y;                 // tensor triple: channels [ty3*192, +192)

#pragma unroll
    for (int i = 0; i < 6; ++i) {
        int il = i * 256 + tid;                 // 16B chunk id, 0..1535
        int p  = il / 24;                       // pixel row in strip
        int cc = il % 24;                       // 16B chunk within row
        uint4 v = *(const uint4*)(xb + (size_t)(m0 + p) * kC + cc * 8);
        int dst = p * 384 + ((cc * 16) ^ ((p & 7) << 4));
        *(uint4*)((char*)xs + dst) = v;
    }
    __syncthreads();

    const int lane = tid & 63;
    const int wave = tid >> 6;
    const int l15  = lane & 15;
    const int q    = lane >> 4;
    const int sbase = ty3 * 12 + wave * 3;      // first of 3 N-strips for this wave

    f4v acc[3][4];
#pragma unroll
    for (int i = 0; i < 3; ++i)
#pragma unroll
        for (int m = 0; m < 4; ++m) acc[i][m] = (f4v){0.f, 0.f, 0.f, 0.f};

    const ushort_t* ap = awb + ((size_t)sbase * 6 * 64 + lane) * 8;

#pragma unroll
    for (int kc = 0; kc < 6; ++kc) {
        s8v bfr[4];
#pragma unroll
        for (int m = 0; m < 4; ++m) {
            int row = m * 16 + l15;
            int col = (kc * 64 + q * 16) ^ ((l15 & 7) << 4);
            bfr[m] = *(const s8v*)((const char*)xs + row * 384 + col);
        }
#pragma unroll
        for (int i = 0; i < 3; ++i) {
            s8v a = *(const s8v*)(ap + (size_t)(i * 6 + kc) * 64 * 8);
#pragma unroll
            for (int m = 0; m < 4; ++m)
                acc[i][m] = __builtin_amdgcn_mfma_f32_16x16x32_bf16(a, bfr[m], acc[i][m], 0, 0, 0);
        }
    }

#pragma unroll
    for (int i = 0; i < 3; ++i) {
        int s   = sbase + i;
        int ty  = s >> 2;                       // tensor 0..8
        int c64 = (s & 3) * 16 + q * 4;         // channel within tensor
        ushort_t* obase = qkvpx + (size_t)ty * kM * 64 + (size_t)m0 * 64 + c64;
#pragma unroll
        for (int m = 0; m < 4; ++m) {
            f4v v = acc[i][m];
            uint2 u;
            u.x = (unsigned)bf16r(v.x) | ((unsigned)bf16r(v.y) << 16);
            u.y = (unsigned)bf16r(v.z) | ((unsigned)bf16r(v.w) << 16);
            *(uint2*)(obase + (size_t)(m * 16 + l15) * 64) = u;
        }
    }
}

// ---------------------------------------------------------------------------
// Kernel 2: offsets conv via bf16 MFMA over pixel-major k. UNCHANGED.
// ---------------------------------------------------------------------------
__global__ __launch_bounds__(256) void off_conv_mfma(const ushort_t* __restrict__ kpx,
                                                     const ushort_t* __restrict__ owtb,
                                                     const float* __restrict__ obias,
                                                     float* __restrict__ offb,
                                                     int dil) {
    const int lb = (blockIdx.x & 7) * 64 + (blockIdx.x >> 3);   // XCD swizzle (G=512)
    const int b = lb >> 6;
    const int y = lb & 63;
    const int tid  = threadIdx.x;
    const int lane = tid & 63;
    const int wave = tid >> 6;
    const int l15  = lane & 15;
    const int q    = lane >> 4;
    const int px   = wave * 16 + l15;

    const ushort_t* inpx = kpx + (size_t)b * kHW * 64 + q * 8;

    f4v acc[2];
    acc[0] = (f4v){0.f, 0.f, 0.f, 0.f};
    acc[1] = (f4v){0.f, 0.f, 0.f, 0.f};

#pragma unroll
    for (int kk = 0; kk < 9; ++kk) {
        const int yy = y + (kk / 3 - 1) * dil;
        const int xx = px + (kk % 3 - 1) * dil;
        const bool valid = (yy >= 0) & (yy < kH) & (xx >= 0) & (xx < kW);
        const size_t idx = valid ? (size_t)(yy * kW + xx) * 64 : 0;
        s8v a0 = *(const s8v*)(inpx + idx);
        s8v a1 = *(const s8v*)(inpx + idx + 32);
        if (!valid) {
            a0 = (s8v){0, 0, 0, 0, 0, 0, 0, 0};
            a1 = (s8v){0, 0, 0, 0, 0, 0, 0, 0};
        }
        const ushort_t* wb = owtb + (size_t)kk * 2048 + l15 * 64 + q * 8;
#pragma unroll
        for (int nbk = 0; nbk < 2; ++nbk) {
            s8v b0 = *(const s8v*)(wb + nbk * 1024);
            s8v b1 = *(const s8v*)(wb + nbk * 1024 + 32);
            acc[nbk] = __builtin_amdgcn_mfma_f32_16x16x32_bf16(a0, b0, acc[nbk], 0, 0, 0);
            acc[nbk] = __builtin_amdgcn_mfma_f32_16x16x32_bf16(a1, b1, acc[nbk], 0, 0, 0);
        }
    }
#pragma unroll
    for (int nbk = 0; nbk < 2; ++nbk) {
        int n = nbk * 16 + l15;
        if (n < 18) {
            float bias = obias[n];
            f4v v = acc[nbk];
            v.x += bias; v.y += bias; v.z += bias; v.w += bias;
            *(f4v*)&offb[((size_t)b * 18 + n) * kHW + y * kW + wave * 16 + q * 4] = v;
        }
    }
}

// ---------------------------------------------------------------------------
// Kernel 3 (round-15, verified): deformable 3x3 conv, fully LDS-resident
// inner loop. UNCHANGED this round (control).
// ---------------------------------------------------------------------------
template<int DIL>
__global__ __launch_bounds__(512) void deform_lds(const ushort_t* __restrict__ kpx,
                                                  const ushort_t* __restrict__ vpx,
                                                  const float* __restrict__ offb,
                                                  const ushort_t* __restrict__ dwtb,
                                                  const float* __restrict__ db,
                                                  ushort_t* __restrict__ outkpx,
                                                  ushort_t* __restrict__ outvpx) {
    constexpr int NR = 2 * DIL + 4;         // staged rows (|oy|<1 window)
    __shared__ ushort_t kv[NR * 4096];      // NR x 8192 B, swizzled
    __shared__ ushort_t wlds[9 * 4096];     // 73728 B: dwtb copy, swizzled

    const int tid = threadIdx.x;
    const int bx  = blockIdx.x;
    const int lb  = (bx & 7) * 64 + (bx >> 3);  // XCD swizzle (G=512)
    const int t   = lb >> 8;                // 0 = k, 1 = v
    const int b   = (lb >> 5) & 7;
    const int y0  = (lb & 31) * 2;          // first of 2 output rows
    const int wlo = y0 - DIL - 1;           // staged window start (may be <0)

    const ushort_t* inb = (t ? vpx : kpx) + (size_t)b * kHW * 64;
    ushort_t* outp = t ? outvpx : outkpx;

    // ---- stage weights: 9 x 512 x 16B, linear->row-swizzled ----
#pragma unroll
    for (int i = 0; i < 9; ++i) {
        int g = (i * 512 + tid) * 16;            // linear byte offset
        uint4 v = *(const uint4*)((const char*)dwtb + g);
        int row = (g >> 7) & 63;                 // o-row within kk tile
        int dst = g ^ ((row & 7) << 4);
        *(uint4*)((char*)wlds + dst) = v;
    }
    // ---- stage NR kv rows, coalesced 16B/thread, swizzled ----
#pragma unroll
    for (int r = 0; r < NR; ++r) {
        int gy = min(max(wlo + r, 0), kH - 1);
        uint4 v = *(const uint4*)(inb + (size_t)gy * 4096 + tid * 8);
        int x  = tid >> 3;
        int cc = tid & 7;
        int dst = r * 8192 + ((x * 128 + cc * 16) ^ ((x & 7) << 4));
        *(uint4*)((char*)kv + dst) = v;
    }
    __syncthreads();

    const int lane = tid & 63;
    const int wave = tid >> 6;          // 0..7
    const int ry   = wave >> 2;         // output row within pair
    const int wc   = wave & 3;          // px column
    const int l15  = lane & 15;
    const int q    = lane >> 4;
    const int y    = y0 + ry;
    const int px   = wc * 16 + l15;
    const int wsw  = (l15 & 7) << 4;    // weight-read swizzle bits (row&7 == l15&7)
    const int wcol0 = (q * 16) ^ wsw;        // swizzled column, low half  (0..127)
    const int wcol1 = (q * 16 + 64) ^ wsw;   // swizzled column, high half (0..127)

    const ushort_t* inpx = inb + q * 8; // global fallback base

    f4v acc[4];
#pragma unroll
    for (int ob = 0; ob < 4; ++ob) acc[ob] = (f4v){0.f, 0.f, 0.f, 0.f};

    // prefetch all 18 offset channels for my pixel
    const float* offrow = offb + (size_t)b * 18 * kHW + y * kW + px;
    float offv[18];
#pragma unroll
    for (int i = 0; i < 18; ++i) offv[i] = offrow[(size_t)i * kHW];

#pragma unroll
    for (int kk = 0; kk < 9; ++kk) {
        float oy = offv[kk * 2 + 0];
        float ox = offv[kk * 2 + 1];
        float py  = (float)y  + (float)((kk / 3 - 1) * DIL) + oy;
        float pxf = (float)px + (float)((kk % 3 - 1) * DIL) + ox;
        float fy = floorf(py), fx = floorf(pxf);
        float wy = py - fy, wx = pxf - fx;
        int iy0 = (int)fy, ix0 = (int)fx;
        int iy1 = iy0 + 1, ix1 = ix0 + 1;
        int y0c = min(max(iy0, 0), kH - 1), x0c = min(max(ix0, 0), kW - 1);
        int y1c = min(max(iy1, 0), kH - 1), x1c = min(max(ix1, 0), kW - 1);
        bool vy0 = (iy0 >= 0) & (iy0 < kH), vx0 = (ix0 >= 0) & (ix0 < kW);
        bool vy1 = (iy1 >= 0) & (iy1 < kH), vx1 = (ix1 >= 0) & (ix1 < kW);
        float w0 = (vy0 && vx0) ? (1.f - wy) * (1.f - wx) : 0.f;
        float w1 = (vy0 && vx1) ? (1.f - wy) * wx : 0.f;
        float w2 = (vy1 && vx0) ? wy * (1.f - wx) : 0.f;
        float w3 = (vy1 && vx1) ? wy * wx : 0.f;

        s8v c[8];
        if (__builtin_expect(fabsf(oy) < 1.0f, 1)) {
            // LDS fast path: |oy|<1 guarantees rows inside the staged window
            int r0 = min(max(y0c - wlo, 0), NR - 1);
            int r1 = min(max(y1c - wlo, 0), NR - 1);
            int b00 = r0 * 8192 + ((x0c * 128 + q * 16) ^ ((x0c & 7) << 4));
            int b00h = r0 * 8192 + ((x0c * 128 + q * 16 + 64) ^ ((x0c & 7) << 4));
            int b01 = r0 * 8192 + ((x1c * 128 + q * 16) ^ ((x1c & 7) << 4));
            int b01h = r0 * 8192 + ((x1c * 128 + q * 16 + 64) ^ ((x1c & 7) << 4));
            int b10 = r1 * 8192 + ((x0c * 128 + q * 16) ^ ((x0c & 7) << 4));
            int b10h = r1 * 8192 + ((x0c * 128 + q * 16 + 64) ^ ((x0c & 7) << 4));
            int b11 = r1 * 8192 + ((x1c * 128 + q * 16) ^ ((x1c & 7) << 4));
            int b11h = r1 * 8192 + ((x1c * 128 + q * 16 + 64) ^ ((x1c & 7) << 4));
            c[0] = *(const s8v*)((const char*)kv + b00);
            c[1] = *(const s8v*)((const char*)kv + b00h);
            c[2] = *(const s8v*)((const char*)kv + b01);
            c[3] = *(const s8v*)((const char*)kv + b01h);
            c[4] = *(const s8v*)((const char*)kv + b10);
            c[5] = *(const s8v*)((const char*)kv + b10h);
            c[6] = *(const s8v*)((const char*)kv + b11);
            c[7] = *(const s8v*)((const char*)kv + b11h);
        } else {
            // exact global fallback (cold for this data, exact for any data)
            size_t i00 = (size_t)(y0c * kW + x0c) * 64;
            size_t i01 = (size_t)(y0c * kW + x1c) * 64;
            size_t i10 = (size_t)(y1c * kW + x0c) * 64;
            size_t i11 = (size_t)(y1c * kW + x1c) * 64;
            c[0] = *(const s8v*)(inpx + i00);
            c[1] = *(const s8v*)(inpx + i00 + 32);
            c[2] = *(const s8v*)(inpx + i01);
            c[3] = *(const s8v*)(inpx + i01 + 32);
            c[4] = *(const s8v*)(inpx + i10);
            c[5] = *(const s8v*)(inpx + i10 + 32);
            c[6] = *(const s8v*)(inpx + i11);
            c[7] = *(const s8v*)(inpx + i11 + 32);
        }

        s8v b0, b1;
#pragma unroll
        for (int j = 0; j < 8; ++j) {
            float v0 = w0 * bfu(c[0][j]) + w1 * bfu(c[2][j]) +
                       w2 * bfu(c[4][j]) + w3 * bfu(c[6][j]);
            float v1 = w0 * bfu(c[1][j]) + w1 * bfu(c[3][j]) +
                       w2 * bfu(c[5][j]) + w3 * bfu(c[7][j]);
            b0[j] = (short)bf16r(v0);
            b1[j] = (short)bf16r(v1);
        }
        // A-frags from LDS weights: row = obb*16 + l15, swizzled column
        const char* wkk = (const char*)wlds + kk * 8192 + l15 * 128;
#pragma unroll
        for (int obb = 0; obb < 4; ++obb) {
            s8v a0w = *(const s8v*)(wkk + obb * 2048 + wcol0);
            s8v a1w = *(const s8v*)(wkk + obb * 2048 + wcol1);
            acc[obb] = __builtin_amdgcn_mfma_f32_16x16x32_bf16(a0w, b0, acc[obb], 0, 0, 0);
            acc[obb] = __builtin_amdgcn_mfma_f32_16x16x32_bf16(a1w, b1, acc[obb], 0, 0, 0);
        }
    }

    // store: lane holds o = obb*16 + q*4 + reg at pixel px -> bf16 pixel-major
    ushort_t* orow = outp + ((size_t)b * kHW + y * kW + px) * 64 + q * 4;
#pragma unroll
    for (int obb = 0; obb < 4; ++obb) {
        float4 bias = *(const float4*)&db[obb * 16 + q * 4];
        f4v v = acc[obb];
        uint2 u;
        u.x = (unsigned)bf16r(v.x + bias.x) | ((unsigned)bf16r(v.y + bias.y) << 16);
        u.y = (unsigned)bf16r(v.z + bias.z) | ((unsigned)bf16r(v.w + bias.w) << 16);
        *(uint2*)(orow + obb * 16) = u;
    }
}

// ---------------------------------------------------------------------------
// Kernel 4 (round-17 rewrite): 9-tap local attention, LDS-STAGED k/v.
// History: attn was TLP-invariant (round-12 2x-TLP rework: no change) —
// same VMEM-stream wall as deform (19 scattered loads/lane, each k/v line
// re-gathered 9x). Verified fix (3-for-3 now): stage the k,v row windows
// [y0-DIL, y0+1+DIL] once per block, coalesced + XOR-swizzled; all 36 tap
// reads/lane hit LDS. Block = 2 rows x 64 px, 512 thr (deform's shape).
// LDS: dil1 64KB / dil2 96KB / dil3 128KB. Masked-tap semantics unchanged
// (score 0 in softmax, zeroed in PV — matches zero-pad reference).
// ---------------------------------------------------------------------------
template<int DIL>
__global__ __launch_bounds__(512) void attn_lds(const ushort_t* __restrict__ qpx,
                                                const ushort_t* __restrict__ kpx,
                                                const ushort_t* __restrict__ vpx,
                                                ushort_t* __restrict__ aopx,
                                                int branch) {
    constexpr int NR = 2 * DIL + 2;         // staged rows
    __shared__ ushort_t ks[NR * 4096];      // NR x 8192 B, swizzled
    __shared__ ushort_t vs[NR * 4096];

    const int tid = threadIdx.x;
    const int bx  = blockIdx.x;
    const int lb  = (bx & 7) * 32 + (bx >> 3);  // XCD swizzle (G=256)
    const int b   = lb >> 5;
    const int y0  = (lb & 31) * 2;          // first of 2 output rows
    const int wlo = y0 - DIL;               // window rows wlo .. y0+1+DIL

    const size_t pbase = (size_t)b * kHW;
    const ushort_t* kb = kpx + pbase * 64;
    const ushort_t* vb = vpx + pbase * 64;

    // ---- stage NR rows of k AND v, 16B/thread/row, swizzled ----
    {
        int x  = tid >> 3;
        int cc = tid & 7;
        int dstc = (x * 128 + cc * 16) ^ ((x & 7) << 4);
#pragma unroll
        for (int r = 0; r < NR; ++r) {
            int gy = min(max(wlo + r, 0), kH - 1);
            *(uint4*)((char*)ks + r * 8192 + dstc) = *(const uint4*)(kb + (size_t)gy * 4096 + tid * 8);
            *(uint4*)((char*)vs + r * 8192 + dstc) = *(const uint4*)(vb + (size_t)gy * 4096 + tid * 8);
        }
    }
    __syncthreads();

    const int wave = tid >> 6;          // 0..7
    const int l    = tid & 63;
    const int ry   = wave >> 2;         // row within pair
    const int wc   = wave & 3;          // 16-px column group
    const int pxq  = l >> 2;            // 16 pixels per wave
    const int cg   = l & 3;             // 4 channel-groups of 16 ch
    const int y  = y0 + ry;
    const int x_ = wc * 16 + pxq;
    const int p  = y * kW + x_;

    // q from global (coalesced, read once)
    const ushort_t* qb = qpx + (pbase + p) * 64 + cg * 16;
    s8v q0 = *(const s8v*)qb;
    s8v q1 = *(const s8v*)(qb + 8);
    float qf[16];
#pragma unroll
    for (int j = 0; j < 8; ++j) { qf[j] = bfu(q0[j]); qf[8 + j] = bfu(q1[j]); }

    // tap addresses in LDS
    int a0s[9], a1s[9];
    float msk[9];
#pragma unroll
    for (int kk = 0; kk < 9; ++kk) {
        int dy = (kk / 3 - 1) * DIL, dx = (kk % 3 - 1) * DIL;
        int yy = y + dy, xx = x_ + dx;
        bool v = (yy >= 0) & (yy < kH) & (xx >= 0) & (xx < kW);
        msk[kk] = v ? 1.f : 0.f;
        int r  = min(max(yy - wlo, 0), NR - 1);
        int xc = min(max(xx, 0), kW - 1);
        int sw = (xc & 7) << 4;
        a0s[kk] = r * 8192 + ((xc * 128 + cg * 32) ^ sw);
        a1s[kk] = r * 8192 + ((xc * 128 + cg * 32 + 16) ^ sw);
    }

    float e[9];
#pragma unroll
    for (int kk = 0; kk < 9; ++kk) {
        s8v k0 = *(const s8v*)((const char*)ks + a0s[kk]);
        s8v k1 = *(const s8v*)((const char*)ks + a1s[kk]);
        float s = 0.f;
#pragma unroll
        for (int j = 0; j < 8; ++j) {
            s += qf[j] * bfu(k0[j]);
            s += qf[8 + j] * bfu(k1[j]);
        }
        s += __shfl_xor(s, 1);
        s += __shfl_xor(s, 2);
        e[kk] = s * 0.125f * msk[kk];
    }
    float mx = -1e30f;
#pragma unroll
    for (int kk = 0; kk < 9; ++kk) mx = fmaxf(mx, e[kk]);
    float ssum = 0.f;
#pragma unroll
    for (int kk = 0; kk < 9; ++kk) { e[kk] = __expf(e[kk] - mx); ssum += e[kk]; }
    float inv = 1.f / ssum;
#pragma unroll
    for (int kk = 0; kk < 9; ++kk) e[kk] = e[kk] * inv * msk[kk];

    float acc[16];
#pragma unroll
    for (int j = 0; j < 16; ++j) acc[j] = 0.f;
#pragma unroll
    for (int kk = 0; kk < 9; ++kk) {
        s8v v0 = *(const s8v*)((const char*)vs + a0s[kk]);
        s8v v1 = *(const s8v*)((const char*)vs + a1s[kk]);
        float w = e[kk];
#pragma unroll
        for (int j = 0; j < 8; ++j) {
            acc[j] += w * bfu(v0[j]);
            acc[8 + j] += w * bfu(v1[j]);
        }
    }
    unsigned u[8];
#pragma unroll
    for (int i = 0; i < 8; ++i)
        u[i] = (unsigned)bf16r(acc[2 * i]) | ((unsigned)bf16r(acc[2 * i + 1]) << 16);
    ushort_t* ob = aopx + (pbase + p) * kC + branch * 64 + cg * 16;
    *(uint4*)ob = make_uint4(u[0], u[1], u[2], u[3]);
    *(uint4*)(ob + 8) = make_uint4(u[4], u[5], u[6], u[7]);
}

// ---------------------------------------------------------------------------
// Kernel 5 (round-16, verified): output projection, LDS-staged GEMM. UNCHANGED.
// ---------------------------------------------------------------------------
__global__ __launch_bounds__(256) void proj_mfma3(const ushort_t* __restrict__ aopx,
                                                  const ushort_t* __restrict__ pwbp,
                                                  const float* __restrict__ pb,
                                                  float* __restrict__ out) {
    __shared__ ushort_t xs[64 * kC];            // 24576 B, swizzled rows of 384 B

    const int tid = threadIdx.x;
    const int bx  = blockIdx.x;
    const int lb  = (bx & 7) * 64 + (bx >> 3);  // XCD swizzle (G=512)
    const int m0  = lb * 64;

#pragma unroll
    for (int i = 0; i < 6; ++i) {
        int il = i * 256 + tid;                 // 16B chunk id, 0..1535
        int p  = il / 24;                       // pixel row in strip
        int cc = il % 24;                       // 16B chunk within row
        uint4 v = *(const uint4*)(aopx + (size_t)(m0 + p) * kC + cc * 8);
        int dst = p * 384 + ((cc * 16) ^ ((p & 7) << 4));
        *(uint4*)((char*)xs + dst) = v;
    }
    __syncthreads();

    const int lane = tid & 63;
    const int wave = tid >> 6;
    const int l15  = lane & 15;
    const int q    = lane >> 4;
    const int sbase = wave * 3;                 // strips 0..11, 3 per wave

    f4v acc[3][4];
#pragma unroll
    for (int i = 0; i < 3; ++i)
#pragma unroll
        for (int m = 0; m < 4; ++m) acc[i][m] = (f4v){0.f, 0.f, 0.f, 0.f};

    const ushort_t* ap = pwbp + ((size_t)sbase * 6 * 64 + lane) * 8;

#pragma unroll
    for (int kc = 0; kc < 6; ++kc) {
        s8v bfr[4];
#pragma unroll
        for (int m = 0; m < 4; ++m) {
            int row = m * 16 + l15;
            int col = (kc * 64 + q * 16) ^ ((l15 & 7) << 4);
            bfr[m] = *(const s8v*)((const char*)xs + row * 384 + col);
        }
#pragma unroll
        for (int i = 0; i < 3; ++i) {
            s8v a = *(const s8v*)(ap + (size_t)(i * 6 + kc) * 64 * 8);
#pragma unroll
            for (int m = 0; m < 4; ++m)
                acc[i][m] = __builtin_amdgcn_mfma_f32_16x16x32_bf16(a, bfr[m], acc[i][m], 0, 0, 0);
        }
    }

    // store: D col = pixel (l15), row = n-in-strip (q*4+reg); out fp32 [m][192]
#pragma unroll
    for (int i = 0; i < 3; ++i) {
        int s  = sbase + i;
        int n0 = s * 16 + q * 4;
        float4 bias = *(const float4*)&pb[n0];
#pragma unroll
        for (int m = 0; m < 4; ++m) {
            f4v v = acc[i][m];
            v.x += bias.x; v.y += bias.y; v.z += bias.z; v.w += bias.w;
            *(f4v*)&out[(size_t)(m0 + m * 16 + l15) * kC + n0] = v;
        }
    }
}

// ---------------------------------------------------------------------------
// Host launcher.  Workspace (~63 MB, well under the proven 120 MB).
// ---------------------------------------------------------------------------
extern "C" void kernel_launch(void* const* d_in, const int* in_sizes, int n_in,
                              void* d_out, int out_size, void* d_ws, size_t ws_size,
                              hipStream_t stream) {
    const float* x      = (const float*)d_in[0];
    const float* qkv_w  = (const float*)d_in[1];
    const float* proj_w = (const float*)d_in[2];
    const float* proj_b = (const float*)d_in[3];
    const float* off_w2 = (const float*)d_in[4];
    const float* off_b2 = (const float*)d_in[5];
    const float* def_w2 = (const float*)d_in[6];
    const float* def_b2 = (const float*)d_in[7];
    const float* off_w3 = (const float*)d_in[8];
    const float* off_b3 = (const float*)d_in[9];
    const float* def_w3 = (const float*)d_in[10];
    const float* def_b3 = (const float*)d_in[11];
    float* out = (float*)d_out;

    float* ws   = (float*)d_ws;
    float* offb = ws;                               // 18 * M
    ushort_t* us = (ushort_t*)(offb + (size_t)18 * kM);
    ushort_t* xb     = us;  us += (size_t)kM * kC;
    ushort_t* qkvpx  = us;  us += (size_t)9 * kM * 64;
    ushort_t* kdpx   = us;  us += (size_t)kM * 64;
    ushort_t* vdpx   = us;  us += (size_t)kM * 64;
    ushort_t* aopx   = us;  us += (size_t)kM * kC;
    ushort_t* awb    = us;  us += (size_t)kNQKV * kC;   // 36*6*64*8 == 576*192
    ushort_t* pwbp   = us;  us += (size_t)kC * kC;      // 12*6*64*8 == 192*192
    ushort_t* dwtb2  = us;  us += kD * kD * 9;
    ushort_t* dwtb3  = us;  us += kD * kD * 9;
    ushort_t* owtb2  = us;  us += 9 * 32 * 64;
    ushort_t* owtb3  = us;  us += 9 * 32 * 64;

    // 0. bf16 conversion of x + ALL weight packs in one dispatch
    cvt_bf16<<<(kM * kC / 2 + 255) / 256, 256, 0, stream>>>(x, (unsigned*)xb, kM * kC / 2);
    prep_all<<<504, 256, 0, stream>>>(qkv_w, proj_w, def_w2, def_w3, off_w2, off_w3,
                                      awb, pwbp, dwtb2, dwtb3, owtb2, owtb3);

    // per-tensor pixel-major slices
    ushort_t* q0 = qkvpx;
    ushort_t* q1 = qkvpx + (size_t)1 * kM * 64;
    ushort_t* q2 = qkvpx + (size_t)2 * kM * 64;
    ushort_t* k0 = qkvpx + (size_t)3 * kM * 64;
    ushort_t* k1 = qkvpx + (size_t)4 * kM * 64;
    ushort_t* k2 = qkvpx + (size_t)5 * kM * 64;
    ushort_t* v0 = qkvpx + (size_t)6 * kM * 64;
    ushort_t* v1 = qkvpx + (size_t)7 * kM * 64;
    ushort_t* v2 = qkvpx + (size_t)8 * kM * 64;

    // 1. QKV projection -> 9 bf16 pixel-major tensors (LDS-staged GEMM)
    qkv_mfma3<<<dim3(kM / 64, 3), 256, 0, stream>>>(xb, awb, qkvpx);

    // 2. branch 0 (dil=1)
    attn_lds<1><<<kB * kH / 2, 512, 0, stream>>>(q0, k0, v0, aopx, 0);

    // 3. branch 1 (dil=2)
    off_conv_mfma<<<512, 256, 0, stream>>>(k1, owtb2, off_b2, offb, 2);
    deform_lds<2><<<512, 512, 0, stream>>>(k1, v1, offb, dwtb2, def_b2, kdpx, vdpx);
    attn_lds<2><<<kB * kH / 2, 512, 0, stream>>>(q1, kdpx, vdpx, aopx, 1);

    // 4. branch 2 (dil=3)
    off_conv_mfma<<<512, 256, 0, stream>>>(k2, owtb3, off_b3, offb, 3);
    deform_lds<3><<<512, 512, 0, stream>>>(k2, v2, offb, dwtb3, def_b3, kdpx, vdpx);
    attn_lds<3><<<kB * kH / 2, 512, 0, stream>>>(q2, kdpx, vdpx, aopx, 2);

    // 5. output projection (LDS-staged bf16 MFMA, fp32 out)
    proj_mfma3<<<512, 256, 0, stream>>>(aopx, pwbp, proj_b, out);
}

// Round 9
// 219.363 us; speedup vs baseline: 1.5218x; 1.0461x over previous
//
#include <hip/hip_runtime.h>
#include <cmath>

// ---------------------------------------------------------------------------
// Problem constants (B=8, H=W=64, C=192, 3 dilation branches of d=64, heads=64)
// ---------------------------------------------------------------------------
#define kB    8
#define kH    64
#define kW    64
#define kHW   4096          // H*W
#define kC    192
#define kD    64            // channels per dilation branch == head_dim
#define kM    (kB * kHW)    // 32768 total pixels
#define kNQKV 576           // 3*C

typedef unsigned short ushort_t;
typedef __attribute__((ext_vector_type(8))) short  s8v;   // 8 bf16 (4 VGPRs)
typedef __attribute__((ext_vector_type(4))) float  f4v;   // MFMA C/D frag

__device__ inline unsigned short bf16r(float f) {   // round-to-nearest-even
    union { float f; unsigned u; } v; v.f = f;
    unsigned u = v.u + 0x7FFFu + ((v.u >> 16) & 1u);
    return (unsigned short)(u >> 16);
}
__device__ inline float bfu(short s) {              // bf16 -> fp32
    union { unsigned u; float f; } v;
    v.u = ((unsigned)(unsigned short)s) << 16;
    return v.f;
}

// ---------------------------------------------------------------------------
// cvt_prep (round-18): x bf16 conversion + ALL weight packs, ONE dispatch.
//   [    0,12288): cvt x -> xb
//   [12288,12342): qw_pack   [12342,12360): pw_pack
//   [12360,12504): dw_tb2    [12504,12648): dw_tb3
//   [12648,12720): ow_tb2    [12720,12792): ow_tb3
// ---------------------------------------------------------------------------
__global__ void cvt_prep(const float* __restrict__ x, unsigned* __restrict__ xb,
                         const float* __restrict__ qkv_w,
                         const float* __restrict__ proj_w,
                         const float* __restrict__ def_w2,
                         const float* __restrict__ def_w3,
                         const float* __restrict__ off_w2,
                         const float* __restrict__ off_w3,
                         ushort_t* __restrict__ awb,
                         ushort_t* __restrict__ pwbp,
                         ushort_t* __restrict__ dwtb2,
                         ushort_t* __restrict__ dwtb3,
                         ushort_t* __restrict__ owtb2,
                         ushort_t* __restrict__ owtb3) {
    const int bid = blockIdx.x;
    const int tid = threadIdx.x;
    if (bid < 12288) {                    // cvt x
        int i = bid * 256 + tid;          // kM*kC/2 = 3145728
        if (i >= kM * kC / 2) return;
        float2 f = ((const float2*)x)[i];
        xb[i] = (unsigned)bf16r(f.x) | ((unsigned)bf16r(f.y) << 16);
    } else if (bid < 12342) {             // qw_pack
        int idx = (bid - 12288) * 256 + tid;
        if (idx >= 36 * 6 * 64) return;
        int lane = idx & 63;
        int kc   = (idx >> 6) % 6;
        int s    = idx / 384;
        int row  = s * 16 + (lane & 15);
        int k0   = kc * 32 + (lane >> 4) * 8;
        const float* src = qkv_w + (size_t)row * kC + k0;
        ushort_t* dst = awb + (size_t)idx * 8;
#pragma unroll
        for (int j = 0; j < 8; ++j) dst[j] = bf16r(src[j]);
    } else if (bid < 12360) {             // pw_pack
        int idx = (bid - 12342) * 256 + tid;
        if (idx >= 12 * 6 * 64) return;
        int lane = idx & 63;
        int kc   = (idx >> 6) % 6;
        int s    = idx / 384;
        int row  = s * 16 + (lane & 15);
        int k0   = kc * 32 + (lane >> 4) * 8;
        const float* src = proj_w + (size_t)row * kC + k0;
        ushort_t* dst = pwbp + (size_t)idx * 8;
#pragma unroll
        for (int j = 0; j < 8; ++j) dst[j] = bf16r(src[j]);
    } else if (bid < 12648) {             // dw_tb x2
        const float* dw = (bid < 12504) ? def_w2 : def_w3;
        ushort_t* dwtb  = (bid < 12504) ? dwtb2 : dwtb3;
        int l = ((bid < 12504) ? (bid - 12360) : (bid - 12504)) * 256 + tid;
        if (l >= kD * kD * 9) return;
        int o = l / 576;
        int c = (l / 9) % 64;
        int kk = l % 9;
        dwtb[(kk * 64 + o) * 64 + c] = bf16r(dw[l]);
    } else {                              // ow_tb x2
        const float* ow = (bid < 12720) ? off_w2 : off_w3;
        ushort_t* owtb  = (bid < 12720) ? owtb2 : owtb3;
        int l = ((bid < 12720) ? (bid - 12648) : (bid - 12720)) * 256 + tid;
        if (l >= 9 * 32 * 64) return;
        int kk = l >> 11;
        int j  = (l >> 6) & 31;
        int c  = l & 63;
        owtb[l] = (j < 18) ? bf16r(ow[j * 576 + c * 9 + kk]) : (ushort_t)0;
    }
}

// ---------------------------------------------------------------------------
// Kernel 1: QKV projection GEMM, LDS-staged (round-11, verified). UNCHANGED.
// ---------------------------------------------------------------------------
__global__ __launch_bounds__(256) void qkv_mfma3(const ushort_t* __restrict__ xb,
                                                 const ushort_t* __restrict__ awb,
                                                 ushort_t* __restrict__ qkvpx) {
    __shared__ ushort_t xs[64 * kC];            // 24576 B, swizzled rows of 384 B

    const int tid = threadIdx.x;
    const int bx  = blockIdx.x;
    const int lb  = (bx & 7) * 64 + (bx >> 3);  // XCD swizzle (G=512)
    const int m0  = lb * 64;
    const int ty3 = blockIdx.y;                 // tensor triple: channels [ty3*192, +192)

#pragma unroll
    for (int i = 0; i < 6; ++i) {
        int il = i * 256 + tid;                 // 16B chunk id, 0..1535
        int p  = il / 24;                       // pixel row in strip
        int cc = il % 24;                       // 16B chunk within row
        uint4 v = *(const uint4*)(xb + (size_t)(m0 + p) * kC + cc * 8);
        int dst = p * 384 + ((cc * 16) ^ ((p & 7) << 4));
        *(uint4*)((char*)xs + dst) = v;
    }
    __syncthreads();

    const int lane = tid & 63;
    const int wave = tid >> 6;
    const int l15  = lane & 15;
    const int q    = lane >> 4;
    const int sbase = ty3 * 12 + wave * 3;      // first of 3 N-strips for this wave

    f4v acc[3][4];
#pragma unroll
    for (int i = 0; i < 3; ++i)
#pragma unroll
        for (int m = 0; m < 4; ++m) acc[i][m] = (f4v){0.f, 0.f, 0.f, 0.f};

    const ushort_t* ap = awb + ((size_t)sbase * 6 * 64 + lane) * 8;

#pragma unroll
    for (int kc = 0; kc < 6; ++kc) {
        s8v bfr[4];
#pragma unroll
        for (int m = 0; m < 4; ++m) {
            int row = m * 16 + l15;
            int col = (kc * 64 + q * 16) ^ ((l15 & 7) << 4);
            bfr[m] = *(const s8v*)((const char*)xs + row * 384 + col);
        }
#pragma unroll
        for (int i = 0; i < 3; ++i) {
            s8v a = *(const s8v*)(ap + (size_t)(i * 6 + kc) * 64 * 8);
#pragma unroll
            for (int m = 0; m < 4; ++m)
                acc[i][m] = __builtin_amdgcn_mfma_f32_16x16x32_bf16(a, bfr[m], acc[i][m], 0, 0, 0);
        }
    }

#pragma unroll
    for (int i = 0; i < 3; ++i) {
        int s   = sbase + i;
        int ty  = s >> 2;                       // tensor 0..8
        int c64 = (s & 3) * 16 + q * 4;         // channel within tensor
        ushort_t* obase = qkvpx + (size_t)ty * kM * 64 + (size_t)m0 * 64 + c64;
#pragma unroll
        for (int m = 0; m < 4; ++m) {
            f4v v = acc[i][m];
            uint2 u;
            u.x = (unsigned)bf16r(v.x) | ((unsigned)bf16r(v.y) << 16);
            u.y = (unsigned)bf16r(v.z) | ((unsigned)bf16r(v.w) << 16);
            *(uint2*)(obase + (size_t)(m * 16 + l15) * 64) = u;
        }
    }
}

// ---------------------------------------------------------------------------
// Kernel 2 (round-18): offsets conv, BOTH dilation branches in one dispatch.
// Body identical to off_conv_mfma; branch select by block index.
// ---------------------------------------------------------------------------
__global__ __launch_bounds__(256) void off_conv_fused(const ushort_t* __restrict__ k1,
                                                      const ushort_t* __restrict__ k2,
                                                      const ushort_t* __restrict__ owtb2,
                                                      const ushort_t* __restrict__ owtb3,
                                                      const float* __restrict__ ob2,
                                                      const float* __restrict__ ob3,
                                                      float* __restrict__ offb2,
                                                      float* __restrict__ offb3) {
    const int bx = blockIdx.x;
    const int lb = (bx & 7) * 128 + (bx >> 3);  // XCD swizzle (G=1024)
    const int zb = lb >> 9;                     // 0: dil2, 1: dil3
    const int rest = lb & 511;
    const int b = rest >> 6;
    const int y = rest & 63;
    const int dil = 2 + zb;
    const ushort_t* kpx  = zb ? k2 : k1;
    const ushort_t* owtb = zb ? owtb3 : owtb2;
    const float* obias   = zb ? ob3 : ob2;
    float* offb          = zb ? offb3 : offb2;

    const int tid  = threadIdx.x;
    const int lane = tid & 63;
    const int wave = tid >> 6;
    const int l15  = lane & 15;
    const int q    = lane >> 4;
    const int px   = wave * 16 + l15;

    const ushort_t* inpx = kpx + (size_t)b * kHW * 64 + q * 8;

    f4v acc[2];
    acc[0] = (f4v){0.f, 0.f, 0.f, 0.f};
    acc[1] = (f4v){0.f, 0.f, 0.f, 0.f};

#pragma unroll
    for (int kk = 0; kk < 9; ++kk) {
        const int yy = y + (kk / 3 - 1) * dil;
        const int xx = px + (kk % 3 - 1) * dil;
        const bool valid = (yy >= 0) & (yy < kH) & (xx >= 0) & (xx < kW);
        const size_t idx = valid ? (size_t)(yy * kW + xx) * 64 : 0;
        s8v a0 = *(const s8v*)(inpx + idx);
        s8v a1 = *(const s8v*)(inpx + idx + 32);
        if (!valid) {
            a0 = (s8v){0, 0, 0, 0, 0, 0, 0, 0};
            a1 = (s8v){0, 0, 0, 0, 0, 0, 0, 0};
        }
        const ushort_t* wb = owtb + (size_t)kk * 2048 + l15 * 64 + q * 8;
#pragma unroll
        for (int nbk = 0; nbk < 2; ++nbk) {
            s8v b0 = *(const s8v*)(wb + nbk * 1024);
            s8v b1 = *(const s8v*)(wb + nbk * 1024 + 32);
            acc[nbk] = __builtin_amdgcn_mfma_f32_16x16x32_bf16(a0, b0, acc[nbk], 0, 0, 0);
            acc[nbk] = __builtin_amdgcn_mfma_f32_16x16x32_bf16(a1, b1, acc[nbk], 0, 0, 0);
        }
    }
#pragma unroll
    for (int nbk = 0; nbk < 2; ++nbk) {
        int n = nbk * 16 + l15;
        if (n < 18) {
            float bias = obias[n];
            f4v v = acc[nbk];
            v.x += bias; v.y += bias; v.z += bias; v.w += bias;
            *(f4v*)&offb[((size_t)b * 18 + n) * kHW + y * kW + wave * 16 + q * 4] = v;
        }
    }
}

// ---------------------------------------------------------------------------
// Kernel 3 (round-18): deformable conv, BOTH branches in one 1024-block
// dispatch (body = verified round-15 deform_lds, dil runtime, NR=10 max).
// Split kd/vd buffers per branch so both can live concurrently.
// ---------------------------------------------------------------------------
__global__ __launch_bounds__(512) void deform_fused(const ushort_t* __restrict__ k1,
                                                    const ushort_t* __restrict__ v1,
                                                    const ushort_t* __restrict__ k2,
                                                    const ushort_t* __restrict__ v2,
                                                    const float* __restrict__ offb2,
                                                    const float* __restrict__ offb3,
                                                    const ushort_t* __restrict__ dwtb2,
                                                    const ushort_t* __restrict__ dwtb3,
                                                    const float* __restrict__ db2,
                                                    const float* __restrict__ db3,
                                                    ushort_t* __restrict__ kd2,
                                                    ushort_t* __restrict__ vd2,
                                                    ushort_t* __restrict__ kd3,
                                                    ushort_t* __restrict__ vd3) {
    __shared__ ushort_t kv[10 * 4096];      // up to 10 rows x 8192 B, swizzled
    __shared__ ushort_t wlds[9 * 4096];     // 73728 B: dwtb copy, swizzled

    const int tid = threadIdx.x;
    const int bx  = blockIdx.x;
    const int lb  = (bx & 7) * 128 + (bx >> 3); // XCD swizzle (G=1024)
    const int zb  = lb >> 9;                // 0: dil2, 1: dil3
    const int t   = (lb >> 8) & 1;          // 0 = k, 1 = v
    const int b   = (lb >> 5) & 7;
    const int y0  = (lb & 31) * 2;          // first of 2 output rows
    const int dil = 2 + zb;
    const int nr  = 2 * dil + 4;            // staged rows (|oy|<1 window)
    const int wlo = y0 - dil - 1;

    const ushort_t* kin = zb ? k2 : k1;
    const ushort_t* vin = zb ? v2 : v1;
    const float* offbS  = zb ? offb3 : offb2;
    const ushort_t* dwtb = zb ? dwtb3 : dwtb2;
    const float* db      = zb ? db3 : db2;
    ushort_t* outk = zb ? kd3 : kd2;
    ushort_t* outv = zb ? vd3 : vd2;

    const ushort_t* inb = (t ? vin : kin) + (size_t)b * kHW * 64;
    ushort_t* outp = t ? outv : outk;

    // ---- stage weights: 9 x 512 x 16B, linear->row-swizzled ----
#pragma unroll
    for (int i = 0; i < 9; ++i) {
        int g = (i * 512 + tid) * 16;            // linear byte offset
        uint4 v = *(const uint4*)((const char*)dwtb + g);
        int row = (g >> 7) & 63;                 // o-row within kk tile
        int dst = g ^ ((row & 7) << 4);
        *(uint4*)((char*)wlds + dst) = v;
    }
    // ---- stage nr kv rows, coalesced 16B/thread, swizzled ----
    {
        int x  = tid >> 3;
        int cc = tid & 7;
        int dstc = (x * 128 + cc * 16) ^ ((x & 7) << 4);
        for (int r = 0; r < nr; ++r) {
            int gy = min(max(wlo + r, 0), kH - 1);
            *(uint4*)((char*)kv + r * 8192 + dstc) =
                *(const uint4*)(inb + (size_t)gy * 4096 + tid * 8);
        }
    }
    __syncthreads();

    const int lane = tid & 63;
    const int wave = tid >> 6;          // 0..7
    const int ry   = wave >> 2;         // output row within pair
    const int wc   = wave & 3;          // px column
    const int l15  = lane & 15;
    const int q    = lane >> 4;
    const int y    = y0 + ry;
    const int px   = wc * 16 + l15;
    const int wsw  = (l15 & 7) << 4;
    const int wcol0 = (q * 16) ^ wsw;
    const int wcol1 = (q * 16 + 64) ^ wsw;

    const ushort_t* inpx = inb + q * 8; // global fallback base

    f4v acc[4];
#pragma unroll
    for (int ob = 0; ob < 4; ++ob) acc[ob] = (f4v){0.f, 0.f, 0.f, 0.f};

    const float* offrow = offbS + (size_t)b * 18 * kHW + y * kW + px;
    float offv[18];
#pragma unroll
    for (int i = 0; i < 18; ++i) offv[i] = offrow[(size_t)i * kHW];

#pragma unroll
    for (int kk = 0; kk < 9; ++kk) {
        float oy = offv[kk * 2 + 0];
        float ox = offv[kk * 2 + 1];
        float py  = (float)y  + (float)((kk / 3 - 1) * dil) + oy;
        float pxf = (float)px + (float)((kk % 3 - 1) * dil) + ox;
        float fy = floorf(py), fx = floorf(pxf);
        float wy = py - fy, wx = pxf - fx;
        int iy0 = (int)fy, ix0 = (int)fx;
        int iy1 = iy0 + 1, ix1 = ix0 + 1;
        int y0c = min(max(iy0, 0), kH - 1), x0c = min(max(ix0, 0), kW - 1);
        int y1c = min(max(iy1, 0), kH - 1), x1c = min(max(ix1, 0), kW - 1);
        bool vy0 = (iy0 >= 0) & (iy0 < kH), vx0 = (ix0 >= 0) & (ix0 < kW);
        bool vy1 = (iy1 >= 0) & (iy1 < kH), vx1 = (ix1 >= 0) & (ix1 < kW);
        float w0 = (vy0 && vx0) ? (1.f - wy) * (1.f - wx) : 0.f;
        float w1 = (vy0 && vx1) ? (1.f - wy) * wx : 0.f;
        float w2 = (vy1 && vx0) ? wy * (1.f - wx) : 0.f;
        float w3 = (vy1 && vx1) ? wy * wx : 0.f;

        s8v c[8];
        if (__builtin_expect(fabsf(oy) < 1.0f, 1)) {
            int r0 = min(max(y0c - wlo, 0), nr - 1);
            int r1 = min(max(y1c - wlo, 0), nr - 1);
            int b00 = r0 * 8192 + ((x0c * 128 + q * 16) ^ ((x0c & 7) << 4));
            int b00h = r0 * 8192 + ((x0c * 128 + q * 16 + 64) ^ ((x0c & 7) << 4));
            int b01 = r0 * 8192 + ((x1c * 128 + q * 16) ^ ((x1c & 7) << 4));
            int b01h = r0 * 8192 + ((x1c * 128 + q * 16 + 64) ^ ((x1c & 7) << 4));
            int b10 = r1 * 8192 + ((x0c * 128 + q * 16) ^ ((x0c & 7) << 4));
            int b10h = r1 * 8192 + ((x0c * 128 + q * 16 + 64) ^ ((x0c & 7) << 4));
            int b11 = r1 * 8192 + ((x1c * 128 + q * 16) ^ ((x1c & 7) << 4));
            int b11h = r1 * 8192 + ((x1c * 128 + q * 16 + 64) ^ ((x1c & 7) << 4));
            c[0] = *(const s8v*)((const char*)kv + b00);
            c[1] = *(const s8v*)((const char*)kv + b00h);
            c[2] = *(const s8v*)((const char*)kv + b01);
            c[3] = *(const s8v*)((const char*)kv + b01h);
            c[4] = *(const s8v*)((const char*)kv + b10);
            c[5] = *(const s8v*)((const char*)kv + b10h);
            c[6] = *(const s8v*)((const char*)kv + b11);
            c[7] = *(const s8v*)((const char*)kv + b11h);
        } else {
            size_t i00 = (size_t)(y0c * kW + x0c) * 64;
            size_t i01 = (size_t)(y0c * kW + x1c) * 64;
            size_t i10 = (size_t)(y1c * kW + x0c) * 64;
            size_t i11 = (size_t)(y1c * kW + x1c) * 64;
            c[0] = *(const s8v*)(inpx + i00);
            c[1] = *(const s8v*)(inpx + i00 + 32);
            c[2] = *(const s8v*)(inpx + i01);
            c[3] = *(const s8v*)(inpx + i01 + 32);
            c[4] = *(const s8v*)(inpx + i10);
            c[5] = *(const s8v*)(inpx + i10 + 32);
            c[6] = *(const s8v*)(inpx + i11);
            c[7] = *(const s8v*)(inpx + i11 + 32);
        }

        s8v b0, b1;
#pragma unroll
        for (int j = 0; j < 8; ++j) {
            float v0 = w0 * bfu(c[0][j]) + w1 * bfu(c[2][j]) +
                       w2 * bfu(c[4][j]) + w3 * bfu(c[6][j]);
            float v1 = w0 * bfu(c[1][j]) + w1 * bfu(c[3][j]) +
                       w2 * bfu(c[5][j]) + w3 * bfu(c[7][j]);
            b0[j] = (short)bf16r(v0);
            b1[j] = (short)bf16r(v1);
        }
        const char* wkk = (const char*)wlds + kk * 8192 + l15 * 128;
#pragma unroll
        for (int obb = 0; obb < 4; ++obb) {
            s8v a0w = *(const s8v*)(wkk + obb * 2048 + wcol0);
            s8v a1w = *(const s8v*)(wkk + obb * 2048 + wcol1);
            acc[obb] = __builtin_amdgcn_mfma_f32_16x16x32_bf16(a0w, b0, acc[obb], 0, 0, 0);
            acc[obb] = __builtin_amdgcn_mfma_f32_16x16x32_bf16(a1w, b1, acc[obb], 0, 0, 0);
        }
    }

    ushort_t* orow = outp + ((size_t)b * kHW + y * kW + px) * 64 + q * 4;
#pragma unroll
    for (int obb = 0; obb < 4; ++obb) {
        float4 bias = *(const float4*)&db[obb * 16 + q * 4];
        f4v v = acc[obb];
        uint2 u;
        u.x = (unsigned)bf16r(v.x + bias.x) | ((unsigned)bf16r(v.y + bias.y) << 16);
        u.y = (unsigned)bf16r(v.z + bias.z) | ((unsigned)bf16r(v.w + bias.w) << 16);
        *(uint2*)(orow + obb * 16) = u;
    }
}

// ---------------------------------------------------------------------------
// Kernel 4 (round-18): 9-tap local attention, ALL 3 branches in one
// 768-block dispatch (body = round-17 attn_lds, dil runtime, NR=8 max).
// ---------------------------------------------------------------------------
__global__ __launch_bounds__(512) void attn_fused(const ushort_t* __restrict__ q0,
                                                  const ushort_t* __restrict__ k0,
                                                  const ushort_t* __restrict__ v0,
                                                  const ushort_t* __restrict__ q1,
                                                  const ushort_t* __restrict__ kd2,
                                                  const ushort_t* __restrict__ vd2,
                                                  const ushort_t* __restrict__ q2,
                                                  const ushort_t* __restrict__ kd3,
                                                  const ushort_t* __restrict__ vd3,
                                                  ushort_t* __restrict__ aopx) {
    __shared__ ushort_t ks[8 * 4096];       // up to 8 rows x 8192 B, swizzled
    __shared__ ushort_t vs[8 * 4096];

    const int tid = threadIdx.x;
    const int bx  = blockIdx.x;
    const int lb  = (bx & 7) * 96 + (bx >> 3);  // XCD swizzle (G=768)
    const int zb  = lb >> 8;                // branch 0,1,2
    const int rest = lb & 255;
    const int b   = rest >> 5;
    const int y0  = (rest & 31) * 2;        // first of 2 output rows
    const int dil = zb + 1;
    const int nr  = 2 * dil + 2;            // staged rows
    const int wlo = y0 - dil;

    const ushort_t* qpx = (zb == 0) ? q0 : (zb == 1) ? q1 : q2;
    const ushort_t* kpx = (zb == 0) ? k0 : (zb == 1) ? kd2 : kd3;
    const ushort_t* vpx = (zb == 0) ? v0 : (zb == 1) ? vd2 : vd3;

    const size_t pbase = (size_t)b * kHW;
    const ushort_t* kb = kpx + pbase * 64;
    const ushort_t* vb = vpx + pbase * 64;

    // ---- stage nr rows of k AND v, 16B/thread/row, swizzled ----
    {
        int x  = tid >> 3;
        int cc = tid & 7;
        int dstc = (x * 128 + cc * 16) ^ ((x & 7) << 4);
        for (int r = 0; r < nr; ++r) {
            int gy = min(max(wlo + r, 0), kH - 1);
            *(uint4*)((char*)ks + r * 8192 + dstc) = *(const uint4*)(kb + (size_t)gy * 4096 + tid * 8);
            *(uint4*)((char*)vs + r * 8192 + dstc) = *(const uint4*)(vb + (size_t)gy * 4096 + tid * 8);
        }
    }
    __syncthreads();

    const int wave = tid >> 6;          // 0..7
    const int l    = tid & 63;
    const int ry   = wave >> 2;         // row within pair
    const int wc   = wave & 3;          // 16-px column group
    const int pxq  = l >> 2;            // 16 pixels per wave
    const int cg   = l & 3;             // 4 channel-groups of 16 ch
    const int y  = y0 + ry;
    const int x_ = wc * 16 + pxq;
    const int p  = y * kW + x_;

    const ushort_t* qb = qpx + (pbase + p) * 64 + cg * 16;
    s8v qv0 = *(const s8v*)qb;
    s8v qv1 = *(const s8v*)(qb + 8);
    float qf[16];
#pragma unroll
    for (int j = 0; j < 8; ++j) { qf[j] = bfu(qv0[j]); qf[8 + j] = bfu(qv1[j]); }

    int a0s[9], a1s[9];
    float msk[9];
#pragma unroll
    for (int kk = 0; kk < 9; ++kk) {
        int dy = (kk / 3 - 1) * dil, dx = (kk % 3 - 1) * dil;
        int yy = y + dy, xx = x_ + dx;
        bool v = (yy >= 0) & (yy < kH) & (xx >= 0) & (xx < kW);
        msk[kk] = v ? 1.f : 0.f;
        int r  = min(max(yy - wlo, 0), nr - 1);
        int xc = min(max(xx, 0), kW - 1);
        int sw = (xc & 7) << 4;
        a0s[kk] = r * 8192 + ((xc * 128 + cg * 32) ^ sw);
        a1s[kk] = r * 8192 + ((xc * 128 + cg * 32 + 16) ^ sw);
    }

    float e[9];
#pragma unroll
    for (int kk = 0; kk < 9; ++kk) {
        s8v k0v = *(const s8v*)((const char*)ks + a0s[kk]);
        s8v k1v = *(const s8v*)((const char*)ks + a1s[kk]);
        float s = 0.f;
#pragma unroll
        for (int j = 0; j < 8; ++j) {
            s += qf[j] * bfu(k0v[j]);
            s += qf[8 + j] * bfu(k1v[j]);
        }
        s += __shfl_xor(s, 1);
        s += __shfl_xor(s, 2);
        e[kk] = s * 0.125f * msk[kk];
    }
    float mx = -1e30f;
#pragma unroll
    for (int kk = 0; kk < 9; ++kk) mx = fmaxf(mx, e[kk]);
    float ssum = 0.f;
#pragma unroll
    for (int kk = 0; kk < 9; ++kk) { e[kk] = __expf(e[kk] - mx); ssum += e[kk]; }
    float inv = 1.f / ssum;
#pragma unroll
    for (int kk = 0; kk < 9; ++kk) e[kk] = e[kk] * inv * msk[kk];

    float acc[16];
#pragma unroll
    for (int j = 0; j < 16; ++j) acc[j] = 0.f;
#pragma unroll
    for (int kk = 0; kk < 9; ++kk) {
        s8v v0v = *(const s8v*)((const char*)vs + a0s[kk]);
        s8v v1v = *(const s8v*)((const char*)vs + a1s[kk]);
        float w = e[kk];
#pragma unroll
        for (int j = 0; j < 8; ++j) {
            acc[j] += w * bfu(v0v[j]);
            acc[8 + j] += w * bfu(v1v[j]);
        }
    }
    unsigned u[8];
#pragma unroll
    for (int i = 0; i < 8; ++i)
        u[i] = (unsigned)bf16r(acc[2 * i]) | ((unsigned)bf16r(acc[2 * i + 1]) << 16);
    ushort_t* ob = aopx + (pbase + p) * kC + zb * 64 + cg * 16;
    *(uint4*)ob = make_uint4(u[0], u[1], u[2], u[3]);
    *(uint4*)(ob + 8) = make_uint4(u[4], u[5], u[6], u[7]);
}

// ---------------------------------------------------------------------------
// Kernel 5 (round-16, verified): output projection, LDS-staged GEMM. UNCHANGED.
// ---------------------------------------------------------------------------
__global__ __launch_bounds__(256) void proj_mfma3(const ushort_t* __restrict__ aopx,
                                                  const ushort_t* __restrict__ pwbp,
                                                  const float* __restrict__ pb,
                                                  float* __restrict__ out) {
    __shared__ ushort_t xs[64 * kC];            // 24576 B, swizzled rows of 384 B

    const int tid = threadIdx.x;
    const int bx  = blockIdx.x;
    const int lb  = (bx & 7) * 64 + (bx >> 3);  // XCD swizzle (G=512)
    const int m0  = lb * 64;

#pragma unroll
    for (int i = 0; i < 6; ++i) {
        int il = i * 256 + tid;                 // 16B chunk id, 0..1535
        int p  = il / 24;                       // pixel row in strip
        int cc = il % 24;                       // 16B chunk within row
        uint4 v = *(const uint4*)(aopx + (size_t)(m0 + p) * kC + cc * 8);
        int dst = p * 384 + ((cc * 16) ^ ((p & 7) << 4));
        *(uint4*)((char*)xs + dst) = v;
    }
    __syncthreads();

    const int lane = tid & 63;
    const int wave = tid >> 6;
    const int l15  = lane & 15;
    const int q    = lane >> 4;
    const int sbase = wave * 3;                 // strips 0..11, 3 per wave

    f4v acc[3][4];
#pragma unroll
    for (int i = 0; i < 3; ++i)
#pragma unroll
        for (int m = 0; m < 4; ++m) acc[i][m] = (f4v){0.f, 0.f, 0.f, 0.f};

    const ushort_t* ap = pwbp + ((size_t)sbase * 6 * 64 + lane) * 8;

#pragma unroll
    for (int kc = 0; kc < 6; ++kc) {
        s8v bfr[4];
#pragma unroll
        for (int m = 0; m < 4; ++m) {
            int row = m * 16 + l15;
            int col = (kc * 64 + q * 16) ^ ((l15 & 7) << 4);
            bfr[m] = *(const s8v*)((const char*)xs + row * 384 + col);
        }
#pragma unroll
        for (int i = 0; i < 3; ++i) {
            s8v a = *(const s8v*)(ap + (size_t)(i * 6 + kc) * 64 * 8);
#pragma unroll
            for (int m = 0; m < 4; ++m)
                acc[i][m] = __builtin_amdgcn_mfma_f32_16x16x32_bf16(a, bfr[m], acc[i][m], 0, 0, 0);
        }
    }

#pragma unroll
    for (int i = 0; i < 3; ++i) {
        int s  = sbase + i;
        int n0 = s * 16 + q * 4;
        float4 bias = *(const float4*)&pb[n0];
#pragma unroll
        for (int m = 0; m < 4; ++m) {
            f4v v = acc[i][m];
            v.x += bias.x; v.y += bias.y; v.z += bias.z; v.w += bias.w;
            *(f4v*)&out[(size_t)(m0 + m * 16 + l15) * kC + n0] = v;
        }
    }
}

// ---------------------------------------------------------------------------
// Host launcher.  Workspace ~85 MB (offb x2, kd/vd x2 branches).
// 6 dispatches: cvt_prep, qkv, off_fused, deform_fused, attn_fused, proj.
// ---------------------------------------------------------------------------
extern "C" void kernel_launch(void* const* d_in, const int* in_sizes, int n_in,
                              void* d_out, int out_size, void* d_ws, size_t ws_size,
                              hipStream_t stream) {
    const float* x      = (const float*)d_in[0];
    const float* qkv_w  = (const float*)d_in[1];
    const float* proj_w = (const float*)d_in[2];
    const float* proj_b = (const float*)d_in[3];
    const float* off_w2 = (const float*)d_in[4];
    const float* off_b2 = (const float*)d_in[5];
    const float* def_w2 = (const float*)d_in[6];
    const float* def_b2 = (const float*)d_in[7];
    const float* off_w3 = (const float*)d_in[8];
    const float* off_b3 = (const float*)d_in[9];
    const float* def_w3 = (const float*)d_in[10];
    const float* def_b3 = (const float*)d_in[11];
    float* out = (float*)d_out;

    float* ws    = (float*)d_ws;
    float* offb2 = ws;                              // 18 * M
    float* offb3 = offb2 + (size_t)18 * kM;         // 18 * M
    ushort_t* us = (ushort_t*)(offb3 + (size_t)18 * kM);
    ushort_t* xb     = us;  us += (size_t)kM * kC;
    ushort_t* qkvpx  = us;  us += (size_t)9 * kM * 64;
    ushort_t* kd2    = us;  us += (size_t)kM * 64;
    ushort_t* vd2    = us;  us += (size_t)kM * 64;
    ushort_t* kd3    = us;  us += (size_t)kM * 64;
    ushort_t* vd3    = us;  us += (size_t)kM * 64;
    ushort_t* aopx   = us;  us += (size_t)kM * kC;
    ushort_t* awb    = us;  us += (size_t)kNQKV * kC;   // 36*6*64*8 == 576*192
    ushort_t* pwbp   = us;  us += (size_t)kC * kC;      // 12*6*64*8 == 192*192
    ushort_t* dwtb2  = us;  us += kD * kD * 9;
    ushort_t* dwtb3  = us;  us += kD * kD * 9;
    ushort_t* owtb2  = us;  us += 9 * 32 * 64;
    ushort_t* owtb3  = us;  us += 9 * 32 * 64;

    // 0. x conversion + all weight packs (one dispatch)
    cvt_prep<<<12792, 256, 0, stream>>>(x, (unsigned*)xb, qkv_w, proj_w,
                                        def_w2, def_w3, off_w2, off_w3,
                                        awb, pwbp, dwtb2, dwtb3, owtb2, owtb3);

    // per-tensor pixel-major slices
    ushort_t* q0 = qkvpx;
    ushort_t* q1 = qkvpx + (size_t)1 * kM * 64;
    ushort_t* q2 = qkvpx + (size_t)2 * kM * 64;
    ushort_t* k0 = qkvpx + (size_t)3 * kM * 64;
    ushort_t* k1 = qkvpx + (size_t)4 * kM * 64;
    ushort_t* k2 = qkvpx + (size_t)5 * kM * 64;
    ushort_t* v0 = qkvpx + (size_t)6 * kM * 64;
    ushort_t* v1 = qkvpx + (size_t)7 * kM * 64;
    ushort_t* v2 = qkvpx + (size_t)8 * kM * 64;

    // 1. QKV projection -> 9 bf16 pixel-major tensors (LDS-staged GEMM)
    qkv_mfma3<<<dim3(kM / 64, 3), 256, 0, stream>>>(xb, awb, qkvpx);

    // 2. offsets conv, both branches (one dispatch)
    off_conv_fused<<<1024, 256, 0, stream>>>(k1, k2, owtb2, owtb3,
                                             off_b2, off_b3, offb2, offb3);

    // 3. deformable conv, both branches (one dispatch)
    deform_fused<<<1024, 512, 0, stream>>>(k1, v1, k2, v2, offb2, offb3,
                                           dwtb2, dwtb3, def_b2, def_b3,
                                           kd2, vd2, kd3, vd3);

    // 4. attention, all three branches (one dispatch)
    attn_fused<<<768, 512, 0, stream>>>(q0, k0, v0, q1, kd2, vd2, q2, kd3, vd3, aopx);

    // 5. output projection (LDS-staged bf16 MFMA, fp32 out)
    proj_mfma3<<<512, 256, 0, stream>>>(aopx, pwbp, proj_b, out);
}

// Round 10
// 209.884 us; speedup vs baseline: 1.5905x; 1.0452x over previous
//
#include <hip/hip_runtime.h>
#include <cmath>

// ---------------------------------------------------------------------------
// Problem constants (B=8, H=W=64, C=192, 3 dilation branches of d=64, heads=64)
// ---------------------------------------------------------------------------
#define kB    8
#define kH    64
#define kW    64
#define kHW   4096          // H*W
#define kC    192
#define kD    64            // channels per dilation branch == head_dim
#define kM    (kB * kHW)    // 32768 total pixels
#define kNQKV 576           // 3*C

typedef unsigned short ushort_t;
typedef __attribute__((ext_vector_type(8))) short  s8v;   // 8 bf16 (4 VGPRs)
typedef __attribute__((ext_vector_type(4))) float  f4v;   // MFMA C/D frag

__device__ inline unsigned short bf16r(float f) {   // round-to-nearest-even
    union { float f; unsigned u; } v; v.f = f;
    unsigned u = v.u + 0x7FFFu + ((v.u >> 16) & 1u);
    return (unsigned short)(u >> 16);
}
__device__ inline float bfu(short s) {              // bf16 -> fp32
    union { unsigned u; float f; } v;
    v.u = ((unsigned)(unsigned short)s) << 16;
    return v.f;
}

// ---------------------------------------------------------------------------
// cvt_prep: x bf16 conversion + ALL weight packs, ONE dispatch (verified).
// ---------------------------------------------------------------------------
__global__ void cvt_prep(const float* __restrict__ x, unsigned* __restrict__ xb,
                         const float* __restrict__ qkv_w,
                         const float* __restrict__ proj_w,
                         const float* __restrict__ def_w2,
                         const float* __restrict__ def_w3,
                         const float* __restrict__ off_w2,
                         const float* __restrict__ off_w3,
                         ushort_t* __restrict__ awb,
                         ushort_t* __restrict__ pwbp,
                         ushort_t* __restrict__ dwtb2,
                         ushort_t* __restrict__ dwtb3,
                         ushort_t* __restrict__ owtb2,
                         ushort_t* __restrict__ owtb3) {
    const int bid = blockIdx.x;
    const int tid = threadIdx.x;
    if (bid < 12288) {                    // cvt x
        int i = bid * 256 + tid;          // kM*kC/2 = 3145728
        if (i >= kM * kC / 2) return;
        float2 f = ((const float2*)x)[i];
        xb[i] = (unsigned)bf16r(f.x) | ((unsigned)bf16r(f.y) << 16);
    } else if (bid < 12342) {             // qw_pack
        int idx = (bid - 12288) * 256 + tid;
        if (idx >= 36 * 6 * 64) return;
        int lane = idx & 63;
        int kc   = (idx >> 6) % 6;
        int s    = idx / 384;
        int row  = s * 16 + (lane & 15);
        int k0   = kc * 32 + (lane >> 4) * 8;
        const float* src = qkv_w + (size_t)row * kC + k0;
        ushort_t* dst = awb + (size_t)idx * 8;
#pragma unroll
        for (int j = 0; j < 8; ++j) dst[j] = bf16r(src[j]);
    } else if (bid < 12360) {             // pw_pack
        int idx = (bid - 12342) * 256 + tid;
        if (idx >= 12 * 6 * 64) return;
        int lane = idx & 63;
        int kc   = (idx >> 6) % 6;
        int s    = idx / 384;
        int row  = s * 16 + (lane & 15);
        int k0   = kc * 32 + (lane >> 4) * 8;
        const float* src = proj_w + (size_t)row * kC + k0;
        ushort_t* dst = pwbp + (size_t)idx * 8;
#pragma unroll
        for (int j = 0; j < 8; ++j) dst[j] = bf16r(src[j]);
    } else if (bid < 12648) {             // dw_tb x2
        const float* dw = (bid < 12504) ? def_w2 : def_w3;
        ushort_t* dwtb  = (bid < 12504) ? dwtb2 : dwtb3;
        int l = ((bid < 12504) ? (bid - 12360) : (bid - 12504)) * 256 + tid;
        if (l >= kD * kD * 9) return;
        int o = l / 576;
        int c = (l / 9) % 64;
        int kk = l % 9;
        dwtb[(kk * 64 + o) * 64 + c] = bf16r(dw[l]);
    } else {                              // ow_tb x2
        const float* ow = (bid < 12720) ? off_w2 : off_w3;
        ushort_t* owtb  = (bid < 12720) ? owtb2 : owtb3;
        int l = ((bid < 12720) ? (bid - 12648) : (bid - 12720)) * 256 + tid;
        if (l >= 9 * 32 * 64) return;
        int kk = l >> 11;
        int j  = (l >> 6) & 31;
        int c  = l & 63;
        owtb[l] = (j < 18) ? bf16r(ow[j * 576 + c * 9 + kk]) : (ushort_t)0;
    }
}

// ---------------------------------------------------------------------------
// Kernel 1: QKV projection GEMM, LDS-staged (verified). UNCHANGED.
// ---------------------------------------------------------------------------
__global__ __launch_bounds__(256) void qkv_mfma3(const ushort_t* __restrict__ xb,
                                                 const ushort_t* __restrict__ awb,
                                                 ushort_t* __restrict__ qkvpx) {
    __shared__ ushort_t xs[64 * kC];            // 24576 B, swizzled rows of 384 B

    const int tid = threadIdx.x;
    const int bx  = blockIdx.x;
    const int lb  = (bx & 7) * 64 + (bx >> 3);  // XCD swizzle (G=512)
    const int m0  = lb * 64;
    const int ty3 = blockIdx.y;                 // tensor triple: channels [ty3*192, +192)

#pragma unroll
    for (int i = 0; i < 6; ++i) {
        int il = i * 256 + tid;                 // 16B chunk id, 0..1535
        int p  = il / 24;                       // pixel row in strip
        int cc = il % 24;                       // 16B chunk within row
        uint4 v = *(const uint4*)(xb + (size_t)(m0 + p) * kC + cc * 8);
        int dst = p * 384 + ((cc * 16) ^ ((p & 7) << 4));
        *(uint4*)((char*)xs + dst) = v;
    }
    __syncthreads();

    const int lane = tid & 63;
    const int wave = tid >> 6;
    const int l15  = lane & 15;
    const int q    = lane >> 4;
    const int sbase = ty3 * 12 + wave * 3;      // first of 3 N-strips for this wave

    f4v acc[3][4];
#pragma unroll
    for (int i = 0; i < 3; ++i)
#pragma unroll
        for (int m = 0; m < 4; ++m) acc[i][m] = (f4v){0.f, 0.f, 0.f, 0.f};

    const ushort_t* ap = awb + ((size_t)sbase * 6 * 64 + lane) * 8;

#pragma unroll
    for (int kc = 0; kc < 6; ++kc) {
        s8v bfr[4];
#pragma unroll
        for (int m = 0; m < 4; ++m) {
            int row = m * 16 + l15;
            int col = (kc * 64 + q * 16) ^ ((l15 & 7) << 4);
            bfr[m] = *(const s8v*)((const char*)xs + row * 384 + col);
        }
#pragma unroll
        for (int i = 0; i < 3; ++i) {
            s8v a = *(const s8v*)(ap + (size_t)(i * 6 + kc) * 64 * 8);
#pragma unroll
            for (int m = 0; m < 4; ++m)
                acc[i][m] = __builtin_amdgcn_mfma_f32_16x16x32_bf16(a, bfr[m], acc[i][m], 0, 0, 0);
        }
    }

#pragma unroll
    for (int i = 0; i < 3; ++i) {
        int s   = sbase + i;
        int ty  = s >> 2;                       // tensor 0..8
        int c64 = (s & 3) * 16 + q * 4;         // channel within tensor
        ushort_t* obase = qkvpx + (size_t)ty * kM * 64 + (size_t)m0 * 64 + c64;
#pragma unroll
        for (int m = 0; m < 4; ++m) {
            f4v v = acc[i][m];
            uint2 u;
            u.x = (unsigned)bf16r(v.x) | ((unsigned)bf16r(v.y) << 16);
            u.y = (unsigned)bf16r(v.z) | ((unsigned)bf16r(v.w) << 16);
            *(uint2*)(obase + (size_t)(m * 16 + l15) * 64) = u;
        }
    }
}

// ---------------------------------------------------------------------------
// Kernel 2: offsets conv, both branches fused (round-18). UNCHANGED.
// ---------------------------------------------------------------------------
__global__ __launch_bounds__(256) void off_conv_fused(const ushort_t* __restrict__ k1,
                                                      const ushort_t* __restrict__ k2,
                                                      const ushort_t* __restrict__ owtb2,
                                                      const ushort_t* __restrict__ owtb3,
                                                      const float* __restrict__ ob2,
                                                      const float* __restrict__ ob3,
                                                      float* __restrict__ offb2,
                                                      float* __restrict__ offb3) {
    const int bx = blockIdx.x;
    const int lb = (bx & 7) * 128 + (bx >> 3);  // XCD swizzle (G=1024)
    const int zb = lb >> 9;                     // 0: dil2, 1: dil3
    const int rest = lb & 511;
    const int b = rest >> 6;
    const int y = rest & 63;
    const int dil = 2 + zb;
    const ushort_t* kpx  = zb ? k2 : k1;
    const ushort_t* owtb = zb ? owtb3 : owtb2;
    const float* obias   = zb ? ob3 : ob2;
    float* offb          = zb ? offb3 : offb2;

    const int tid  = threadIdx.x;
    const int lane = tid & 63;
    const int wave = tid >> 6;
    const int l15  = lane & 15;
    const int q    = lane >> 4;
    const int px   = wave * 16 + l15;

    const ushort_t* inpx = kpx + (size_t)b * kHW * 64 + q * 8;

    f4v acc[2];
    acc[0] = (f4v){0.f, 0.f, 0.f, 0.f};
    acc[1] = (f4v){0.f, 0.f, 0.f, 0.f};

#pragma unroll
    for (int kk = 0; kk < 9; ++kk) {
        const int yy = y + (kk / 3 - 1) * dil;
        const int xx = px + (kk % 3 - 1) * dil;
        const bool valid = (yy >= 0) & (yy < kH) & (xx >= 0) & (xx < kW);
        const size_t idx = valid ? (size_t)(yy * kW + xx) * 64 : 0;
        s8v a0 = *(const s8v*)(inpx + idx);
        s8v a1 = *(const s8v*)(inpx + idx + 32);
        if (!valid) {
            a0 = (s8v){0, 0, 0, 0, 0, 0, 0, 0};
            a1 = (s8v){0, 0, 0, 0, 0, 0, 0, 0};
        }
        const ushort_t* wb = owtb + (size_t)kk * 2048 + l15 * 64 + q * 8;
#pragma unroll
        for (int nbk = 0; nbk < 2; ++nbk) {
            s8v b0 = *(const s8v*)(wb + nbk * 1024);
            s8v b1 = *(const s8v*)(wb + nbk * 1024 + 32);
            acc[nbk] = __builtin_amdgcn_mfma_f32_16x16x32_bf16(a0, b0, acc[nbk], 0, 0, 0);
            acc[nbk] = __builtin_amdgcn_mfma_f32_16x16x32_bf16(a1, b1, acc[nbk], 0, 0, 0);
        }
    }
#pragma unroll
    for (int nbk = 0; nbk < 2; ++nbk) {
        int n = nbk * 16 + l15;
        if (n < 18) {
            float bias = obias[n];
            f4v v = acc[nbk];
            v.x += bias; v.y += bias; v.z += bias; v.w += bias;
            *(f4v*)&offb[((size_t)b * 18 + n) * kHW + y * kW + wave * 16 + q * 4] = v;
        }
    }
}

// ---------------------------------------------------------------------------
// Kernel 3 (round-19): deformable conv, 16-WAVE blocks for occupancy.
// Round-18 counters: 56.8us, VALUBusy 47%, Occupancy 16% (152KB LDS -> 1
// block/CU = 2 waves/SIMD): bilinear VALU can't overlap LDS latency.
// Now: block = 1024 thr (16 waves = 4 rows x 4 px-cols) over 4 output rows;
// weights staged in TWO phases (kk 0-4 then restage kk 5-8) -> LDS =
// kv 96KB (nr=2*dil+6) + w 40KB = 136KB, 16 waves/CU = 4 waves/SIMD (2x).
// Grid 512 (both branches, k/v split). Per-wave body identical to verified
// round-15 deform_lds.
// ---------------------------------------------------------------------------
__global__ __launch_bounds__(1024) void deform_big(const ushort_t* __restrict__ k1,
                                                   const ushort_t* __restrict__ v1,
                                                   const ushort_t* __restrict__ k2,
                                                   const ushort_t* __restrict__ v2,
                                                   const float* __restrict__ offb2,
                                                   const float* __restrict__ offb3,
                                                   const ushort_t* __restrict__ dwtb2,
                                                   const ushort_t* __restrict__ dwtb3,
                                                   const float* __restrict__ db2,
                                                   const float* __restrict__ db3,
                                                   ushort_t* __restrict__ kd2,
                                                   ushort_t* __restrict__ vd2,
                                                   ushort_t* __restrict__ kd3,
                                                   ushort_t* __restrict__ vd3) {
    __shared__ ushort_t kv[12 * 4096];      // up to 12 rows x 8192 B, swizzled (96KB)
    __shared__ ushort_t wlds[5 * 4096];     // 40KB: 5 kk tiles, two-phase

    const int tid = threadIdx.x;
    const int bx  = blockIdx.x;
    const int lb  = (bx & 7) * 64 + (bx >> 3);  // XCD swizzle (G=512)
    const int zb  = lb >> 8;                // 0: dil2, 1: dil3
    const int t   = (lb >> 7) & 1;          // 0 = k, 1 = v
    const int b   = (lb >> 4) & 7;
    const int y0  = (lb & 15) * 4;          // first of 4 output rows
    const int dil = 2 + zb;
    const int nr  = 2 * dil + 6;            // staged rows (|oy|<1, 4 rows)
    const int wlo = y0 - dil - 1;

    const ushort_t* kin = zb ? k2 : k1;
    const ushort_t* vin = zb ? v2 : v1;
    const float* offbS  = zb ? offb3 : offb2;
    const ushort_t* dwtb = zb ? dwtb3 : dwtb2;
    const float* db      = zb ? db3 : db2;
    ushort_t* outp = t ? (zb ? vd3 : vd2) : (zb ? kd3 : kd2);

    const ushort_t* inb = (t ? vin : kin) + (size_t)b * kHW * 64;

    // ---- stage nr kv rows: 1024 thr = 2 rows/pass, swizzled ----
    {
        int half  = tid >> 9;               // 0/1: row within pass
        int chunk = tid & 511;              // 16B chunk within row
        int xcol  = chunk >> 3;
        int cc    = chunk & 7;
        int dstc  = (xcol * 128 + cc * 16) ^ ((xcol & 7) << 4);
        for (int r0 = 0; r0 < nr; r0 += 2) {
            int r = r0 + half;
            if (r < nr) {
                int gy = min(max(wlo + r, 0), kH - 1);
                *(uint4*)((char*)kv + r * 8192 + dstc) =
                    *(const uint4*)(inb + (size_t)gy * 4096 + chunk * 8);
            }
        }
    }
    // ---- stage weights phase A: kk 0-4 (40960 B) ----
    for (int i = tid; i < 2560; i += 1024) {
        int g = i * 16;
        uint4 v = *(const uint4*)((const char*)dwtb + g);
        int row = (g >> 7) & 63;
        *(uint4*)((char*)wlds + (g ^ ((row & 7) << 4))) = v;
    }
    __syncthreads();

    const int lane = tid & 63;
    const int wave = tid >> 6;          // 0..15
    const int ry   = wave >> 2;         // output row within quad
    const int wc   = wave & 3;          // px column
    const int l15  = lane & 15;
    const int q    = lane >> 4;
    const int y    = y0 + ry;
    const int px   = wc * 16 + l15;
    const int wsw  = (l15 & 7) << 4;
    const int wcol0 = (q * 16) ^ wsw;
    const int wcol1 = (q * 16 + 64) ^ wsw;

    const ushort_t* inpx = inb + q * 8; // global fallback base

    f4v acc[4];
#pragma unroll
    for (int ob = 0; ob < 4; ++ob) acc[ob] = (f4v){0.f, 0.f, 0.f, 0.f};

    const float* offrow = offbS + (size_t)b * 18 * kHW + y * kW + px;
    float offv[18];
#pragma unroll
    for (int i = 0; i < 18; ++i) offv[i] = offrow[(size_t)i * kHW];

    auto do_tap = [&](int kk, int kkbase) {
        float oy = offv[kk * 2 + 0];
        float ox = offv[kk * 2 + 1];
        float py  = (float)y  + (float)((kk / 3 - 1) * dil) + oy;
        float pxf = (float)px + (float)((kk % 3 - 1) * dil) + ox;
        float fy = floorf(py), fx = floorf(pxf);
        float wy = py - fy, wx = pxf - fx;
        int iy0 = (int)fy, ix0 = (int)fx;
        int iy1 = iy0 + 1, ix1 = ix0 + 1;
        int y0c = min(max(iy0, 0), kH - 1), x0c = min(max(ix0, 0), kW - 1);
        int y1c = min(max(iy1, 0), kH - 1), x1c = min(max(ix1, 0), kW - 1);
        bool vy0 = (iy0 >= 0) & (iy0 < kH), vx0 = (ix0 >= 0) & (ix0 < kW);
        bool vy1 = (iy1 >= 0) & (iy1 < kH), vx1 = (ix1 >= 0) & (ix1 < kW);
        float w0 = (vy0 && vx0) ? (1.f - wy) * (1.f - wx) : 0.f;
        float w1 = (vy0 && vx1) ? (1.f - wy) * wx : 0.f;
        float w2 = (vy1 && vx0) ? wy * (1.f - wx) : 0.f;
        float w3 = (vy1 && vx1) ? wy * wx : 0.f;

        s8v c[8];
        if (__builtin_expect(fabsf(oy) < 1.0f, 1)) {
            int r0 = min(max(y0c - wlo, 0), nr - 1);
            int r1 = min(max(y1c - wlo, 0), nr - 1);
            int b00 = r0 * 8192 + ((x0c * 128 + q * 16) ^ ((x0c & 7) << 4));
            int b00h = r0 * 8192 + ((x0c * 128 + q * 16 + 64) ^ ((x0c & 7) << 4));
            int b01 = r0 * 8192 + ((x1c * 128 + q * 16) ^ ((x1c & 7) << 4));
            int b01h = r0 * 8192 + ((x1c * 128 + q * 16 + 64) ^ ((x1c & 7) << 4));
            int b10 = r1 * 8192 + ((x0c * 128 + q * 16) ^ ((x0c & 7) << 4));
            int b10h = r1 * 8192 + ((x0c * 128 + q * 16 + 64) ^ ((x0c & 7) << 4));
            int b11 = r1 * 8192 + ((x1c * 128 + q * 16) ^ ((x1c & 7) << 4));
            int b11h = r1 * 8192 + ((x1c * 128 + q * 16 + 64) ^ ((x1c & 7) << 4));
            c[0] = *(const s8v*)((const char*)kv + b00);
            c[1] = *(const s8v*)((const char*)kv + b00h);
            c[2] = *(const s8v*)((const char*)kv + b01);
            c[3] = *(const s8v*)((const char*)kv + b01h);
            c[4] = *(const s8v*)((const char*)kv + b10);
            c[5] = *(const s8v*)((const char*)kv + b10h);
            c[6] = *(const s8v*)((const char*)kv + b11);
            c[7] = *(const s8v*)((const char*)kv + b11h);
        } else {
            size_t i00 = (size_t)(y0c * kW + x0c) * 64;
            size_t i01 = (size_t)(y0c * kW + x1c) * 64;
            size_t i10 = (size_t)(y1c * kW + x0c) * 64;
            size_t i11 = (size_t)(y1c * kW + x1c) * 64;
            c[0] = *(const s8v*)(inpx + i00);
            c[1] = *(const s8v*)(inpx + i00 + 32);
            c[2] = *(const s8v*)(inpx + i01);
            c[3] = *(const s8v*)(inpx + i01 + 32);
            c[4] = *(const s8v*)(inpx + i10);
            c[5] = *(const s8v*)(inpx + i10 + 32);
            c[6] = *(const s8v*)(inpx + i11);
            c[7] = *(const s8v*)(inpx + i11 + 32);
        }

        s8v b0, b1;
#pragma unroll
        for (int j = 0; j < 8; ++j) {
            float v0 = w0 * bfu(c[0][j]) + w1 * bfu(c[2][j]) +
                       w2 * bfu(c[4][j]) + w3 * bfu(c[6][j]);
            float v1 = w0 * bfu(c[1][j]) + w1 * bfu(c[3][j]) +
                       w2 * bfu(c[5][j]) + w3 * bfu(c[7][j]);
            b0[j] = (short)bf16r(v0);
            b1[j] = (short)bf16r(v1);
        }
        const char* wkk = (const char*)wlds + (kk - kkbase) * 8192 + l15 * 128;
#pragma unroll
        for (int obb = 0; obb < 4; ++obb) {
            s8v a0w = *(const s8v*)(wkk + obb * 2048 + wcol0);
            s8v a1w = *(const s8v*)(wkk + obb * 2048 + wcol1);
            acc[obb] = __builtin_amdgcn_mfma_f32_16x16x32_bf16(a0w, b0, acc[obb], 0, 0, 0);
            acc[obb] = __builtin_amdgcn_mfma_f32_16x16x32_bf16(a1w, b1, acc[obb], 0, 0, 0);
        }
    };

    // ---- phase A: taps 0-4 ----
#pragma unroll
    for (int kk = 0; kk < 5; ++kk) do_tap(kk, 0);
    __syncthreads();
    // ---- restage weights: kk 5-8 (32768 B) ----
    for (int i = tid; i < 2048; i += 1024) {
        int g = i * 16;
        uint4 v = *(const uint4*)((const char*)dwtb + 40960 + g);
        int row = (g >> 7) & 63;
        *(uint4*)((char*)wlds + (g ^ ((row & 7) << 4))) = v;
    }
    __syncthreads();
    // ---- phase B: taps 5-8 ----
#pragma unroll
    for (int kk = 5; kk < 9; ++kk) do_tap(kk, 5);

    // store: lane holds o = obb*16 + q*4 + reg at pixel px -> bf16 pixel-major
    ushort_t* orow = outp + ((size_t)b * kHW + y * kW + px) * 64 + q * 4;
#pragma unroll
    for (int obb = 0; obb < 4; ++obb) {
        float4 bias = *(const float4*)&db[obb * 16 + q * 4];
        f4v v = acc[obb];
        uint2 u;
        u.x = (unsigned)bf16r(v.x + bias.x) | ((unsigned)bf16r(v.y + bias.y) << 16);
        u.y = (unsigned)bf16r(v.z + bias.z) | ((unsigned)bf16r(v.w + bias.w) << 16);
        *(uint2*)(orow + obb * 16) = u;
    }
}

// ---------------------------------------------------------------------------
// Kernel 4 (round-18): 9-tap local attention, ALL 3 branches, one dispatch.
// UNCHANGED (control; <41us total per round-18 top-5 evidence).
// ---------------------------------------------------------------------------
__global__ __launch_bounds__(512) void attn_fused(const ushort_t* __restrict__ q0,
                                                  const ushort_t* __restrict__ k0,
                                                  const ushort_t* __restrict__ v0,
                                                  const ushort_t* __restrict__ q1,
                                                  const ushort_t* __restrict__ kd2,
                                                  const ushort_t* __restrict__ vd2,
                                                  const ushort_t* __restrict__ q2,
                                                  const ushort_t* __restrict__ kd3,
                                                  const ushort_t* __restrict__ vd3,
                                                  ushort_t* __restrict__ aopx) {
    __shared__ ushort_t ks[8 * 4096];       // up to 8 rows x 8192 B, swizzled
    __shared__ ushort_t vs[8 * 4096];

    const int tid = threadIdx.x;
    const int bx  = blockIdx.x;
    const int lb  = (bx & 7) * 96 + (bx >> 3);  // XCD swizzle (G=768)
    const int zb  = lb >> 8;                // branch 0,1,2
    const int rest = lb & 255;
    const int b   = rest >> 5;
    const int y0  = (rest & 31) * 2;        // first of 2 output rows
    const int dil = zb + 1;
    const int nr  = 2 * dil + 2;            // staged rows
    const int wlo = y0 - dil;

    const ushort_t* qpx = (zb == 0) ? q0 : (zb == 1) ? q1 : q2;
    const ushort_t* kpx = (zb == 0) ? k0 : (zb == 1) ? kd2 : kd3;
    const ushort_t* vpx = (zb == 0) ? v0 : (zb == 1) ? vd2 : vd3;

    const size_t pbase = (size_t)b * kHW;
    const ushort_t* kb = kpx + pbase * 64;
    const ushort_t* vb = vpx + pbase * 64;

    // ---- stage nr rows of k AND v, 16B/thread/row, swizzled ----
    {
        int x  = tid >> 3;
        int cc = tid & 7;
        int dstc = (x * 128 + cc * 16) ^ ((x & 7) << 4);
        for (int r = 0; r < nr; ++r) {
            int gy = min(max(wlo + r, 0), kH - 1);
            *(uint4*)((char*)ks + r * 8192 + dstc) = *(const uint4*)(kb + (size_t)gy * 4096 + tid * 8);
            *(uint4*)((char*)vs + r * 8192 + dstc) = *(const uint4*)(vb + (size_t)gy * 4096 + tid * 8);
        }
    }
    __syncthreads();

    const int wave = tid >> 6;          // 0..7
    const int l    = tid & 63;
    const int ry   = wave >> 2;         // row within pair
    const int wc   = wave & 3;          // 16-px column group
    const int pxq  = l >> 2;            // 16 pixels per wave
    const int cg   = l & 3;             // 4 channel-groups of 16 ch
    const int y  = y0 + ry;
    const int x_ = wc * 16 + pxq;
    const int p  = y * kW + x_;

    const ushort_t* qb = qpx + (pbase + p) * 64 + cg * 16;
    s8v qv0 = *(const s8v*)qb;
    s8v qv1 = *(const s8v*)(qb + 8);
    float qf[16];
#pragma unroll
    for (int j = 0; j < 8; ++j) { qf[j] = bfu(qv0[j]); qf[8 + j] = bfu(qv1[j]); }

    int a0s[9], a1s[9];
    float msk[9];
#pragma unroll
    for (int kk = 0; kk < 9; ++kk) {
        int dy = (kk / 3 - 1) * dil, dx = (kk % 3 - 1) * dil;
        int yy = y + dy, xx = x_ + dx;
        bool v = (yy >= 0) & (yy < kH) & (xx >= 0) & (xx < kW);
        msk[kk] = v ? 1.f : 0.f;
        int r  = min(max(yy - wlo, 0), nr - 1);
        int xc = min(max(xx, 0), kW - 1);
        int sw = (xc & 7) << 4;
        a0s[kk] = r * 8192 + ((xc * 128 + cg * 32) ^ sw);
        a1s[kk] = r * 8192 + ((xc * 128 + cg * 32 + 16) ^ sw);
    }

    float e[9];
#pragma unroll
    for (int kk = 0; kk < 9; ++kk) {
        s8v k0v = *(const s8v*)((const char*)ks + a0s[kk]);
        s8v k1v = *(const s8v*)((const char*)ks + a1s[kk]);
        float s = 0.f;
#pragma unroll
        for (int j = 0; j < 8; ++j) {
            s += qf[j] * bfu(k0v[j]);
            s += qf[8 + j] * bfu(k1v[j]);
        }
        s += __shfl_xor(s, 1);
        s += __shfl_xor(s, 2);
        e[kk] = s * 0.125f * msk[kk];
    }
    float mx = -1e30f;
#pragma unroll
    for (int kk = 0; kk < 9; ++kk) mx = fmaxf(mx, e[kk]);
    float ssum = 0.f;
#pragma unroll
    for (int kk = 0; kk < 9; ++kk) { e[kk] = __expf(e[kk] - mx); ssum += e[kk]; }
    float inv = 1.f / ssum;
#pragma unroll
    for (int kk = 0; kk < 9; ++kk) e[kk] = e[kk] * inv * msk[kk];

    float acc[16];
#pragma unroll
    for (int j = 0; j < 16; ++j) acc[j] = 0.f;
#pragma unroll
    for (int kk = 0; kk < 9; ++kk) {
        s8v v0v = *(const s8v*)((const char*)vs + a0s[kk]);
        s8v v1v = *(const s8v*)((const char*)vs + a1s[kk]);
        float w = e[kk];
#pragma unroll
        for (int j = 0; j < 8; ++j) {
            acc[j] += w * bfu(v0v[j]);
            acc[8 + j] += w * bfu(v1v[j]);
        }
    }
    unsigned u[8];
#pragma unroll
    for (int i = 0; i < 8; ++i)
        u[i] = (unsigned)bf16r(acc[2 * i]) | ((unsigned)bf16r(acc[2 * i + 1]) << 16);
    ushort_t* ob = aopx + (pbase + p) * kC + zb * 64 + cg * 16;
    *(uint4*)ob = make_uint4(u[0], u[1], u[2], u[3]);
    *(uint4*)(ob + 8) = make_uint4(u[4], u[5], u[6], u[7]);
}

// ---------------------------------------------------------------------------
// Kernel 5 (verified): output projection, LDS-staged GEMM. UNCHANGED.
// ---------------------------------------------------------------------------
__global__ __launch_bounds__(256) void proj_mfma3(const ushort_t* __restrict__ aopx,
                                                  const ushort_t* __restrict__ pwbp,
                                                  const float* __restrict__ pb,
                                                  float* __restrict__ out) {
    __shared__ ushort_t xs[64 * kC];            // 24576 B, swizzled rows of 384 B

    const int tid = threadIdx.x;
    const int bx  = blockIdx.x;
    const int lb  = (bx & 7) * 64 + (bx >> 3);  // XCD swizzle (G=512)
    const int m0  = lb * 64;

#pragma unroll
    for (int i = 0; i < 6; ++i) {
        int il = i * 256 + tid;                 // 16B chunk id, 0..1535
        int p  = il / 24;                       // pixel row in strip
        int cc = il % 24;                       // 16B chunk within row
        uint4 v = *(const uint4*)(aopx + (size_t)(m0 + p) * kC + cc * 8);
        int dst = p * 384 + ((cc * 16) ^ ((p & 7) << 4));
        *(uint4*)((char*)xs + dst) = v;
    }
    __syncthreads();

    const int lane = tid & 63;
    const int wave = tid >> 6;
    const int l15  = lane & 15;
    const int q    = lane >> 4;
    const int sbase = wave * 3;                 // strips 0..11, 3 per wave

    f4v acc[3][4];
#pragma unroll
    for (int i = 0; i < 3; ++i)
#pragma unroll
        for (int m = 0; m < 4; ++m) acc[i][m] = (f4v){0.f, 0.f, 0.f, 0.f};

    const ushort_t* ap = pwbp + ((size_t)sbase * 6 * 64 + lane) * 8;

#pragma unroll
    for (int kc = 0; kc < 6; ++kc) {
        s8v bfr[4];
#pragma unroll
        for (int m = 0; m < 4; ++m) {
            int row = m * 16 + l15;
            int col = (kc * 64 + q * 16) ^ ((l15 & 7) << 4);
            bfr[m] = *(const s8v*)((const char*)xs + row * 384 + col);
        }
#pragma unroll
        for (int i = 0; i < 3; ++i) {
            s8v a = *(const s8v*)(ap + (size_t)(i * 6 + kc) * 64 * 8);
#pragma unroll
            for (int m = 0; m < 4; ++m)
                acc[i][m] = __builtin_amdgcn_mfma_f32_16x16x32_bf16(a, bfr[m], acc[i][m], 0, 0, 0);
        }
    }

#pragma unroll
    for (int i = 0; i < 3; ++i) {
        int s  = sbase + i;
        int n0 = s * 16 + q * 4;
        float4 bias = *(const float4*)&pb[n0];
#pragma unroll
        for (int m = 0; m < 4; ++m) {
            f4v v = acc[i][m];
            v.x += bias.x; v.y += bias.y; v.z += bias.z; v.w += bias.w;
            *(f4v*)&out[(size_t)(m0 + m * 16 + l15) * kC + n0] = v;
        }
    }
}

// ---------------------------------------------------------------------------
// Host launcher.  Workspace ~85 MB (offb x2, kd/vd x2 branches).
// 6 dispatches: cvt_prep, qkv, off_fused, deform_big, attn_fused, proj.
// ---------------------------------------------------------------------------
extern "C" void kernel_launch(void* const* d_in, const int* in_sizes, int n_in,
                              void* d_out, int out_size, void* d_ws, size_t ws_size,
                              hipStream_t stream) {
    const float* x      = (const float*)d_in[0];
    const float* qkv_w  = (const float*)d_in[1];
    const float* proj_w = (const float*)d_in[2];
    const float* proj_b = (const float*)d_in[3];
    const float* off_w2 = (const float*)d_in[4];
    const float* off_b2 = (const float*)d_in[5];
    const float* def_w2 = (const float*)d_in[6];
    const float* def_b2 = (const float*)d_in[7];
    const float* off_w3 = (const float*)d_in[8];
    const float* off_b3 = (const float*)d_in[9];
    const float* def_w3 = (const float*)d_in[10];
    const float* def_b3 = (const float*)d_in[11];
    float* out = (float*)d_out;

    float* ws    = (float*)d_ws;
    float* offb2 = ws;                              // 18 * M
    float* offb3 = offb2 + (size_t)18 * kM;         // 18 * M
    ushort_t* us = (ushort_t*)(offb3 + (size_t)18 * kM);
    ushort_t* xb     = us;  us += (size_t)kM * kC;
    ushort_t* qkvpx  = us;  us += (size_t)9 * kM * 64;
    ushort_t* kd2    = us;  us += (size_t)kM * 64;
    ushort_t* vd2    = us;  us += (size_t)kM * 64;
    ushort_t* kd3    = us;  us += (size_t)kM * 64;
    ushort_t* vd3    = us;  us += (size_t)kM * 64;
    ushort_t* aopx   = us;  us += (size_t)kM * kC;
    ushort_t* awb    = us;  us += (size_t)kNQKV * kC;   // 36*6*64*8 == 576*192
    ushort_t* pwbp   = us;  us += (size_t)kC * kC;      // 12*6*64*8 == 192*192
    ushort_t* dwtb2  = us;  us += kD * kD * 9;
    ushort_t* dwtb3  = us;  us += kD * kD * 9;
    ushort_t* owtb2  = us;  us += 9 * 32 * 64;
    ushort_t* owtb3  = us;  us += 9 * 32 * 64;

    // 0. x conversion + all weight packs (one dispatch)
    cvt_prep<<<12792, 256, 0, stream>>>(x, (unsigned*)xb, qkv_w, proj_w,
                                        def_w2, def_w3, off_w2, off_w3,
                                        awb, pwbp, dwtb2, dwtb3, owtb2, owtb3);

    // per-tensor pixel-major slices
    ushort_t* q0 = qkvpx;
    ushort_t* q1 = qkvpx + (size_t)1 * kM * 64;
    ushort_t* q2 = qkvpx + (size_t)2 * kM * 64;
    ushort_t* k0 = qkvpx + (size_t)3 * kM * 64;
    ushort_t* k1 = qkvpx + (size_t)4 * kM * 64;
    ushort_t* k2 = qkvpx + (size_t)5 * kM * 64;
    ushort_t* v0 = qkvpx + (size_t)6 * kM * 64;
    ushort_t* v1 = qkvpx + (size_t)7 * kM * 64;
    ushort_t* v2 = qkvpx + (size_t)8 * kM * 64;

    // 1. QKV projection -> 9 bf16 pixel-major tensors (LDS-staged GEMM)
    qkv_mfma3<<<dim3(kM / 64, 3), 256, 0, stream>>>(xb, awb, qkvpx);

    // 2. offsets conv, both branches (one dispatch)
    off_conv_fused<<<1024, 256, 0, stream>>>(k1, k2, owtb2, owtb3,
                                             off_b2, off_b3, offb2, offb3);

    // 3. deformable conv, both branches, 16-wave blocks (one dispatch)
    deform_big<<<512, 1024, 0, stream>>>(k1, v1, k2, v2, offb2, offb3,
                                         dwtb2, dwtb3, def_b2, def_b3,
                                         kd2, vd2, kd3, vd3);

    // 4. attention, all three branches (one dispatch)
    attn_fused<<<768, 512, 0, stream>>>(q0, k0, v0, q1, kd2, vd2, q2, kd3, vd3, aopx);

    // 5. output projection (LDS-staged bf16 MFMA, fp32 out)
    proj_mfma3<<<512, 256, 0, stream>>>(aopx, pwbp, proj_b, out);
}

// Round 11
// 204.571 us; speedup vs baseline: 1.6318x; 1.0260x over previous
//
#include <hip/hip_runtime.h>
#include <cmath>

// ---------------------------------------------------------------------------
// Problem constants (B=8, H=W=64, C=192, 3 dilation branches of d=64, heads=64)
// ---------------------------------------------------------------------------
#define kB    8
#define kH    64
#define kW    64
#define kHW   4096          // H*W
#define kC    192
#define kD    64            // channels per dilation branch == head_dim
#define kM    (kB * kHW)    // 32768 total pixels
#define kNQKV 576           // 3*C

typedef unsigned short ushort_t;
typedef __attribute__((ext_vector_type(8))) short  s8v;   // 8 bf16 (4 VGPRs)
typedef __attribute__((ext_vector_type(4))) float  f4v;   // MFMA C/D frag
typedef __attribute__((ext_vector_type(2))) float  f2v;   // packed f32 pair

__device__ inline unsigned short bf16r(float f) {   // round-to-nearest-even
    union { float f; unsigned u; } v; v.f = f;
    unsigned u = v.u + 0x7FFFu + ((v.u >> 16) & 1u);
    return (unsigned short)(u >> 16);
}
__device__ inline float bfu(short s) {              // bf16 -> fp32
    union { unsigned u; float f; } v;
    v.u = ((unsigned)(unsigned short)s) << 16;
    return v.f;
}
__device__ inline f2v bfu2(unsigned u) {            // 2 packed bf16 -> f2v
    union { unsigned u; float f; } lo, hi;
    lo.u = u << 16;
    hi.u = u & 0xFFFF0000u;
    return (f2v){lo.f, hi.f};
}
__device__ inline unsigned pk2(f2v a) {             // f2v -> 2 packed bf16 (RTNE)
    union { float f; unsigned u; } x, y;
    x.f = a.x; y.f = a.y;
    unsigned ua = x.u + 0x7FFFu + ((x.u >> 16) & 1u);
    unsigned ub = y.u + 0x7FFFu + ((y.u >> 16) & 1u);
    return (ua >> 16) | (ub & 0xFFFF0000u);
}

// ---------------------------------------------------------------------------
// cvt_prep: x bf16 conversion + ALL weight packs, ONE dispatch (verified).
// ---------------------------------------------------------------------------
__global__ void cvt_prep(const float* __restrict__ x, unsigned* __restrict__ xb,
                         const float* __restrict__ qkv_w,
                         const float* __restrict__ proj_w,
                         const float* __restrict__ def_w2,
                         const float* __restrict__ def_w3,
                         const float* __restrict__ off_w2,
                         const float* __restrict__ off_w3,
                         ushort_t* __restrict__ awb,
                         ushort_t* __restrict__ pwbp,
                         ushort_t* __restrict__ dwtb2,
                         ushort_t* __restrict__ dwtb3,
                         ushort_t* __restrict__ owtb2,
                         ushort_t* __restrict__ owtb3) {
    const int bid = blockIdx.x;
    const int tid = threadIdx.x;
    if (bid < 12288) {                    // cvt x
        int i = bid * 256 + tid;          // kM*kC/2 = 3145728
        if (i >= kM * kC / 2) return;
        float2 f = ((const float2*)x)[i];
        xb[i] = (unsigned)bf16r(f.x) | ((unsigned)bf16r(f.y) << 16);
    } else if (bid < 12342) {             // qw_pack
        int idx = (bid - 12288) * 256 + tid;
        if (idx >= 36 * 6 * 64) return;
        int lane = idx & 63;
        int kc   = (idx >> 6) % 6;
        int s    = idx / 384;
        int row  = s * 16 + (lane & 15);
        int k0   = kc * 32 + (lane >> 4) * 8;
        const float* src = qkv_w + (size_t)row * kC + k0;
        ushort_t* dst = awb + (size_t)idx * 8;
#pragma unroll
        for (int j = 0; j < 8; ++j) dst[j] = bf16r(src[j]);
    } else if (bid < 12360) {             // pw_pack
        int idx = (bid - 12342) * 256 + tid;
        if (idx >= 12 * 6 * 64) return;
        int lane = idx & 63;
        int kc   = (idx >> 6) % 6;
        int s    = idx / 384;
        int row  = s * 16 + (lane & 15);
        int k0   = kc * 32 + (lane >> 4) * 8;
        const float* src = proj_w + (size_t)row * kC + k0;
        ushort_t* dst = pwbp + (size_t)idx * 8;
#pragma unroll
        for (int j = 0; j < 8; ++j) dst[j] = bf16r(src[j]);
    } else if (bid < 12648) {             // dw_tb x2
        const float* dw = (bid < 12504) ? def_w2 : def_w3;
        ushort_t* dwtb  = (bid < 12504) ? dwtb2 : dwtb3;
        int l = ((bid < 12504) ? (bid - 12360) : (bid - 12504)) * 256 + tid;
        if (l >= kD * kD * 9) return;
        int o = l / 576;
        int c = (l / 9) % 64;
        int kk = l % 9;
        dwtb[(kk * 64 + o) * 64 + c] = bf16r(dw[l]);
    } else {                              // ow_tb x2
        const float* ow = (bid < 12720) ? off_w2 : off_w3;
        ushort_t* owtb  = (bid < 12720) ? owtb2 : owtb3;
        int l = ((bid < 12720) ? (bid - 12648) : (bid - 12720)) * 256 + tid;
        if (l >= 9 * 32 * 64) return;
        int kk = l >> 11;
        int j  = (l >> 6) & 31;
        int c  = l & 63;
        owtb[l] = (j < 18) ? bf16r(ow[j * 576 + c * 9 + kk]) : (ushort_t)0;
    }
}

// ---------------------------------------------------------------------------
// Kernel 1: QKV projection GEMM, LDS-staged (verified). UNCHANGED.
// ---------------------------------------------------------------------------
__global__ __launch_bounds__(256) void qkv_mfma3(const ushort_t* __restrict__ xb,
                                                 const ushort_t* __restrict__ awb,
                                                 ushort_t* __restrict__ qkvpx) {
    __shared__ ushort_t xs[64 * kC];            // 24576 B, swizzled rows of 384 B

    const int tid = threadIdx.x;
    const int bx  = blockIdx.x;
    const int lb  = (bx & 7) * 64 + (bx >> 3);  // XCD swizzle (G=512)
    const int m0  = lb * 64;
    const int ty3 = blockIdx.y;                 // tensor triple: channels [ty3*192, +192)

#pragma unroll
    for (int i = 0; i < 6; ++i) {
        int il = i * 256 + tid;                 // 16B chunk id, 0..1535
        int p  = il / 24;                       // pixel row in strip
        int cc = il % 24;                       // 16B chunk within row
        uint4 v = *(const uint4*)(xb + (size_t)(m0 + p) * kC + cc * 8);
        int dst = p * 384 + ((cc * 16) ^ ((p & 7) << 4));
        *(uint4*)((char*)xs + dst) = v;
    }
    __syncthreads();

    const int lane = tid & 63;
    const int wave = tid >> 6;
    const int l15  = lane & 15;
    const int q    = lane >> 4;
    const int sbase = ty3 * 12 + wave * 3;      // first of 3 N-strips for this wave

    f4v acc[3][4];
#pragma unroll
    for (int i = 0; i < 3; ++i)
#pragma unroll
        for (int m = 0; m < 4; ++m) acc[i][m] = (f4v){0.f, 0.f, 0.f, 0.f};

    const ushort_t* ap = awb + ((size_t)sbase * 6 * 64 + lane) * 8;

#pragma unroll
    for (int kc = 0; kc < 6; ++kc) {
        s8v bfr[4];
#pragma unroll
        for (int m = 0; m < 4; ++m) {
            int row = m * 16 + l15;
            int col = (kc * 64 + q * 16) ^ ((l15 & 7) << 4);
            bfr[m] = *(const s8v*)((const char*)xs + row * 384 + col);
        }
#pragma unroll
        for (int i = 0; i < 3; ++i) {
            s8v a = *(const s8v*)(ap + (size_t)(i * 6 + kc) * 64 * 8);
#pragma unroll
            for (int m = 0; m < 4; ++m)
                acc[i][m] = __builtin_amdgcn_mfma_f32_16x16x32_bf16(a, bfr[m], acc[i][m], 0, 0, 0);
        }
    }

#pragma unroll
    for (int i = 0; i < 3; ++i) {
        int s   = sbase + i;
        int ty  = s >> 2;                       // tensor 0..8
        int c64 = (s & 3) * 16 + q * 4;         // channel within tensor
        ushort_t* obase = qkvpx + (size_t)ty * kM * 64 + (size_t)m0 * 64 + c64;
#pragma unroll
        for (int m = 0; m < 4; ++m) {
            f4v v = acc[i][m];
            uint2 u;
            u.x = (unsigned)bf16r(v.x) | ((unsigned)bf16r(v.y) << 16);
            u.y = (unsigned)bf16r(v.z) | ((unsigned)bf16r(v.w) << 16);
            *(uint2*)(obase + (size_t)(m * 16 + l15) * 64) = u;
        }
    }
}

// ---------------------------------------------------------------------------
// Kernel 2 (round-20): offsets conv, LDS-STAGED k window.
// Old version did the proven-wall pattern: 18 scattered global loads/lane,
// each k line re-gathered 9x by neighboring output pixels (the pathology
// that cost 67->38 on deform when staged). Stage rows y-dil..y+dil
// (nr=2dil+1 <= 7, 56KB max, swizzled); taps read LDS.
// ---------------------------------------------------------------------------
__global__ __launch_bounds__(256) void off_conv_fused(const ushort_t* __restrict__ k1,
                                                      const ushort_t* __restrict__ k2,
                                                      const ushort_t* __restrict__ owtb2,
                                                      const ushort_t* __restrict__ owtb3,
                                                      const float* __restrict__ ob2,
                                                      const float* __restrict__ ob3,
                                                      float* __restrict__ offb2,
                                                      float* __restrict__ offb3) {
    __shared__ ushort_t ks[7 * 4096];           // up to 7 rows x 8192 B, swizzled

    const int bx = blockIdx.x;
    const int lb = (bx & 7) * 128 + (bx >> 3);  // XCD swizzle (G=1024)
    const int zb = lb >> 9;                     // 0: dil2, 1: dil3
    const int rest = lb & 511;
    const int b = rest >> 6;
    const int y = rest & 63;
    const int dil = 2 + zb;
    const int nr  = 2 * dil + 1;
    const int wlo = y - dil;
    const ushort_t* kpx  = zb ? k2 : k1;
    const ushort_t* owtb = zb ? owtb3 : owtb2;
    const float* obias   = zb ? ob3 : ob2;
    float* offb          = zb ? offb3 : offb2;

    const int tid  = threadIdx.x;
    const ushort_t* kb = kpx + (size_t)b * kHW * 64;

    // ---- stage nr rows, 256 thr = half-row per pass, swizzled ----
    for (int r = 0; r < nr; ++r) {
        int gy = min(max(wlo + r, 0), kH - 1);
#pragma unroll
        for (int h = 0; h < 2; ++h) {
            int chunk = h * 256 + tid;
            int xcol = chunk >> 3, cc = chunk & 7;
            int dstc = (xcol * 128 + cc * 16) ^ ((xcol & 7) << 4);
            *(uint4*)((char*)ks + r * 8192 + dstc) =
                *(const uint4*)(kb + (size_t)gy * 4096 + chunk * 8);
        }
    }
    __syncthreads();

    const int lane = tid & 63;
    const int wave = tid >> 6;
    const int l15  = lane & 15;
    const int q    = lane >> 4;
    const int px   = wave * 16 + l15;

    f4v acc[2];
    acc[0] = (f4v){0.f, 0.f, 0.f, 0.f};
    acc[1] = (f4v){0.f, 0.f, 0.f, 0.f};

#pragma unroll
    for (int kk = 0; kk < 9; ++kk) {
        const int yy = y + (kk / 3 - 1) * dil;
        const int xx = px + (kk % 3 - 1) * dil;
        const bool valid = (yy >= 0) & (yy < kH) & (xx >= 0) & (xx < kW);
        int r  = min(max(yy - wlo, 0), nr - 1);
        int xc = min(max(xx, 0), kW - 1);
        int sw = (xc & 7) << 4;
        s8v a0 = *(const s8v*)((const char*)ks + r * 8192 + ((xc * 128 + q * 16) ^ sw));
        s8v a1 = *(const s8v*)((const char*)ks + r * 8192 + ((xc * 128 + q * 16 + 64) ^ sw));
        if (!valid) {
            a0 = (s8v){0, 0, 0, 0, 0, 0, 0, 0};
            a1 = (s8v){0, 0, 0, 0, 0, 0, 0, 0};
        }
        const ushort_t* wb = owtb + (size_t)kk * 2048 + l15 * 64 + q * 8;
#pragma unroll
        for (int nbk = 0; nbk < 2; ++nbk) {
            s8v b0 = *(const s8v*)(wb + nbk * 1024);
            s8v b1 = *(const s8v*)(wb + nbk * 1024 + 32);
            acc[nbk] = __builtin_amdgcn_mfma_f32_16x16x32_bf16(a0, b0, acc[nbk], 0, 0, 0);
            acc[nbk] = __builtin_amdgcn_mfma_f32_16x16x32_bf16(a1, b1, acc[nbk], 0, 0, 0);
        }
    }
#pragma unroll
    for (int nbk = 0; nbk < 2; ++nbk) {
        int n = nbk * 16 + l15;
        if (n < 18) {
            float bias = obias[n];
            f4v v = acc[nbk];
            v.x += bias; v.y += bias; v.z += bias; v.w += bias;
            *(f4v*)&offb[((size_t)b * 18 + n) * kHW + y * kW + wave * 16 + q * 4] = v;
        }
    }
}

// ---------------------------------------------------------------------------
// Kernel 3 (round-20): deformable conv, 16-wave blocks (round-19 verified:
// 56.8->47.2us, VALUBusy 57%). New: bilinear in PACKED f32 (f2v ->
// v_pk_fma_f32) — ~20% fewer bilinear VALU ops, identical rounding.
// ---------------------------------------------------------------------------
__global__ __launch_bounds__(1024) void deform_big(const ushort_t* __restrict__ k1,
                                                   const ushort_t* __restrict__ v1,
                                                   const ushort_t* __restrict__ k2,
                                                   const ushort_t* __restrict__ v2,
                                                   const float* __restrict__ offb2,
                                                   const float* __restrict__ offb3,
                                                   const ushort_t* __restrict__ dwtb2,
                                                   const ushort_t* __restrict__ dwtb3,
                                                   const float* __restrict__ db2,
                                                   const float* __restrict__ db3,
                                                   ushort_t* __restrict__ kd2,
                                                   ushort_t* __restrict__ vd2,
                                                   ushort_t* __restrict__ kd3,
                                                   ushort_t* __restrict__ vd3) {
    __shared__ ushort_t kv[12 * 4096];      // up to 12 rows x 8192 B, swizzled (96KB)
    __shared__ ushort_t wlds[5 * 4096];     // 40KB: 5 kk tiles, two-phase

    const int tid = threadIdx.x;
    const int bx  = blockIdx.x;
    const int lb  = (bx & 7) * 64 + (bx >> 3);  // XCD swizzle (G=512)
    const int zb  = lb >> 8;                // 0: dil2, 1: dil3
    const int t   = (lb >> 7) & 1;          // 0 = k, 1 = v
    const int b   = (lb >> 4) & 7;
    const int y0  = (lb & 15) * 4;          // first of 4 output rows
    const int dil = 2 + zb;
    const int nr  = 2 * dil + 6;            // staged rows (|oy|<1, 4 rows)
    const int wlo = y0 - dil - 1;

    const ushort_t* kin = zb ? k2 : k1;
    const ushort_t* vin = zb ? v2 : v1;
    const float* offbS  = zb ? offb3 : offb2;
    const ushort_t* dwtb = zb ? dwtb3 : dwtb2;
    const float* db      = zb ? db3 : db2;
    ushort_t* outp = t ? (zb ? vd3 : vd2) : (zb ? kd3 : kd2);

    const ushort_t* inb = (t ? vin : kin) + (size_t)b * kHW * 64;

    // ---- stage nr kv rows: 1024 thr = 2 rows/pass, swizzled ----
    {
        int half  = tid >> 9;               // 0/1: row within pass
        int chunk = tid & 511;              // 16B chunk within row
        int xcol  = chunk >> 3;
        int cc    = chunk & 7;
        int dstc  = (xcol * 128 + cc * 16) ^ ((xcol & 7) << 4);
        for (int r0 = 0; r0 < nr; r0 += 2) {
            int r = r0 + half;
            if (r < nr) {
                int gy = min(max(wlo + r, 0), kH - 1);
                *(uint4*)((char*)kv + r * 8192 + dstc) =
                    *(const uint4*)(inb + (size_t)gy * 4096 + chunk * 8);
            }
        }
    }
    // ---- stage weights phase A: kk 0-4 (40960 B) ----
    for (int i = tid; i < 2560; i += 1024) {
        int g = i * 16;
        uint4 v = *(const uint4*)((const char*)dwtb + g);
        int row = (g >> 7) & 63;
        *(uint4*)((char*)wlds + (g ^ ((row & 7) << 4))) = v;
    }
    __syncthreads();

    const int lane = tid & 63;
    const int wave = tid >> 6;          // 0..15
    const int ry   = wave >> 2;         // output row within quad
    const int wc   = wave & 3;          // px column
    const int l15  = lane & 15;
    const int q    = lane >> 4;
    const int y    = y0 + ry;
    const int px   = wc * 16 + l15;
    const int wsw  = (l15 & 7) << 4;
    const int wcol0 = (q * 16) ^ wsw;
    const int wcol1 = (q * 16 + 64) ^ wsw;

    const ushort_t* inpx = inb + q * 8; // global fallback base

    f4v acc[4];
#pragma unroll
    for (int ob = 0; ob < 4; ++ob) acc[ob] = (f4v){0.f, 0.f, 0.f, 0.f};

    const float* offrow = offbS + (size_t)b * 18 * kHW + y * kW + px;
    float offv[18];
#pragma unroll
    for (int i = 0; i < 18; ++i) offv[i] = offrow[(size_t)i * kHW];

    auto do_tap = [&](int kk, int kkbase) {
        float oy = offv[kk * 2 + 0];
        float ox = offv[kk * 2 + 1];
        float py  = (float)y  + (float)((kk / 3 - 1) * dil) + oy;
        float pxf = (float)px + (float)((kk % 3 - 1) * dil) + ox;
        float fy = floorf(py), fx = floorf(pxf);
        float wy = py - fy, wx = pxf - fx;
        int iy0 = (int)fy, ix0 = (int)fx;
        int iy1 = iy0 + 1, ix1 = ix0 + 1;
        int y0c = min(max(iy0, 0), kH - 1), x0c = min(max(ix0, 0), kW - 1);
        int y1c = min(max(iy1, 0), kH - 1), x1c = min(max(ix1, 0), kW - 1);
        bool vy0 = (iy0 >= 0) & (iy0 < kH), vx0 = (ix0 >= 0) & (ix0 < kW);
        bool vy1 = (iy1 >= 0) & (iy1 < kH), vx1 = (ix1 >= 0) & (ix1 < kW);
        float w0 = (vy0 && vx0) ? (1.f - wy) * (1.f - wx) : 0.f;
        float w1 = (vy0 && vx1) ? (1.f - wy) * wx : 0.f;
        float w2 = (vy1 && vx0) ? wy * (1.f - wx) : 0.f;
        float w3 = (vy1 && vx1) ? wy * wx : 0.f;

        s8v c[8];
        if (__builtin_expect(fabsf(oy) < 1.0f, 1)) {
            int r0 = min(max(y0c - wlo, 0), nr - 1);
            int r1 = min(max(y1c - wlo, 0), nr - 1);
            int b00 = r0 * 8192 + ((x0c * 128 + q * 16) ^ ((x0c & 7) << 4));
            int b00h = r0 * 8192 + ((x0c * 128 + q * 16 + 64) ^ ((x0c & 7) << 4));
            int b01 = r0 * 8192 + ((x1c * 128 + q * 16) ^ ((x1c & 7) << 4));
            int b01h = r0 * 8192 + ((x1c * 128 + q * 16 + 64) ^ ((x1c & 7) << 4));
            int b10 = r1 * 8192 + ((x0c * 128 + q * 16) ^ ((x0c & 7) << 4));
            int b10h = r1 * 8192 + ((x0c * 128 + q * 16 + 64) ^ ((x0c & 7) << 4));
            int b11 = r1 * 8192 + ((x1c * 128 + q * 16) ^ ((x1c & 7) << 4));
            int b11h = r1 * 8192 + ((x1c * 128 + q * 16 + 64) ^ ((x1c & 7) << 4));
            c[0] = *(const s8v*)((const char*)kv + b00);
            c[1] = *(const s8v*)((const char*)kv + b00h);
            c[2] = *(const s8v*)((const char*)kv + b01);
            c[3] = *(const s8v*)((const char*)kv + b01h);
            c[4] = *(const s8v*)((const char*)kv + b10);
            c[5] = *(const s8v*)((const char*)kv + b10h);
            c[6] = *(const s8v*)((const char*)kv + b11);
            c[7] = *(const s8v*)((const char*)kv + b11h);
        } else {
            size_t i00 = (size_t)(y0c * kW + x0c) * 64;
            size_t i01 = (size_t)(y0c * kW + x1c) * 64;
            size_t i10 = (size_t)(y1c * kW + x0c) * 64;
            size_t i11 = (size_t)(y1c * kW + x1c) * 64;
            c[0] = *(const s8v*)(inpx + i00);
            c[1] = *(const s8v*)(inpx + i00 + 32);
            c[2] = *(const s8v*)(inpx + i01);
            c[3] = *(const s8v*)(inpx + i01 + 32);
            c[4] = *(const s8v*)(inpx + i10);
            c[5] = *(const s8v*)(inpx + i10 + 32);
            c[6] = *(const s8v*)(inpx + i11);
            c[7] = *(const s8v*)(inpx + i11 + 32);
        }

        // bilinear in packed f32 (f2v -> v_pk_fma_f32); same RTNE pack
        const f2v w0v = {w0, w0}, w1v = {w1, w1}, w2v = {w2, w2}, w3v = {w3, w3};
        s8v b0, b1;
#pragma unroll
        for (int jp = 0; jp < 4; ++jp) {
            f2v a0 = w0v * bfu2(((const unsigned*)&c[0])[jp])
                   + w1v * bfu2(((const unsigned*)&c[2])[jp])
                   + w2v * bfu2(((const unsigned*)&c[4])[jp])
                   + w3v * bfu2(((const unsigned*)&c[6])[jp]);
            f2v a1 = w0v * bfu2(((const unsigned*)&c[1])[jp])
                   + w1v * bfu2(((const unsigned*)&c[3])[jp])
                   + w2v * bfu2(((const unsigned*)&c[5])[jp])
                   + w3v * bfu2(((const unsigned*)&c[7])[jp]);
            ((unsigned*)&b0)[jp] = pk2(a0);
            ((unsigned*)&b1)[jp] = pk2(a1);
        }
        const char* wkk = (const char*)wlds + (kk - kkbase) * 8192 + l15 * 128;
#pragma unroll
        for (int obb = 0; obb < 4; ++obb) {
            s8v a0w = *(const s8v*)(wkk + obb * 2048 + wcol0);
            s8v a1w = *(const s8v*)(wkk + obb * 2048 + wcol1);
            acc[obb] = __builtin_amdgcn_mfma_f32_16x16x32_bf16(a0w, b0, acc[obb], 0, 0, 0);
            acc[obb] = __builtin_amdgcn_mfma_f32_16x16x32_bf16(a1w, b1, acc[obb], 0, 0, 0);
        }
    };

    // ---- phase A: taps 0-4 ----
#pragma unroll
    for (int kk = 0; kk < 5; ++kk) do_tap(kk, 0);
    __syncthreads();
    // ---- restage weights: kk 5-8 (32768 B) ----
    for (int i = tid; i < 2048; i += 1024) {
        int g = i * 16;
        uint4 v = *(const uint4*)((const char*)dwtb + 40960 + g);
        int row = (g >> 7) & 63;
        *(uint4*)((char*)wlds + (g ^ ((row & 7) << 4))) = v;
    }
    __syncthreads();
    // ---- phase B: taps 5-8 ----
#pragma unroll
    for (int kk = 5; kk < 9; ++kk) do_tap(kk, 5);

    // store: lane holds o = obb*16 + q*4 + reg at pixel px -> bf16 pixel-major
    ushort_t* orow = outp + ((size_t)b * kHW + y * kW + px) * 64 + q * 4;
#pragma unroll
    for (int obb = 0; obb < 4; ++obb) {
        float4 bias = *(const float4*)&db[obb * 16 + q * 4];
        f4v v = acc[obb];
        uint2 u;
        u.x = (unsigned)bf16r(v.x + bias.x) | ((unsigned)bf16r(v.y + bias.y) << 16);
        u.y = (unsigned)bf16r(v.z + bias.z) | ((unsigned)bf16r(v.w + bias.w) << 16);
        *(uint2*)(orow + obb * 16) = u;
    }
}

// ---------------------------------------------------------------------------
// Kernel 4 (round-20): 9-tap local attention, TWO-PHASE k->v staging in one
// 64KB buffer (was ks+vs = 128KB -> 1 block/CU). Now all branches fit 2
// blocks/CU (4 waves/SIMD). Same tap addressing; extra barrier between QK
// and V staging.
// ---------------------------------------------------------------------------
__global__ __launch_bounds__(512) void attn_fused(const ushort_t* __restrict__ q0,
                                                  const ushort_t* __restrict__ k0,
                                                  const ushort_t* __restrict__ v0,
                                                  const ushort_t* __restrict__ q1,
                                                  const ushort_t* __restrict__ kd2,
                                                  const ushort_t* __restrict__ vd2,
                                                  const ushort_t* __restrict__ q2,
                                                  const ushort_t* __restrict__ kd3,
                                                  const ushort_t* __restrict__ vd3,
                                                  ushort_t* __restrict__ aopx) {
    __shared__ ushort_t kvs[8 * 4096];      // 64KB: k then v (two-phase)

    const int tid = threadIdx.x;
    const int bx  = blockIdx.x;
    const int lb  = (bx & 7) * 96 + (bx >> 3);  // XCD swizzle (G=768)
    const int zb  = lb >> 8;                // branch 0,1,2
    const int rest = lb & 255;
    const int b   = rest >> 5;
    const int y0  = (rest & 31) * 2;        // first of 2 output rows
    const int dil = zb + 1;
    const int nr  = 2 * dil + 2;            // staged rows
    const int wlo = y0 - dil;

    const ushort_t* qpx = (zb == 0) ? q0 : (zb == 1) ? q1 : q2;
    const ushort_t* kpx = (zb == 0) ? k0 : (zb == 1) ? kd2 : kd3;
    const ushort_t* vpx = (zb == 0) ? v0 : (zb == 1) ? vd2 : vd3;

    const size_t pbase = (size_t)b * kHW;
    const ushort_t* kb = kpx + pbase * 64;
    const ushort_t* vb = vpx + pbase * 64;

    const int stx  = tid >> 3;
    const int stcc = tid & 7;
    const int dstc = (stx * 128 + stcc * 16) ^ ((stx & 7) << 4);

    // ---- phase 1: stage k rows ----
    for (int r = 0; r < nr; ++r) {
        int gy = min(max(wlo + r, 0), kH - 1);
        *(uint4*)((char*)kvs + r * 8192 + dstc) = *(const uint4*)(kb + (size_t)gy * 4096 + tid * 8);
    }
    __syncthreads();

    const int wave = tid >> 6;          // 0..7
    const int l    = tid & 63;
    const int ry   = wave >> 2;         // row within pair
    const int wc   = wave & 3;          // 16-px column group
    const int pxq  = l >> 2;            // 16 pixels per wave
    const int cg   = l & 3;             // 4 channel-groups of 16 ch
    const int y  = y0 + ry;
    const int x_ = wc * 16 + pxq;
    const int p  = y * kW + x_;

    const ushort_t* qb = qpx + (pbase + p) * 64 + cg * 16;
    s8v qv0 = *(const s8v*)qb;
    s8v qv1 = *(const s8v*)(qb + 8);
    float qf[16];
#pragma unroll
    for (int j = 0; j < 8; ++j) { qf[j] = bfu(qv0[j]); qf[8 + j] = bfu(qv1[j]); }

    int a0s[9], a1s[9];
    float msk[9];
#pragma unroll
    for (int kk = 0; kk < 9; ++kk) {
        int dy = (kk / 3 - 1) * dil, dx = (kk % 3 - 1) * dil;
        int yy = y + dy, xx = x_ + dx;
        bool v = (yy >= 0) & (yy < kH) & (xx >= 0) & (xx < kW);
        msk[kk] = v ? 1.f : 0.f;
        int r  = min(max(yy - wlo, 0), nr - 1);
        int xc = min(max(xx, 0), kW - 1);
        int sw = (xc & 7) << 4;
        a0s[kk] = r * 8192 + ((xc * 128 + cg * 32) ^ sw);
        a1s[kk] = r * 8192 + ((xc * 128 + cg * 32 + 16) ^ sw);
    }

    float e[9];
#pragma unroll
    for (int kk = 0; kk < 9; ++kk) {
        s8v k0v = *(const s8v*)((const char*)kvs + a0s[kk]);
        s8v k1v = *(const s8v*)((const char*)kvs + a1s[kk]);
        float s = 0.f;
#pragma unroll
        for (int j = 0; j < 8; ++j) {
            s += qf[j] * bfu(k0v[j]);
            s += qf[8 + j] * bfu(k1v[j]);
        }
        s += __shfl_xor(s, 1);
        s += __shfl_xor(s, 2);
        e[kk] = s * 0.125f * msk[kk];
    }
    // softmax (no LDS dependence)
    float mx = -1e30f;
#pragma unroll
    for (int kk = 0; kk < 9; ++kk) mx = fmaxf(mx, e[kk]);
    float ssum = 0.f;
#pragma unroll
    for (int kk = 0; kk < 9; ++kk) { e[kk] = __expf(e[kk] - mx); ssum += e[kk]; }
    float inv = 1.f / ssum;
#pragma unroll
    for (int kk = 0; kk < 9; ++kk) e[kk] = e[kk] * inv * msk[kk];

    __syncthreads();                     // all k reads done
    // ---- phase 2: restage with v rows ----
    for (int r = 0; r < nr; ++r) {
        int gy = min(max(wlo + r, 0), kH - 1);
        *(uint4*)((char*)kvs + r * 8192 + dstc) = *(const uint4*)(vb + (size_t)gy * 4096 + tid * 8);
    }
    __syncthreads();

    float acc[16];
#pragma unroll
    for (int j = 0; j < 16; ++j) acc[j] = 0.f;
#pragma unroll
    for (int kk = 0; kk < 9; ++kk) {
        s8v v0v = *(const s8v*)((const char*)kvs + a0s[kk]);
        s8v v1v = *(const s8v*)((const char*)kvs + a1s[kk]);
        float w = e[kk];
#pragma unroll
        for (int j = 0; j < 8; ++j) {
            acc[j] += w * bfu(v0v[j]);
            acc[8 + j] += w * bfu(v1v[j]);
        }
    }
    unsigned u[8];
#pragma unroll
    for (int i = 0; i < 8; ++i)
        u[i] = (unsigned)bf16r(acc[2 * i]) | ((unsigned)bf16r(acc[2 * i + 1]) << 16);
    ushort_t* ob = aopx + (pbase + p) * kC + zb * 64 + cg * 16;
    *(uint4*)ob = make_uint4(u[0], u[1], u[2], u[3]);
    *(uint4*)(ob + 8) = make_uint4(u[4], u[5], u[6], u[7]);
}

// ---------------------------------------------------------------------------
// Kernel 5 (verified): output projection, LDS-staged GEMM. UNCHANGED.
// ---------------------------------------------------------------------------
__global__ __launch_bounds__(256) void proj_mfma3(const ushort_t* __restrict__ aopx,
                                                  const ushort_t* __restrict__ pwbp,
                                                  const float* __restrict__ pb,
                                                  float* __restrict__ out) {
    __shared__ ushort_t xs[64 * kC];            // 24576 B, swizzled rows of 384 B

    const int tid = threadIdx.x;
    const int bx  = blockIdx.x;
    const int lb  = (bx & 7) * 64 + (bx >> 3);  // XCD swizzle (G=512)
    const int m0  = lb * 64;

#pragma unroll
    for (int i = 0; i < 6; ++i) {
        int il = i * 256 + tid;                 // 16B chunk id, 0..1535
        int p  = il / 24;                       // pixel row in strip
        int cc = il % 24;                       // 16B chunk within row
        uint4 v = *(const uint4*)(aopx + (size_t)(m0 + p) * kC + cc * 8);
        int dst = p * 384 + ((cc * 16) ^ ((p & 7) << 4));
        *(uint4*)((char*)xs + dst) = v;
    }
    __syncthreads();

    const int lane = tid & 63;
    const int wave = tid >> 6;
    const int l15  = lane & 15;
    const int q    = lane >> 4;
    const int sbase = wave * 3;                 // strips 0..11, 3 per wave

    f4v acc[3][4];
#pragma unroll
    for (int i = 0; i < 3; ++i)
#pragma unroll
        for (int m = 0; m < 4; ++m) acc[i][m] = (f4v){0.f, 0.f, 0.f, 0.f};

    const ushort_t* ap = pwbp + ((size_t)sbase * 6 * 64 + lane) * 8;

#pragma unroll
    for (int kc = 0; kc < 6; ++kc) {
        s8v bfr[4];
#pragma unroll
        for (int m = 0; m < 4; ++m) {
            int row = m * 16 + l15;
            int col = (kc * 64 + q * 16) ^ ((l15 & 7) << 4);
            bfr[m] = *(const s8v*)((const char*)xs + row * 384 + col);
        }
#pragma unroll
        for (int i = 0; i < 3; ++i) {
            s8v a = *(const s8v*)(ap + (size_t)(i * 6 + kc) * 64 * 8);
#pragma unroll
            for (int m = 0; m < 4; ++m)
                acc[i][m] = __builtin_amdgcn_mfma_f32_16x16x32_bf16(a, bfr[m], acc[i][m], 0, 0, 0);
        }
    }

#pragma unroll
    for (int i = 0; i < 3; ++i) {
        int s  = sbase + i;
        int n0 = s * 16 + q * 4;
        float4 bias = *(const float4*)&pb[n0];
#pragma unroll
        for (int m = 0; m < 4; ++m) {
            f4v v = acc[i][m];
            v.x += bias.x; v.y += bias.y; v.z += bias.z; v.w += bias.w;
            *(f4v*)&out[(size_t)(m0 + m * 16 + l15) * kC + n0] = v;
        }
    }
}

// ---------------------------------------------------------------------------
// Host launcher.  Workspace ~85 MB (offb x2, kd/vd x2 branches).
// 6 dispatches: cvt_prep, qkv, off_fused, deform_big, attn_fused, proj.
// ---------------------------------------------------------------------------
extern "C" void kernel_launch(void* const* d_in, const int* in_sizes, int n_in,
                              void* d_out, int out_size, void* d_ws, size_t ws_size,
                              hipStream_t stream) {
    const float* x      = (const float*)d_in[0];
    const float* qkv_w  = (const float*)d_in[1];
    const float* proj_w = (const float*)d_in[2];
    const float* proj_b = (const float*)d_in[3];
    const float* off_w2 = (const float*)d_in[4];
    const float* off_b2 = (const float*)d_in[5];
    const float* def_w2 = (const float*)d_in[6];
    const float* def_b2 = (const float*)d_in[7];
    const float* off_w3 = (const float*)d_in[8];
    const float* off_b3 = (const float*)d_in[9];
    const float* def_w3 = (const float*)d_in[10];
    const float* def_b3 = (const float*)d_in[11];
    float* out = (float*)d_out;

    float* ws    = (float*)d_ws;
    float* offb2 = ws;                              // 18 * M
    float* offb3 = offb2 + (size_t)18 * kM;         // 18 * M
    ushort_t* us = (ushort_t*)(offb3 + (size_t)18 * kM);
    ushort_t* xb     = us;  us += (size_t)kM * kC;
    ushort_t* qkvpx  = us;  us += (size_t)9 * kM * 64;
    ushort_t* kd2    = us;  us += (size_t)kM * 64;
    ushort_t* vd2    = us;  us += (size_t)kM * 64;
    ushort_t* kd3    = us;  us += (size_t)kM * 64;
    ushort_t* vd3    = us;  us += (size_t)kM * 64;
    ushort_t* aopx   = us;  us += (size_t)kM * kC;
    ushort_t* awb    = us;  us += (size_t)kNQKV * kC;   // 36*6*64*8 == 576*192
    ushort_t* pwbp   = us;  us += (size_t)kC * kC;      // 12*6*64*8 == 192*192
    ushort_t* dwtb2  = us;  us += kD * kD * 9;
    ushort_t* dwtb3  = us;  us += kD * kD * 9;
    ushort_t* owtb2  = us;  us += 9 * 32 * 64;
    ushort_t* owtb3  = us;  us += 9 * 32 * 64;

    // 0. x conversion + all weight packs (one dispatch)
    cvt_prep<<<12792, 256, 0, stream>>>(x, (unsigned*)xb, qkv_w, proj_w,
                                        def_w2, def_w3, off_w2, off_w3,
                                        awb, pwbp, dwtb2, dwtb3, owtb2, owtb3);

    // per-tensor pixel-major slices
    ushort_t* q0 = qkvpx;
    ushort_t* q1 = qkvpx + (size_t)1 * kM * 64;
    ushort_t* q2 = qkvpx + (size_t)2 * kM * 64;
    ushort_t* k0 = qkvpx + (size_t)3 * kM * 64;
    ushort_t* k1 = qkvpx + (size_t)4 * kM * 64;
    ushort_t* k2 = qkvpx + (size_t)5 * kM * 64;
    ushort_t* v0 = qkvpx + (size_t)6 * kM * 64;
    ushort_t* v1 = qkvpx + (size_t)7 * kM * 64;
    ushort_t* v2 = qkvpx + (size_t)8 * kM * 64;

    // 1. QKV projection -> 9 bf16 pixel-major tensors (LDS-staged GEMM)
    qkv_mfma3<<<dim3(kM / 64, 3), 256, 0, stream>>>(xb, awb, qkvpx);

    // 2. offsets conv, both branches, LDS-staged (one dispatch)
    off_conv_fused<<<1024, 256, 0, stream>>>(k1, k2, owtb2, owtb3,
                                             off_b2, off_b3, offb2, offb3);

    // 3. deformable conv, both branches, 16-wave blocks (one dispatch)
    deform_big<<<512, 1024, 0, stream>>>(k1, v1, k2, v2, offb2, offb3,
                                         dwtb2, dwtb3, def_b2, def_b3,
                                         kd2, vd2, kd3, vd3);

    // 4. attention, all three branches, two-phase k/v staging (one dispatch)
    attn_fused<<<768, 512, 0, stream>>>(q0, k0, v0, q1, kd2, vd2, q2, kd3, vd3, aopx);

    // 5. output projection (LDS-staged bf16 MFMA, fp32 out)
    proj_mfma3<<<512, 256, 0, stream>>>(aopx, pwbp, proj_b, out);
}

// Round 13
// 202.179 us; speedup vs baseline: 1.6511x; 1.0118x over previous
//
#include <hip/hip_runtime.h>
#include <cmath>

// ---------------------------------------------------------------------------
// Problem constants (B=8, H=W=64, C=192, 3 dilation branches of d=64, heads=64)
// ---------------------------------------------------------------------------
#define kB    8
#define kH    64
#define kW    64
#define kHW   4096          // H*W
#define kC    192
#define kD    64            // channels per dilation branch == head_dim
#define kM    (kB * kHW)    // 32768 total pixels
#define kNQKV 576           // 3*C

typedef unsigned short ushort_t;
typedef __attribute__((ext_vector_type(8))) short  s8v;   // 8 bf16 (4 VGPRs)
typedef __attribute__((ext_vector_type(4))) float  f4v;   // MFMA C/D frag
typedef __attribute__((ext_vector_type(2))) float  f2v;   // packed f32 pair

__device__ inline unsigned short bf16r(float f) {   // round-to-nearest-even
    union { float f; unsigned u; } v; v.f = f;
    unsigned u = v.u + 0x7FFFu + ((v.u >> 16) & 1u);
    return (unsigned short)(u >> 16);
}
__device__ inline float bfu(short s) {              // bf16 -> fp32
    union { unsigned u; float f; } v;
    v.u = ((unsigned)(unsigned short)s) << 16;
    return v.f;
}
__device__ inline f2v bfu2(unsigned u) {            // 2 packed bf16 -> f2v
    union { unsigned u; float f; } lo, hi;
    lo.u = u << 16;
    hi.u = u & 0xFFFF0000u;
    return (f2v){lo.f, hi.f};
}
__device__ inline unsigned pk2(f2v a) {             // f2v -> 2 packed bf16 (RTNE)
    union { float f; unsigned u; } x, y;
    x.f = a.x; y.f = a.y;
    unsigned ua = x.u + 0x7FFFu + ((x.u >> 16) & 1u);
    unsigned ub = y.u + 0x7FFFu + ((y.u >> 16) & 1u);
    return (ua >> 16) | (ub & 0xFFFF0000u);
}

// ---------------------------------------------------------------------------
// prep_all (round-21): weight packs only — x conversion is now fused into
// qkv_mfma4's staging. 504 blocks (round-16 verified logic).
// ---------------------------------------------------------------------------
__global__ void prep_all(const float* __restrict__ qkv_w,
                         const float* __restrict__ proj_w,
                         const float* __restrict__ def_w2,
                         const float* __restrict__ def_w3,
                         const float* __restrict__ off_w2,
                         const float* __restrict__ off_w3,
                         ushort_t* __restrict__ awb,
                         ushort_t* __restrict__ pwbp,
                         ushort_t* __restrict__ dwtb2,
                         ushort_t* __restrict__ dwtb3,
                         ushort_t* __restrict__ owtb2,
                         ushort_t* __restrict__ owtb3) {
    const int bid = blockIdx.x;
    const int tid = threadIdx.x;
    if (bid < 54) {                       // qw_pack
        int idx = bid * 256 + tid;        // 36*6*64 = 13824
        if (idx >= 36 * 6 * 64) return;
        int lane = idx & 63;
        int kc   = (idx >> 6) % 6;
        int s    = idx / 384;
        int row  = s * 16 + (lane & 15);
        int k0   = kc * 32 + (lane >> 4) * 8;
        const float* src = qkv_w + (size_t)row * kC + k0;
        ushort_t* dst = awb + (size_t)idx * 8;
#pragma unroll
        for (int j = 0; j < 8; ++j) dst[j] = bf16r(src[j]);
    } else if (bid < 72) {                // pw_pack
        int idx = (bid - 54) * 256 + tid; // 12*6*64 = 4608
        if (idx >= 12 * 6 * 64) return;
        int lane = idx & 63;
        int kc   = (idx >> 6) % 6;
        int s    = idx / 384;
        int row  = s * 16 + (lane & 15);
        int k0   = kc * 32 + (lane >> 4) * 8;
        const float* src = proj_w + (size_t)row * kC + k0;
        ushort_t* dst = pwbp + (size_t)idx * 8;
#pragma unroll
        for (int j = 0; j < 8; ++j) dst[j] = bf16r(src[j]);
    } else if (bid < 360) {               // dw_tb x2
        const float* dw = (bid < 216) ? def_w2 : def_w3;
        ushort_t* dwtb  = (bid < 216) ? dwtb2 : dwtb3;
        int l = ((bid < 216) ? (bid - 72) : (bid - 216)) * 256 + tid;  // 36864
        if (l >= kD * kD * 9) return;
        int o = l / 576;
        int c = (l / 9) % 64;
        int kk = l % 9;
        dwtb[(kk * 64 + o) * 64 + c] = bf16r(dw[l]);
    } else {                              // ow_tb x2
        const float* ow = (bid < 432) ? off_w2 : off_w3;
        ushort_t* owtb  = (bid < 432) ? owtb2 : owtb3;
        int l = ((bid < 432) ? (bid - 360) : (bid - 432)) * 256 + tid; // 18432
        if (l >= 9 * 32 * 64) return;
        int kk = l >> 11;
        int j  = (l >> 6) & 31;
        int c  = l & 63;
        owtb[l] = (j < 18) ? bf16r(ow[j * 576 + c * 9 + kk]) : (ushort_t)0;
    }
}

// ---------------------------------------------------------------------------
// Kernel 1 (round-21, resubmitted after GPU-acquisition timeout):
// QKV projection GEMM with FUSED f32->bf16 staging. Reads x directly in
// f32 (2x float4/thread), converts during the LDS stage — eliminates the
// 12288-block cvt dispatch and the xb buffer. GEMM body identical to the
// verified round-11 form.
// ---------------------------------------------------------------------------
__global__ __launch_bounds__(256) void qkv_mfma4(const float* __restrict__ xf,
                                                 const ushort_t* __restrict__ awb,
                                                 ushort_t* __restrict__ qkvpx) {
    __shared__ ushort_t xs[64 * kC];            // 24576 B, swizzled rows of 384 B

    const int tid = threadIdx.x;
    const int bx  = blockIdx.x;
    const int lb  = (bx & 7) * 64 + (bx >> 3);  // XCD swizzle (G=512)
    const int m0  = lb * 64;
    const int ty3 = blockIdx.y;                 // tensor triple: channels [ty3*192, +192)

#pragma unroll
    for (int i = 0; i < 6; ++i) {
        int il = i * 256 + tid;                 // 16B chunk id, 0..1535
        int p  = il / 24;                       // pixel row in strip
        int cc = il % 24;                       // 16B chunk within row
        const float* src = xf + (size_t)(m0 + p) * kC + cc * 8;
        float4 f0 = *(const float4*)(src);
        float4 f1 = *(const float4*)(src + 4);
        uint4 v;
        v.x = (unsigned)bf16r(f0.x) | ((unsigned)bf16r(f0.y) << 16);
        v.y = (unsigned)bf16r(f0.z) | ((unsigned)bf16r(f0.w) << 16);
        v.z = (unsigned)bf16r(f1.x) | ((unsigned)bf16r(f1.y) << 16);
        v.w = (unsigned)bf16r(f1.z) | ((unsigned)bf16r(f1.w) << 16);
        int dst = p * 384 + ((cc * 16) ^ ((p & 7) << 4));
        *(uint4*)((char*)xs + dst) = v;
    }
    __syncthreads();

    const int lane = tid & 63;
    const int wave = tid >> 6;
    const int l15  = lane & 15;
    const int q    = lane >> 4;
    const int sbase = ty3 * 12 + wave * 3;      // first of 3 N-strips for this wave

    f4v acc[3][4];
#pragma unroll
    for (int i = 0; i < 3; ++i)
#pragma unroll
        for (int m = 0; m < 4; ++m) acc[i][m] = (f4v){0.f, 0.f, 0.f, 0.f};

    const ushort_t* ap = awb + ((size_t)sbase * 6 * 64 + lane) * 8;

#pragma unroll
    for (int kc = 0; kc < 6; ++kc) {
        s8v bfr[4];
#pragma unroll
        for (int m = 0; m < 4; ++m) {
            int row = m * 16 + l15;
            int col = (kc * 64 + q * 16) ^ ((l15 & 7) << 4);
            bfr[m] = *(const s8v*)((const char*)xs + row * 384 + col);
        }
#pragma unroll
        for (int i = 0; i < 3; ++i) {
            s8v a = *(const s8v*)(ap + (size_t)(i * 6 + kc) * 64 * 8);
#pragma unroll
            for (int m = 0; m < 4; ++m)
                acc[i][m] = __builtin_amdgcn_mfma_f32_16x16x32_bf16(a, bfr[m], acc[i][m], 0, 0, 0);
        }
    }

#pragma unroll
    for (int i = 0; i < 3; ++i) {
        int s   = sbase + i;
        int ty  = s >> 2;                       // tensor 0..8
        int c64 = (s & 3) * 16 + q * 4;         // channel within tensor
        ushort_t* obase = qkvpx + (size_t)ty * kM * 64 + (size_t)m0 * 64 + c64;
#pragma unroll
        for (int m = 0; m < 4; ++m) {
            f4v v = acc[i][m];
            uint2 u;
            u.x = (unsigned)bf16r(v.x) | ((unsigned)bf16r(v.y) << 16);
            u.y = (unsigned)bf16r(v.z) | ((unsigned)bf16r(v.w) << 16);
            *(uint2*)(obase + (size_t)(m * 16 + l15) * 64) = u;
        }
    }
}

// ---------------------------------------------------------------------------
// Kernel 2 (round-20, verified): offsets conv, LDS-staged k window. UNCHANGED.
// ---------------------------------------------------------------------------
__global__ __launch_bounds__(256) void off_conv_fused(const ushort_t* __restrict__ k1,
                                                      const ushort_t* __restrict__ k2,
                                                      const ushort_t* __restrict__ owtb2,
                                                      const ushort_t* __restrict__ owtb3,
                                                      const float* __restrict__ ob2,
                                                      const float* __restrict__ ob3,
                                                      float* __restrict__ offb2,
                                                      float* __restrict__ offb3) {
    __shared__ ushort_t ks[7 * 4096];           // up to 7 rows x 8192 B, swizzled

    const int bx = blockIdx.x;
    const int lb = (bx & 7) * 128 + (bx >> 3);  // XCD swizzle (G=1024)
    const int zb = lb >> 9;                     // 0: dil2, 1: dil3
    const int rest = lb & 511;
    const int b = rest >> 6;
    const int y = rest & 63;
    const int dil = 2 + zb;
    const int nr  = 2 * dil + 1;
    const int wlo = y - dil;
    const ushort_t* kpx  = zb ? k2 : k1;
    const ushort_t* owtb = zb ? owtb3 : owtb2;
    const float* obias   = zb ? ob3 : ob2;
    float* offb          = zb ? offb3 : offb2;

    const int tid  = threadIdx.x;
    const ushort_t* kb = kpx + (size_t)b * kHW * 64;

    for (int r = 0; r < nr; ++r) {
        int gy = min(max(wlo + r, 0), kH - 1);
#pragma unroll
        for (int h = 0; h < 2; ++h) {
            int chunk = h * 256 + tid;
            int xcol = chunk >> 3, cc = chunk & 7;
            int dstc = (xcol * 128 + cc * 16) ^ ((xcol & 7) << 4);
            *(uint4*)((char*)ks + r * 8192 + dstc) =
                *(const uint4*)(kb + (size_t)gy * 4096 + chunk * 8);
        }
    }
    __syncthreads();

    const int lane = tid & 63;
    const int wave = tid >> 6;
    const int l15  = lane & 15;
    const int q    = lane >> 4;
    const int px   = wave * 16 + l15;

    f4v acc[2];
    acc[0] = (f4v){0.f, 0.f, 0.f, 0.f};
    acc[1] = (f4v){0.f, 0.f, 0.f, 0.f};

#pragma unroll
    for (int kk = 0; kk < 9; ++kk) {
        const int yy = y + (kk / 3 - 1) * dil;
        const int xx = px + (kk % 3 - 1) * dil;
        const bool valid = (yy >= 0) & (yy < kH) & (xx >= 0) & (xx < kW);
        int r  = min(max(yy - wlo, 0), nr - 1);
        int xc = min(max(xx, 0), kW - 1);
        int sw = (xc & 7) << 4;
        s8v a0 = *(const s8v*)((const char*)ks + r * 8192 + ((xc * 128 + q * 16) ^ sw));
        s8v a1 = *(const s8v*)((const char*)ks + r * 8192 + ((xc * 128 + q * 16 + 64) ^ sw));
        if (!valid) {
            a0 = (s8v){0, 0, 0, 0, 0, 0, 0, 0};
            a1 = (s8v){0, 0, 0, 0, 0, 0, 0, 0};
        }
        const ushort_t* wb = owtb + (size_t)kk * 2048 + l15 * 64 + q * 8;
#pragma unroll
        for (int nbk = 0; nbk < 2; ++nbk) {
            s8v b0 = *(const s8v*)(wb + nbk * 1024);
            s8v b1 = *(const s8v*)(wb + nbk * 1024 + 32);
            acc[nbk] = __builtin_amdgcn_mfma_f32_16x16x32_bf16(a0, b0, acc[nbk], 0, 0, 0);
            acc[nbk] = __builtin_amdgcn_mfma_f32_16x16x32_bf16(a1, b1, acc[nbk], 0, 0, 0);
        }
    }
#pragma unroll
    for (int nbk = 0; nbk < 2; ++nbk) {
        int n = nbk * 16 + l15;
        if (n < 18) {
            float bias = obias[n];
            f4v v = acc[nbk];
            v.x += bias; v.y += bias; v.z += bias; v.w += bias;
            *(f4v*)&offb[((size_t)b * 18 + n) * kHW + y * kW + wave * 16 + q * 4] = v;
        }
    }
}

// ---------------------------------------------------------------------------
// Kernel 3 (round-21): deformable conv, 16-wave blocks. Corner address
// generation reduced — col0/col1 computed once per tap, row terms added,
// +64B halves derived by ^64 (valid: bit6 of x*128+q*16 is 0 for q<4;
// write side (a+64)^s == (a^s)^64 since no carry and XOR bits disjoint
// from the +64 carry chain).
// ---------------------------------------------------------------------------
__global__ __launch_bounds__(1024) void deform_big(const ushort_t* __restrict__ k1,
                                                   const ushort_t* __restrict__ v1,
                                                   const ushort_t* __restrict__ k2,
                                                   const ushort_t* __restrict__ v2,
                                                   const float* __restrict__ offb2,
                                                   const float* __restrict__ offb3,
                                                   const ushort_t* __restrict__ dwtb2,
                                                   const ushort_t* __restrict__ dwtb3,
                                                   const float* __restrict__ db2,
                                                   const float* __restrict__ db3,
                                                   ushort_t* __restrict__ kd2,
                                                   ushort_t* __restrict__ vd2,
                                                   ushort_t* __restrict__ kd3,
                                                   ushort_t* __restrict__ vd3) {
    __shared__ ushort_t kv[12 * 4096];      // up to 12 rows x 8192 B, swizzled (96KB)
    __shared__ ushort_t wlds[5 * 4096];     // 40KB: 5 kk tiles, two-phase

    const int tid = threadIdx.x;
    const int bx  = blockIdx.x;
    const int lb  = (bx & 7) * 64 + (bx >> 3);  // XCD swizzle (G=512)
    const int zb  = lb >> 8;                // 0: dil2, 1: dil3
    const int t   = (lb >> 7) & 1;          // 0 = k, 1 = v
    const int b   = (lb >> 4) & 7;
    const int y0  = (lb & 15) * 4;          // first of 4 output rows
    const int dil = 2 + zb;
    const int nr  = 2 * dil + 6;            // staged rows (|oy|<1, 4 rows)
    const int wlo = y0 - dil - 1;

    const ushort_t* kin = zb ? k2 : k1;
    const ushort_t* vin = zb ? v2 : v1;
    const float* offbS  = zb ? offb3 : offb2;
    const ushort_t* dwtb = zb ? dwtb3 : dwtb2;
    const float* db      = zb ? db3 : db2;
    ushort_t* outp = t ? (zb ? vd3 : vd2) : (zb ? kd3 : kd2);

    const ushort_t* inb = (t ? vin : kin) + (size_t)b * kHW * 64;

    // ---- stage nr kv rows: 1024 thr = 2 rows/pass, swizzled ----
    {
        int half  = tid >> 9;               // 0/1: row within pass
        int chunk = tid & 511;              // 16B chunk within row
        int xcol  = chunk >> 3;
        int cc    = chunk & 7;
        int dstc  = (xcol * 128 + cc * 16) ^ ((xcol & 7) << 4);
        for (int r0 = 0; r0 < nr; r0 += 2) {
            int r = r0 + half;
            if (r < nr) {
                int gy = min(max(wlo + r, 0), kH - 1);
                *(uint4*)((char*)kv + r * 8192 + dstc) =
                    *(const uint4*)(inb + (size_t)gy * 4096 + chunk * 8);
            }
        }
    }
    // ---- stage weights phase A: kk 0-4 (40960 B) ----
    for (int i = tid; i < 2560; i += 1024) {
        int g = i * 16;
        uint4 v = *(const uint4*)((const char*)dwtb + g);
        int row = (g >> 7) & 63;
        *(uint4*)((char*)wlds + (g ^ ((row & 7) << 4))) = v;
    }
    __syncthreads();

    const int lane = tid & 63;
    const int wave = tid >> 6;          // 0..15
    const int ry   = wave >> 2;         // output row within quad
    const int wc   = wave & 3;          // px column
    const int l15  = lane & 15;
    const int q    = lane >> 4;
    const int y    = y0 + ry;
    const int px   = wc * 16 + l15;
    const int wsw  = (l15 & 7) << 4;
    const int wcol0 = (q * 16) ^ wsw;

    const ushort_t* inpx = inb + q * 8; // global fallback base

    f4v acc[4];
#pragma unroll
    for (int ob = 0; ob < 4; ++ob) acc[ob] = (f4v){0.f, 0.f, 0.f, 0.f};

    const float* offrow = offbS + (size_t)b * 18 * kHW + y * kW + px;
    float offv[18];
#pragma unroll
    for (int i = 0; i < 18; ++i) offv[i] = offrow[(size_t)i * kHW];

    auto do_tap = [&](int kk, int kkbase) {
        float oy = offv[kk * 2 + 0];
        float ox = offv[kk * 2 + 1];
        float py  = (float)y  + (float)((kk / 3 - 1) * dil) + oy;
        float pxf = (float)px + (float)((kk % 3 - 1) * dil) + ox;
        float fy = floorf(py), fx = floorf(pxf);
        float wy = py - fy, wx = pxf - fx;
        int iy0 = (int)fy, ix0 = (int)fx;
        int iy1 = iy0 + 1, ix1 = ix0 + 1;
        int y0c = min(max(iy0, 0), kH - 1), x0c = min(max(ix0, 0), kW - 1);
        int y1c = min(max(iy1, 0), kH - 1), x1c = min(max(ix1, 0), kW - 1);
        bool vy0 = (iy0 >= 0) & (iy0 < kH), vx0 = (ix0 >= 0) & (ix0 < kW);
        bool vy1 = (iy1 >= 0) & (iy1 < kH), vx1 = (ix1 >= 0) & (ix1 < kW);
        float w0 = (vy0 && vx0) ? (1.f - wy) * (1.f - wx) : 0.f;
        float w1 = (vy0 && vx1) ? (1.f - wy) * wx : 0.f;
        float w2 = (vy1 && vx0) ? wy * (1.f - wx) : 0.f;
        float w3 = (vy1 && vx1) ? wy * wx : 0.f;

        s8v c[8];
        if (__builtin_expect(fabsf(oy) < 1.0f, 1)) {
            int r0 = min(max(y0c - wlo, 0), nr - 1) * 8192;
            int r1 = min(max(y1c - wlo, 0), nr - 1) * 8192;
            // column parts computed once; +64B half is a pure ^64
            int col0 = (x0c * 128 + q * 16) ^ ((x0c & 7) << 4);
            int col1 = (x1c * 128 + q * 16) ^ ((x1c & 7) << 4);
            int b00 = r0 + col0;
            int b01 = r0 + col1;
            int b10 = r1 + col0;
            int b11 = r1 + col1;
            c[0] = *(const s8v*)((const char*)kv + b00);
            c[1] = *(const s8v*)((const char*)kv + (b00 ^ 64));
            c[2] = *(const s8v*)((const char*)kv + b01);
            c[3] = *(const s8v*)((const char*)kv + (b01 ^ 64));
            c[4] = *(const s8v*)((const char*)kv + b10);
            c[5] = *(const s8v*)((const char*)kv + (b10 ^ 64));
            c[6] = *(const s8v*)((const char*)kv + b11);
            c[7] = *(const s8v*)((const char*)kv + (b11 ^ 64));
        } else {
            size_t i00 = (size_t)(y0c * kW + x0c) * 64;
            size_t i01 = (size_t)(y0c * kW + x1c) * 64;
            size_t i10 = (size_t)(y1c * kW + x0c) * 64;
            size_t i11 = (size_t)(y1c * kW + x1c) * 64;
            c[0] = *(const s8v*)(inpx + i00);
            c[1] = *(const s8v*)(inpx + i00 + 32);
            c[2] = *(const s8v*)(inpx + i01);
            c[3] = *(const s8v*)(inpx + i01 + 32);
            c[4] = *(const s8v*)(inpx + i10);
            c[5] = *(const s8v*)(inpx + i10 + 32);
            c[6] = *(const s8v*)(inpx + i11);
            c[7] = *(const s8v*)(inpx + i11 + 32);
        }

        // bilinear in packed f32; same RTNE pack
        const f2v w0v = {w0, w0}, w1v = {w1, w1}, w2v = {w2, w2}, w3v = {w3, w3};
        s8v b0, b1;
#pragma unroll
        for (int jp = 0; jp < 4; ++jp) {
            f2v a0 = w0v * bfu2(((const unsigned*)&c[0])[jp])
                   + w1v * bfu2(((const unsigned*)&c[2])[jp])
                   + w2v * bfu2(((const unsigned*)&c[4])[jp])
                   + w3v * bfu2(((const unsigned*)&c[6])[jp]);
            f2v a1 = w0v * bfu2(((const unsigned*)&c[1])[jp])
                   + w1v * bfu2(((const unsigned*)&c[3])[jp])
                   + w2v * bfu2(((const unsigned*)&c[5])[jp])
                   + w3v * bfu2(((const unsigned*)&c[7])[jp]);
            ((unsigned*)&b0)[jp] = pk2(a0);
            ((unsigned*)&b1)[jp] = pk2(a1);
        }
        const char* wkk = (const char*)wlds + (kk - kkbase) * 8192 + l15 * 128;
#pragma unroll
        for (int obb = 0; obb < 4; ++obb) {
            s8v a0w = *(const s8v*)(wkk + (obb * 2048 + wcol0));
            s8v a1w = *(const s8v*)(wkk + ((obb * 2048 + wcol0) ^ 64));
            acc[obb] = __builtin_amdgcn_mfma_f32_16x16x32_bf16(a0w, b0, acc[obb], 0, 0, 0);
            acc[obb] = __builtin_amdgcn_mfma_f32_16x16x32_bf16(a1w, b1, acc[obb], 0, 0, 0);
        }
    };

    // ---- phase A: taps 0-4 ----
#pragma unroll
    for (int kk = 0; kk < 5; ++kk) do_tap(kk, 0);
    __syncthreads();
    // ---- restage weights: kk 5-8 (32768 B) ----
    for (int i = tid; i < 2048; i += 1024) {
        int g = i * 16;
        uint4 v = *(const uint4*)((const char*)dwtb + 40960 + g);
        int row = (g >> 7) & 63;
        *(uint4*)((char*)wlds + (g ^ ((row & 7) << 4))) = v;
    }
    __syncthreads();
    // ---- phase B: taps 5-8 ----
#pragma unroll
    for (int kk = 5; kk < 9; ++kk) do_tap(kk, 5);

    // store: lane holds o = obb*16 + q*4 + reg at pixel px -> bf16 pixel-major
    ushort_t* orow = outp + ((size_t)b * kHW + y * kW + px) * 64 + q * 4;
#pragma unroll
    for (int obb = 0; obb < 4; ++obb) {
        float4 bias = *(const float4*)&db[obb * 16 + q * 4];
        f4v v = acc[obb];
        uint2 u;
        u.x = (unsigned)bf16r(v.x + bias.x) | ((unsigned)bf16r(v.y + bias.y) << 16);
        u.y = (unsigned)bf16r(v.z + bias.z) | ((unsigned)bf16r(v.w + bias.w) << 16);
        *(uint2*)(orow + obb * 16) = u;
    }
}

// ---------------------------------------------------------------------------
// Kernel 4 (round-20, verified): attention, two-phase k->v staging. UNCHANGED.
// ---------------------------------------------------------------------------
__global__ __launch_bounds__(512) void attn_fused(const ushort_t* __restrict__ q0,
                                                  const ushort_t* __restrict__ k0,
                                                  const ushort_t* __restrict__ v0,
                                                  const ushort_t* __restrict__ q1,
                                                  const ushort_t* __restrict__ kd2,
                                                  const ushort_t* __restrict__ vd2,
                                                  const ushort_t* __restrict__ q2,
                                                  const ushort_t* __restrict__ kd3,
                                                  const ushort_t* __restrict__ vd3,
                                                  ushort_t* __restrict__ aopx) {
    __shared__ ushort_t kvs[8 * 4096];      // 64KB: k then v (two-phase)

    const int tid = threadIdx.x;
    const int bx  = blockIdx.x;
    const int lb  = (bx & 7) * 96 + (bx >> 3);  // XCD swizzle (G=768)
    const int zb  = lb >> 8;                // branch 0,1,2
    const int rest = lb & 255;
    const int b   = rest >> 5;
    const int y0  = (rest & 31) * 2;        // first of 2 output rows
    const int dil = zb + 1;
    const int nr  = 2 * dil + 2;            // staged rows
    const int wlo = y0 - dil;

    const ushort_t* qpx = (zb == 0) ? q0 : (zb == 1) ? q1 : q2;
    const ushort_t* kpx = (zb == 0) ? k0 : (zb == 1) ? kd2 : kd3;
    const ushort_t* vpx = (zb == 0) ? v0 : (zb == 1) ? vd2 : vd3;

    const size_t pbase = (size_t)b * kHW;
    const ushort_t* kb = kpx + pbase * 64;
    const ushort_t* vb = vpx + pbase * 64;

    const int stx  = tid >> 3;
    const int stcc = tid & 7;
    const int dstc = (stx * 128 + stcc * 16) ^ ((stx & 7) << 4);

    // ---- phase 1: stage k rows ----
    for (int r = 0; r < nr; ++r) {
        int gy = min(max(wlo + r, 0), kH - 1);
        *(uint4*)((char*)kvs + r * 8192 + dstc) = *(const uint4*)(kb + (size_t)gy * 4096 + tid * 8);
    }
    __syncthreads();

    const int wave = tid >> 6;          // 0..7
    const int l    = tid & 63;
    const int ry   = wave >> 2;         // row within pair
    const int wc   = wave & 3;          // 16-px column group
    const int pxq  = l >> 2;            // 16 pixels per wave
    const int cg   = l & 3;             // 4 channel-groups of 16 ch
    const int y  = y0 + ry;
    const int x_ = wc * 16 + pxq;
    const int p  = y * kW + x_;

    const ushort_t* qb = qpx + (pbase + p) * 64 + cg * 16;
    s8v qv0 = *(const s8v*)qb;
    s8v qv1 = *(const s8v*)(qb + 8);
    float qf[16];
#pragma unroll
    for (int j = 0; j < 8; ++j) { qf[j] = bfu(qv0[j]); qf[8 + j] = bfu(qv1[j]); }

    int a0s[9], a1s[9];
    float msk[9];
#pragma unroll
    for (int kk = 0; kk < 9; ++kk) {
        int dy = (kk / 3 - 1) * dil, dx = (kk % 3 - 1) * dil;
        int yy = y + dy, xx = x_ + dx;
        bool v = (yy >= 0) & (yy < kH) & (xx >= 0) & (xx < kW);
        msk[kk] = v ? 1.f : 0.f;
        int r  = min(max(yy - wlo, 0), nr - 1);
        int xc = min(max(xx, 0), kW - 1);
        int sw = (xc & 7) << 4;
        a0s[kk] = r * 8192 + ((xc * 128 + cg * 32) ^ sw);
        a1s[kk] = r * 8192 + ((xc * 128 + cg * 32 + 16) ^ sw);
    }

    float e[9];
#pragma unroll
    for (int kk = 0; kk < 9; ++kk) {
        s8v k0v = *(const s8v*)((const char*)kvs + a0s[kk]);
        s8v k1v = *(const s8v*)((const char*)kvs + a1s[kk]);
        float s = 0.f;
#pragma unroll
        for (int j = 0; j < 8; ++j) {
            s += qf[j] * bfu(k0v[j]);
            s += qf[8 + j] * bfu(k1v[j]);
        }
        s += __shfl_xor(s, 1);
        s += __shfl_xor(s, 2);
        e[kk] = s * 0.125f * msk[kk];
    }
    float mx = -1e30f;
#pragma unroll
    for (int kk = 0; kk < 9; ++kk) mx = fmaxf(mx, e[kk]);
    float ssum = 0.f;
#pragma unroll
    for (int kk = 0; kk < 9; ++kk) { e[kk] = __expf(e[kk] - mx); ssum += e[kk]; }
    float inv = 1.f / ssum;
#pragma unroll
    for (int kk = 0; kk < 9; ++kk) e[kk] = e[kk] * inv * msk[kk];

    __syncthreads();                     // all k reads done
    // ---- phase 2: restage with v rows ----
    for (int r = 0; r < nr; ++r) {
        int gy = min(max(wlo + r, 0), kH - 1);
        *(uint4*)((char*)kvs + r * 8192 + dstc) = *(const uint4*)(vb + (size_t)gy * 4096 + tid * 8);
    }
    __syncthreads();

    float acc[16];
#pragma unroll
    for (int j = 0; j < 16; ++j) acc[j] = 0.f;
#pragma unroll
    for (int kk = 0; kk < 9; ++kk) {
        s8v v0v = *(const s8v*)((const char*)kvs + a0s[kk]);
        s8v v1v = *(const s8v*)((const char*)kvs + a1s[kk]);
        float w = e[kk];
#pragma unroll
        for (int j = 0; j < 8; ++j) {
            acc[j] += w * bfu(v0v[j]);
            acc[8 + j] += w * bfu(v1v[j]);
        }
    }
    unsigned u[8];
#pragma unroll
    for (int i = 0; i < 8; ++i)
        u[i] = (unsigned)bf16r(acc[2 * i]) | ((unsigned)bf16r(acc[2 * i + 1]) << 16);
    ushort_t* ob = aopx + (pbase + p) * kC + zb * 64 + cg * 16;
    *(uint4*)ob = make_uint4(u[0], u[1], u[2], u[3]);
    *(uint4*)(ob + 8) = make_uint4(u[4], u[5], u[6], u[7]);
}

// ---------------------------------------------------------------------------
// Kernel 5 (verified): output projection, LDS-staged GEMM. UNCHANGED.
// ---------------------------------------------------------------------------
__global__ __launch_bounds__(256) void proj_mfma3(const ushort_t* __restrict__ aopx,
                                                  const ushort_t* __restrict__ pwbp,
                                                  const float* __restrict__ pb,
                                                  float* __restrict__ out) {
    __shared__ ushort_t xs[64 * kC];            // 24576 B, swizzled rows of 384 B

    const int tid = threadIdx.x;
    const int bx  = blockIdx.x;
    const int lb  = (bx & 7) * 64 + (bx >> 3);  // XCD swizzle (G=512)
    const int m0  = lb * 64;

#pragma unroll
    for (int i = 0; i < 6; ++i) {
        int il = i * 256 + tid;                 // 16B chunk id, 0..1535
        int p  = il / 24;                       // pixel row in strip
        int cc = il % 24;                       // 16B chunk within row
        uint4 v = *(const uint4*)(aopx + (size_t)(m0 + p) * kC + cc * 8);
        int dst = p * 384 + ((cc * 16) ^ ((p & 7) << 4));
        *(uint4*)((char*)xs + dst) = v;
    }
    __syncthreads();

    const int lane = tid & 63;
    const int wave = tid >> 6;
    const int l15  = lane & 15;
    const int q    = lane >> 4;
    const int sbase = wave * 3;                 // strips 0..11, 3 per wave

    f4v acc[3][4];
#pragma unroll
    for (int i = 0; i < 3; ++i)
#pragma unroll
        for (int m = 0; m < 4; ++m) acc[i][m] = (f4v){0.f, 0.f, 0.f, 0.f};

    const ushort_t* ap = pwbp + ((size_t)sbase * 6 * 64 + lane) * 8;

#pragma unroll
    for (int kc = 0; kc < 6; ++kc) {
        s8v bfr[4];
#pragma unroll
        for (int m = 0; m < 4; ++m) {
            int row = m * 16 + l15;
            int col = (kc * 64 + q * 16) ^ ((l15 & 7) << 4);
            bfr[m] = *(const s8v*)((const char*)xs + row * 384 + col);
        }
#pragma unroll
        for (int i = 0; i < 3; ++i) {
            s8v a = *(const s8v*)(ap + (size_t)(i * 6 + kc) * 64 * 8);
#pragma unroll
            for (int m = 0; m < 4; ++m)
                acc[i][m] = __builtin_amdgcn_mfma_f32_16x16x32_bf16(a, bfr[m], acc[i][m], 0, 0, 0);
        }
    }

#pragma unroll
    for (int i = 0; i < 3; ++i) {
        int s  = sbase + i;
        int n0 = s * 16 + q * 4;
        float4 bias = *(const float4*)&pb[n0];
#pragma unroll
        for (int m = 0; m < 4; ++m) {
            f4v v = acc[i][m];
            v.x += bias.x; v.y += bias.y; v.z += bias.z; v.w += bias.w;
            *(f4v*)&out[(size_t)(m0 + m * 16 + l15) * kC + n0] = v;
        }
    }
}

// ---------------------------------------------------------------------------
// Host launcher.  Workspace ~72 MB (xb eliminated).
// 6 dispatches: prep_all, qkv(fused cvt), off_fused, deform_big, attn_fused, proj.
// ---------------------------------------------------------------------------
extern "C" void kernel_launch(void* const* d_in, const int* in_sizes, int n_in,
                              void* d_out, int out_size, void* d_ws, size_t ws_size,
                              hipStream_t stream) {
    const float* x      = (const float*)d_in[0];
    const float* qkv_w  = (const float*)d_in[1];
    const float* proj_w = (const float*)d_in[2];
    const float* proj_b = (const float*)d_in[3];
    const float* off_w2 = (const float*)d_in[4];
    const float* off_b2 = (const float*)d_in[5];
    const float* def_w2 = (const float*)d_in[6];
    const float* def_b2 = (const float*)d_in[7];
    const float* off_w3 = (const float*)d_in[8];
    const float* off_b3 = (const float*)d_in[9];
    const float* def_w3 = (const float*)d_in[10];
    const float* def_b3 = (const float*)d_in[11];
    float* out = (float*)d_out;

    float* ws    = (float*)d_ws;
    float* offb2 = ws;                              // 18 * M
    float* offb3 = offb2 + (size_t)18 * kM;         // 18 * M
    ushort_t* us = (ushort_t*)(offb3 + (size_t)18 * kM);
    ushort_t* qkvpx  = us;  us += (size_t)9 * kM * 64;
    ushort_t* kd2    = us;  us += (size_t)kM * 64;
    ushort_t* vd2    = us;  us += (size_t)kM * 64;
    ushort_t* kd3    = us;  us += (size_t)kM * 64;
    ushort_t* vd3    = us;  us += (size_t)kM * 64;
    ushort_t* aopx   = us;  us += (size_t)kM * kC;
    ushort_t* awb    = us;  us += (size_t)kNQKV * kC;   // 36*6*64*8 == 576*192
    ushort_t* pwbp   = us;  us += (size_t)kC * kC;      // 12*6*64*8 == 192*192
    ushort_t* dwtb2  = us;  us += kD * kD * 9;
    ushort_t* dwtb3  = us;  us += kD * kD * 9;
    ushort_t* owtb2  = us;  us += 9 * 32 * 64;
    ushort_t* owtb3  = us;  us += 9 * 32 * 64;

    // 0. weight packs only (x conversion fused into qkv)
    prep_all<<<504, 256, 0, stream>>>(qkv_w, proj_w, def_w2, def_w3, off_w2, off_w3,
                                      awb, pwbp, dwtb2, dwtb3, owtb2, owtb3);

    // per-tensor pixel-major slices
    ushort_t* q0 = qkvpx;
    ushort_t* q1 = qkvpx + (size_t)1 * kM * 64;
    ushort_t* q2 = qkvpx + (size_t)2 * kM * 64;
    ushort_t* k0 = qkvpx + (size_t)3 * kM * 64;
    ushort_t* k1 = qkvpx + (size_t)4 * kM * 64;
    ushort_t* k2 = qkvpx + (size_t)5 * kM * 64;
    ushort_t* v0 = qkvpx + (size_t)6 * kM * 64;
    ushort_t* v1 = qkvpx + (size_t)7 * kM * 64;
    ushort_t* v2 = qkvpx + (size_t)8 * kM * 64;

    // 1. QKV projection with fused f32->bf16 staging
    qkv_mfma4<<<dim3(kM / 64, 3), 256, 0, stream>>>(x, awb, qkvpx);

    // 2. offsets conv, both branches, LDS-staged (one dispatch)
    off_conv_fused<<<1024, 256, 0, stream>>>(k1, k2, owtb2, owtb3,
                                             off_b2, off_b3, offb2, offb3);

    // 3. deformable conv, both branches, 16-wave blocks (one dispatch)
    deform_big<<<512, 1024, 0, stream>>>(k1, v1, k2, v2, offb2, offb3,
                                         dwtb2, dwtb3, def_b2, def_b3,
                                         kd2, vd2, kd3, vd3);

    // 4. attention, all three branches, two-phase k/v staging (one dispatch)
    attn_fused<<<768, 512, 0, stream>>>(q0, k0, v0, q1, kd2, vd2, q2, kd3, vd3, aopx);

    // 5. output projection (LDS-staged bf16 MFMA, fp32 out)
    proj_mfma3<<<512, 256, 0, stream>>>(aopx, pwbp, proj_b, out);
}

// Round 14
// 195.355 us; speedup vs baseline: 1.7088x; 1.0349x over previous
//
#include <hip/hip_runtime.h>
#include <cmath>

// ---------------------------------------------------------------------------
// Problem constants (B=8, H=W=64, C=192, 3 dilation branches of d=64, heads=64)
// ---------------------------------------------------------------------------
#define kB    8
#define kH    64
#define kW    64
#define kHW   4096          // H*W
#define kC    192
#define kD    64            // channels per dilation branch == head_dim
#define kM    (kB * kHW)    // 32768 total pixels
#define kNQKV 576           // 3*C

typedef unsigned short ushort_t;
typedef __attribute__((ext_vector_type(8))) short  s8v;   // 8 bf16 (4 VGPRs)
typedef __attribute__((ext_vector_type(4))) float  f4v;   // MFMA C/D frag
typedef __attribute__((ext_vector_type(2))) float  f2v;   // packed f32 pair

__device__ inline unsigned short bf16r(float f) {   // round-to-nearest-even
    union { float f; unsigned u; } v; v.f = f;
    unsigned u = v.u + 0x7FFFu + ((v.u >> 16) & 1u);
    return (unsigned short)(u >> 16);
}
__device__ inline float bfu(short s) {              // bf16 -> fp32
    union { unsigned u; float f; } v;
    v.u = ((unsigned)(unsigned short)s) << 16;
    return v.f;
}
__device__ inline f2v bfu2(unsigned u) {            // 2 packed bf16 -> f2v
    union { unsigned u; float f; } lo, hi;
    lo.u = u << 16;
    hi.u = u & 0xFFFF0000u;
    return (f2v){lo.f, hi.f};
}
// single-instruction RTNE pack: 2 f32 -> packed bf16 (gfx950 v_cvt_pk_bf16_f32;
// no builtin exists — inline asm, non-volatile so the scheduler may move it)
__device__ inline unsigned cvtpk(float lo, float hi) {
    unsigned r;
    asm("v_cvt_pk_bf16_f32 %0, %1, %2" : "=v"(r) : "v"(lo), "v"(hi));
    return r;
}

// ---------------------------------------------------------------------------
// prep_all: weight packs only (x conversion fused into qkv_mfma4). Verified.
// ---------------------------------------------------------------------------
__global__ void prep_all(const float* __restrict__ qkv_w,
                         const float* __restrict__ proj_w,
                         const float* __restrict__ def_w2,
                         const float* __restrict__ def_w3,
                         const float* __restrict__ off_w2,
                         const float* __restrict__ off_w3,
                         ushort_t* __restrict__ awb,
                         ushort_t* __restrict__ pwbp,
                         ushort_t* __restrict__ dwtb2,
                         ushort_t* __restrict__ dwtb3,
                         ushort_t* __restrict__ owtb2,
                         ushort_t* __restrict__ owtb3) {
    const int bid = blockIdx.x;
    const int tid = threadIdx.x;
    if (bid < 54) {                       // qw_pack
        int idx = bid * 256 + tid;        // 36*6*64 = 13824
        if (idx >= 36 * 6 * 64) return;
        int lane = idx & 63;
        int kc   = (idx >> 6) % 6;
        int s    = idx / 384;
        int row  = s * 16 + (lane & 15);
        int k0   = kc * 32 + (lane >> 4) * 8;
        const float* src = qkv_w + (size_t)row * kC + k0;
        ushort_t* dst = awb + (size_t)idx * 8;
#pragma unroll
        for (int j = 0; j < 8; ++j) dst[j] = bf16r(src[j]);
    } else if (bid < 72) {                // pw_pack
        int idx = (bid - 54) * 256 + tid; // 12*6*64 = 4608
        if (idx >= 12 * 6 * 64) return;
        int lane = idx & 63;
        int kc   = (idx >> 6) % 6;
        int s    = idx / 384;
        int row  = s * 16 + (lane & 15);
        int k0   = kc * 32 + (lane >> 4) * 8;
        const float* src = proj_w + (size_t)row * kC + k0;
        ushort_t* dst = pwbp + (size_t)idx * 8;
#pragma unroll
        for (int j = 0; j < 8; ++j) dst[j] = bf16r(src[j]);
    } else if (bid < 360) {               // dw_tb x2
        const float* dw = (bid < 216) ? def_w2 : def_w3;
        ushort_t* dwtb  = (bid < 216) ? dwtb2 : dwtb3;
        int l = ((bid < 216) ? (bid - 72) : (bid - 216)) * 256 + tid;  // 36864
        if (l >= kD * kD * 9) return;
        int o = l / 576;
        int c = (l / 9) % 64;
        int kk = l % 9;
        dwtb[(kk * 64 + o) * 64 + c] = bf16r(dw[l]);
    } else {                              // ow_tb x2
        const float* ow = (bid < 432) ? off_w2 : off_w3;
        ushort_t* owtb  = (bid < 432) ? owtb2 : owtb3;
        int l = ((bid < 432) ? (bid - 360) : (bid - 432)) * 256 + tid; // 18432
        if (l >= 9 * 32 * 64) return;
        int kk = l >> 11;
        int j  = (l >> 6) & 31;
        int c  = l & 63;
        owtb[l] = (j < 18) ? bf16r(ow[j * 576 + c * 9 + kk]) : (ushort_t)0;
    }
}

// ---------------------------------------------------------------------------
// Kernel 1: QKV projection GEMM, fused f32->bf16 staging (round-21 verified).
// Round-22: staging + epilogue packs use v_cvt_pk_bf16_f32 (1 inst/pair).
// ---------------------------------------------------------------------------
__global__ __launch_bounds__(256) void qkv_mfma4(const float* __restrict__ xf,
                                                 const ushort_t* __restrict__ awb,
                                                 ushort_t* __restrict__ qkvpx) {
    __shared__ ushort_t xs[64 * kC];            // 24576 B, swizzled rows of 384 B

    const int tid = threadIdx.x;
    const int bx  = blockIdx.x;
    const int lb  = (bx & 7) * 64 + (bx >> 3);  // XCD swizzle (G=512)
    const int m0  = lb * 64;
    const int ty3 = blockIdx.y;                 // tensor triple: channels [ty3*192, +192)

#pragma unroll
    for (int i = 0; i < 6; ++i) {
        int il = i * 256 + tid;                 // 16B chunk id, 0..1535
        int p  = il / 24;                       // pixel row in strip
        int cc = il % 24;                       // 16B chunk within row
        const float* src = xf + (size_t)(m0 + p) * kC + cc * 8;
        float4 f0 = *(const float4*)(src);
        float4 f1 = *(const float4*)(src + 4);
        uint4 v;
        v.x = cvtpk(f0.x, f0.y);
        v.y = cvtpk(f0.z, f0.w);
        v.z = cvtpk(f1.x, f1.y);
        v.w = cvtpk(f1.z, f1.w);
        int dst = p * 384 + ((cc * 16) ^ ((p & 7) << 4));
        *(uint4*)((char*)xs + dst) = v;
    }
    __syncthreads();

    const int lane = tid & 63;
    const int wave = tid >> 6;
    const int l15  = lane & 15;
    const int q    = lane >> 4;
    const int sbase = ty3 * 12 + wave * 3;      // first of 3 N-strips for this wave

    f4v acc[3][4];
#pragma unroll
    for (int i = 0; i < 3; ++i)
#pragma unroll
        for (int m = 0; m < 4; ++m) acc[i][m] = (f4v){0.f, 0.f, 0.f, 0.f};

    const ushort_t* ap = awb + ((size_t)sbase * 6 * 64 + lane) * 8;

#pragma unroll
    for (int kc = 0; kc < 6; ++kc) {
        s8v bfr[4];
#pragma unroll
        for (int m = 0; m < 4; ++m) {
            int row = m * 16 + l15;
            int col = (kc * 64 + q * 16) ^ ((l15 & 7) << 4);
            bfr[m] = *(const s8v*)((const char*)xs + row * 384 + col);
        }
#pragma unroll
        for (int i = 0; i < 3; ++i) {
            s8v a = *(const s8v*)(ap + (size_t)(i * 6 + kc) * 64 * 8);
#pragma unroll
            for (int m = 0; m < 4; ++m)
                acc[i][m] = __builtin_amdgcn_mfma_f32_16x16x32_bf16(a, bfr[m], acc[i][m], 0, 0, 0);
        }
    }

#pragma unroll
    for (int i = 0; i < 3; ++i) {
        int s   = sbase + i;
        int ty  = s >> 2;                       // tensor 0..8
        int c64 = (s & 3) * 16 + q * 4;         // channel within tensor
        ushort_t* obase = qkvpx + (size_t)ty * kM * 64 + (size_t)m0 * 64 + c64;
#pragma unroll
        for (int m = 0; m < 4; ++m) {
            f4v v = acc[i][m];
            uint2 u;
            u.x = cvtpk(v.x, v.y);
            u.y = cvtpk(v.z, v.w);
            *(uint2*)(obase + (size_t)(m * 16 + l15) * 64) = u;
        }
    }
}

// ---------------------------------------------------------------------------
// Kernel 2 (round-20, verified): offsets conv, LDS-staged k window. UNCHANGED.
// ---------------------------------------------------------------------------
__global__ __launch_bounds__(256) void off_conv_fused(const ushort_t* __restrict__ k1,
                                                      const ushort_t* __restrict__ k2,
                                                      const ushort_t* __restrict__ owtb2,
                                                      const ushort_t* __restrict__ owtb3,
                                                      const float* __restrict__ ob2,
                                                      const float* __restrict__ ob3,
                                                      float* __restrict__ offb2,
                                                      float* __restrict__ offb3) {
    __shared__ ushort_t ks[7 * 4096];           // up to 7 rows x 8192 B, swizzled

    const int bx = blockIdx.x;
    const int lb = (bx & 7) * 128 + (bx >> 3);  // XCD swizzle (G=1024)
    const int zb = lb >> 9;                     // 0: dil2, 1: dil3
    const int rest = lb & 511;
    const int b = rest >> 6;
    const int y = rest & 63;
    const int dil = 2 + zb;
    const int nr  = 2 * dil + 1;
    const int wlo = y - dil;
    const ushort_t* kpx  = zb ? k2 : k1;
    const ushort_t* owtb = zb ? owtb3 : owtb2;
    const float* obias   = zb ? ob3 : ob2;
    float* offb          = zb ? offb3 : offb2;

    const int tid  = threadIdx.x;
    const ushort_t* kb = kpx + (size_t)b * kHW * 64;

    for (int r = 0; r < nr; ++r) {
        int gy = min(max(wlo + r, 0), kH - 1);
#pragma unroll
        for (int h = 0; h < 2; ++h) {
            int chunk = h * 256 + tid;
            int xcol = chunk >> 3, cc = chunk & 7;
            int dstc = (xcol * 128 + cc * 16) ^ ((xcol & 7) << 4);
            *(uint4*)((char*)ks + r * 8192 + dstc) =
                *(const uint4*)(kb + (size_t)gy * 4096 + chunk * 8);
        }
    }
    __syncthreads();

    const int lane = tid & 63;
    const int wave = tid >> 6;
    const int l15  = lane & 15;
    const int q    = lane >> 4;
    const int px   = wave * 16 + l15;

    f4v acc[2];
    acc[0] = (f4v){0.f, 0.f, 0.f, 0.f};
    acc[1] = (f4v){0.f, 0.f, 0.f, 0.f};

#pragma unroll
    for (int kk = 0; kk < 9; ++kk) {
        const int yy = y + (kk / 3 - 1) * dil;
        const int xx = px + (kk % 3 - 1) * dil;
        const bool valid = (yy >= 0) & (yy < kH) & (xx >= 0) & (xx < kW);
        int r  = min(max(yy - wlo, 0), nr - 1);
        int xc = min(max(xx, 0), kW - 1);
        int sw = (xc & 7) << 4;
        s8v a0 = *(const s8v*)((const char*)ks + r * 8192 + ((xc * 128 + q * 16) ^ sw));
        s8v a1 = *(const s8v*)((const char*)ks + r * 8192 + ((xc * 128 + q * 16 + 64) ^ sw));
        if (!valid) {
            a0 = (s8v){0, 0, 0, 0, 0, 0, 0, 0};
            a1 = (s8v){0, 0, 0, 0, 0, 0, 0, 0};
        }
        const ushort_t* wb = owtb + (size_t)kk * 2048 + l15 * 64 + q * 8;
#pragma unroll
        for (int nbk = 0; nbk < 2; ++nbk) {
            s8v b0 = *(const s8v*)(wb + nbk * 1024);
            s8v b1 = *(const s8v*)(wb + nbk * 1024 + 32);
            acc[nbk] = __builtin_amdgcn_mfma_f32_16x16x32_bf16(a0, b0, acc[nbk], 0, 0, 0);
            acc[nbk] = __builtin_amdgcn_mfma_f32_16x16x32_bf16(a1, b1, acc[nbk], 0, 0, 0);
        }
    }
#pragma unroll
    for (int nbk = 0; nbk < 2; ++nbk) {
        int n = nbk * 16 + l15;
        if (n < 18) {
            float bias = obias[n];
            f4v v = acc[nbk];
            v.x += bias; v.y += bias; v.z += bias; v.w += bias;
            *(f4v*)&offb[((size_t)b * 18 + n) * kHW + y * kW + wave * 16 + q * 4] = v;
        }
    }
}

// ---------------------------------------------------------------------------
// Kernel 3 (round-22): deformable conv, 16-wave blocks. Bilinear pack and
// epilogue now use v_cvt_pk_bf16_f32 (1 inst vs ~6 for the manual RTNE) —
// 8 packs/tap x 9 taps was ~25% of tap VALU at VALUBusy 53%.
// ---------------------------------------------------------------------------
__global__ __launch_bounds__(1024) void deform_big(const ushort_t* __restrict__ k1,
                                                   const ushort_t* __restrict__ v1,
                                                   const ushort_t* __restrict__ k2,
                                                   const ushort_t* __restrict__ v2,
                                                   const float* __restrict__ offb2,
                                                   const float* __restrict__ offb3,
                                                   const ushort_t* __restrict__ dwtb2,
                                                   const ushort_t* __restrict__ dwtb3,
                                                   const float* __restrict__ db2,
                                                   const float* __restrict__ db3,
                                                   ushort_t* __restrict__ kd2,
                                                   ushort_t* __restrict__ vd2,
                                                   ushort_t* __restrict__ kd3,
                                                   ushort_t* __restrict__ vd3) {
    __shared__ ushort_t kv[12 * 4096];      // up to 12 rows x 8192 B, swizzled (96KB)
    __shared__ ushort_t wlds[5 * 4096];     // 40KB: 5 kk tiles, two-phase

    const int tid = threadIdx.x;
    const int bx  = blockIdx.x;
    const int lb  = (bx & 7) * 64 + (bx >> 3);  // XCD swizzle (G=512)
    const int zb  = lb >> 8;                // 0: dil2, 1: dil3
    const int t   = (lb >> 7) & 1;          // 0 = k, 1 = v
    const int b   = (lb >> 4) & 7;
    const int y0  = (lb & 15) * 4;          // first of 4 output rows
    const int dil = 2 + zb;
    const int nr  = 2 * dil + 6;            // staged rows (|oy|<1, 4 rows)
    const int wlo = y0 - dil - 1;

    const ushort_t* kin = zb ? k2 : k1;
    const ushort_t* vin = zb ? v2 : v1;
    const float* offbS  = zb ? offb3 : offb2;
    const ushort_t* dwtb = zb ? dwtb3 : dwtb2;
    const float* db      = zb ? db3 : db2;
    ushort_t* outp = t ? (zb ? vd3 : vd2) : (zb ? kd3 : kd2);

    const ushort_t* inb = (t ? vin : kin) + (size_t)b * kHW * 64;

    // ---- stage nr kv rows: 1024 thr = 2 rows/pass, swizzled ----
    {
        int half  = tid >> 9;               // 0/1: row within pass
        int chunk = tid & 511;              // 16B chunk within row
        int xcol  = chunk >> 3;
        int cc    = chunk & 7;
        int dstc  = (xcol * 128 + cc * 16) ^ ((xcol & 7) << 4);
        for (int r0 = 0; r0 < nr; r0 += 2) {
            int r = r0 + half;
            if (r < nr) {
                int gy = min(max(wlo + r, 0), kH - 1);
                *(uint4*)((char*)kv + r * 8192 + dstc) =
                    *(const uint4*)(inb + (size_t)gy * 4096 + chunk * 8);
            }
        }
    }
    // ---- stage weights phase A: kk 0-4 (40960 B) ----
    for (int i = tid; i < 2560; i += 1024) {
        int g = i * 16;
        uint4 v = *(const uint4*)((const char*)dwtb + g);
        int row = (g >> 7) & 63;
        *(uint4*)((char*)wlds + (g ^ ((row & 7) << 4))) = v;
    }
    __syncthreads();

    const int lane = tid & 63;
    const int wave = tid >> 6;          // 0..15
    const int ry   = wave >> 2;         // output row within quad
    const int wc   = wave & 3;          // px column
    const int l15  = lane & 15;
    const int q    = lane >> 4;
    const int y    = y0 + ry;
    const int px   = wc * 16 + l15;
    const int wsw  = (l15 & 7) << 4;
    const int wcol0 = (q * 16) ^ wsw;

    const ushort_t* inpx = inb + q * 8; // global fallback base

    f4v acc[4];
#pragma unroll
    for (int ob = 0; ob < 4; ++ob) acc[ob] = (f4v){0.f, 0.f, 0.f, 0.f};

    const float* offrow = offbS + (size_t)b * 18 * kHW + y * kW + px;
    float offv[18];
#pragma unroll
    for (int i = 0; i < 18; ++i) offv[i] = offrow[(size_t)i * kHW];

    auto do_tap = [&](int kk, int kkbase) {
        float oy = offv[kk * 2 + 0];
        float ox = offv[kk * 2 + 1];
        float py  = (float)y  + (float)((kk / 3 - 1) * dil) + oy;
        float pxf = (float)px + (float)((kk % 3 - 1) * dil) + ox;
        float fy = floorf(py), fx = floorf(pxf);
        float wy = py - fy, wx = pxf - fx;
        int iy0 = (int)fy, ix0 = (int)fx;
        int iy1 = iy0 + 1, ix1 = ix0 + 1;
        int y0c = min(max(iy0, 0), kH - 1), x0c = min(max(ix0, 0), kW - 1);
        int y1c = min(max(iy1, 0), kH - 1), x1c = min(max(ix1, 0), kW - 1);
        bool vy0 = (iy0 >= 0) & (iy0 < kH), vx0 = (ix0 >= 0) & (ix0 < kW);
        bool vy1 = (iy1 >= 0) & (iy1 < kH), vx1 = (ix1 >= 0) & (ix1 < kW);
        float w0 = (vy0 && vx0) ? (1.f - wy) * (1.f - wx) : 0.f;
        float w1 = (vy0 && vx1) ? (1.f - wy) * wx : 0.f;
        float w2 = (vy1 && vx0) ? wy * (1.f - wx) : 0.f;
        float w3 = (vy1 && vx1) ? wy * wx : 0.f;

        s8v c[8];
        if (__builtin_expect(fabsf(oy) < 1.0f, 1)) {
            int r0 = min(max(y0c - wlo, 0), nr - 1) * 8192;
            int r1 = min(max(y1c - wlo, 0), nr - 1) * 8192;
            int col0 = (x0c * 128 + q * 16) ^ ((x0c & 7) << 4);
            int col1 = (x1c * 128 + q * 16) ^ ((x1c & 7) << 4);
            int b00 = r0 + col0;
            int b01 = r0 + col1;
            int b10 = r1 + col0;
            int b11 = r1 + col1;
            c[0] = *(const s8v*)((const char*)kv + b00);
            c[1] = *(const s8v*)((const char*)kv + (b00 ^ 64));
            c[2] = *(const s8v*)((const char*)kv + b01);
            c[3] = *(const s8v*)((const char*)kv + (b01 ^ 64));
            c[4] = *(const s8v*)((const char*)kv + b10);
            c[5] = *(const s8v*)((const char*)kv + (b10 ^ 64));
            c[6] = *(const s8v*)((const char*)kv + b11);
            c[7] = *(const s8v*)((const char*)kv + (b11 ^ 64));
        } else {
            size_t i00 = (size_t)(y0c * kW + x0c) * 64;
            size_t i01 = (size_t)(y0c * kW + x1c) * 64;
            size_t i10 = (size_t)(y1c * kW + x0c) * 64;
            size_t i11 = (size_t)(y1c * kW + x1c) * 64;
            c[0] = *(const s8v*)(inpx + i00);
            c[1] = *(const s8v*)(inpx + i00 + 32);
            c[2] = *(const s8v*)(inpx + i01);
            c[3] = *(const s8v*)(inpx + i01 + 32);
            c[4] = *(const s8v*)(inpx + i10);
            c[5] = *(const s8v*)(inpx + i10 + 32);
            c[6] = *(const s8v*)(inpx + i11);
            c[7] = *(const s8v*)(inpx + i11 + 32);
        }

        // bilinear in packed f32; pack via v_cvt_pk_bf16_f32
        const f2v w0v = {w0, w0}, w1v = {w1, w1}, w2v = {w2, w2}, w3v = {w3, w3};
        s8v b0, b1;
#pragma unroll
        for (int jp = 0; jp < 4; ++jp) {
            f2v a0 = w0v * bfu2(((const unsigned*)&c[0])[jp])
                   + w1v * bfu2(((const unsigned*)&c[2])[jp])
                   + w2v * bfu2(((const unsigned*)&c[4])[jp])
                   + w3v * bfu2(((const unsigned*)&c[6])[jp]);
            f2v a1 = w0v * bfu2(((const unsigned*)&c[1])[jp])
                   + w1v * bfu2(((const unsigned*)&c[3])[jp])
                   + w2v * bfu2(((const unsigned*)&c[5])[jp])
                   + w3v * bfu2(((const unsigned*)&c[7])[jp]);
            ((unsigned*)&b0)[jp] = cvtpk(a0.x, a0.y);
            ((unsigned*)&b1)[jp] = cvtpk(a1.x, a1.y);
        }
        const char* wkk = (const char*)wlds + (kk - kkbase) * 8192 + l15 * 128;
#pragma unroll
        for (int obb = 0; obb < 4; ++obb) {
            s8v a0w = *(const s8v*)(wkk + (obb * 2048 + wcol0));
            s8v a1w = *(const s8v*)(wkk + ((obb * 2048 + wcol0) ^ 64));
            acc[obb] = __builtin_amdgcn_mfma_f32_16x16x32_bf16(a0w, b0, acc[obb], 0, 0, 0);
            acc[obb] = __builtin_amdgcn_mfma_f32_16x16x32_bf16(a1w, b1, acc[obb], 0, 0, 0);
        }
    };

    // ---- phase A: taps 0-4 ----
#pragma unroll
    for (int kk = 0; kk < 5; ++kk) do_tap(kk, 0);
    __syncthreads();
    // ---- restage weights: kk 5-8 (32768 B) ----
    for (int i = tid; i < 2048; i += 1024) {
        int g = i * 16;
        uint4 v = *(const uint4*)((const char*)dwtb + 40960 + g);
        int row = (g >> 7) & 63;
        *(uint4*)((char*)wlds + (g ^ ((row & 7) << 4))) = v;
    }
    __syncthreads();
    // ---- phase B: taps 5-8 ----
#pragma unroll
    for (int kk = 5; kk < 9; ++kk) do_tap(kk, 5);

    // store: lane holds o = obb*16 + q*4 + reg at pixel px -> bf16 pixel-major
    ushort_t* orow = outp + ((size_t)b * kHW + y * kW + px) * 64 + q * 4;
#pragma unroll
    for (int obb = 0; obb < 4; ++obb) {
        float4 bias = *(const float4*)&db[obb * 16 + q * 4];
        f4v v = acc[obb];
        uint2 u;
        u.x = cvtpk(v.x + bias.x, v.y + bias.y);
        u.y = cvtpk(v.z + bias.z, v.w + bias.w);
        *(uint2*)(orow + obb * 16) = u;
    }
}

// ---------------------------------------------------------------------------
// Kernel 4 (round-20, verified): attention, two-phase k->v staging.
// Round-22: output pack via v_cvt_pk_bf16_f32.
// ---------------------------------------------------------------------------
__global__ __launch_bounds__(512) void attn_fused(const ushort_t* __restrict__ q0,
                                                  const ushort_t* __restrict__ k0,
                                                  const ushort_t* __restrict__ v0,
                                                  const ushort_t* __restrict__ q1,
                                                  const ushort_t* __restrict__ kd2,
                                                  const ushort_t* __restrict__ vd2,
                                                  const ushort_t* __restrict__ q2,
                                                  const ushort_t* __restrict__ kd3,
                                                  const ushort_t* __restrict__ vd3,
                                                  ushort_t* __restrict__ aopx) {
    __shared__ ushort_t kvs[8 * 4096];      // 64KB: k then v (two-phase)

    const int tid = threadIdx.x;
    const int bx  = blockIdx.x;
    const int lb  = (bx & 7) * 96 + (bx >> 3);  // XCD swizzle (G=768)
    const int zb  = lb >> 8;                // branch 0,1,2
    const int rest = lb & 255;
    const int b   = rest >> 5;
    const int y0  = (rest & 31) * 2;        // first of 2 output rows
    const int dil = zb + 1;
    const int nr  = 2 * dil + 2;            // staged rows
    const int wlo = y0 - dil;

    const ushort_t* qpx = (zb == 0) ? q0 : (zb == 1) ? q1 : q2;
    const ushort_t* kpx = (zb == 0) ? k0 : (zb == 1) ? kd2 : kd3;
    const ushort_t* vpx = (zb == 0) ? v0 : (zb == 1) ? vd2 : vd3;

    const size_t pbase = (size_t)b * kHW;
    const ushort_t* kb = kpx + pbase * 64;
    const ushort_t* vb = vpx + pbase * 64;

    const int stx  = tid >> 3;
    const int stcc = tid & 7;
    const int dstc = (stx * 128 + stcc * 16) ^ ((stx & 7) << 4);

    // ---- phase 1: stage k rows ----
    for (int r = 0; r < nr; ++r) {
        int gy = min(max(wlo + r, 0), kH - 1);
        *(uint4*)((char*)kvs + r * 8192 + dstc) = *(const uint4*)(kb + (size_t)gy * 4096 + tid * 8);
    }
    __syncthreads();

    const int wave = tid >> 6;          // 0..7
    const int l    = tid & 63;
    const int ry   = wave >> 2;         // row within pair
    const int wc   = wave & 3;          // 16-px column group
    const int pxq  = l >> 2;            // 16 pixels per wave
    const int cg   = l & 3;             // 4 channel-groups of 16 ch
    const int y  = y0 + ry;
    const int x_ = wc * 16 + pxq;
    const int p  = y * kW + x_;

    const ushort_t* qb = qpx + (pbase + p) * 64 + cg * 16;
    s8v qv0 = *(const s8v*)qb;
    s8v qv1 = *(const s8v*)(qb + 8);
    float qf[16];
#pragma unroll
    for (int j = 0; j < 8; ++j) { qf[j] = bfu(qv0[j]); qf[8 + j] = bfu(qv1[j]); }

    int a0s[9], a1s[9];
    float msk[9];
#pragma unroll
    for (int kk = 0; kk < 9; ++kk) {
        int dy = (kk / 3 - 1) * dil, dx = (kk % 3 - 1) * dil;
        int yy = y + dy, xx = x_ + dx;
        bool v = (yy >= 0) & (yy < kH) & (xx >= 0) & (xx < kW);
        msk[kk] = v ? 1.f : 0.f;
        int r  = min(max(yy - wlo, 0), nr - 1);
        int xc = min(max(xx, 0), kW - 1);
        int sw = (xc & 7) << 4;
        a0s[kk] = r * 8192 + ((xc * 128 + cg * 32) ^ sw);
        a1s[kk] = r * 8192 + ((xc * 128 + cg * 32 + 16) ^ sw);
    }

    float e[9];
#pragma unroll
    for (int kk = 0; kk < 9; ++kk) {
        s8v k0v = *(const s8v*)((const char*)kvs + a0s[kk]);
        s8v k1v = *(const s8v*)((const char*)kvs + a1s[kk]);
        float s = 0.f;
#pragma unroll
        for (int j = 0; j < 8; ++j) {
            s += qf[j] * bfu(k0v[j]);
            s += qf[8 + j] * bfu(k1v[j]);
        }
        s += __shfl_xor(s, 1);
        s += __shfl_xor(s, 2);
        e[kk] = s * 0.125f * msk[kk];
    }
    float mx = -1e30f;
#pragma unroll
    for (int kk = 0; kk < 9; ++kk) mx = fmaxf(mx, e[kk]);
    float ssum = 0.f;
#pragma unroll
    for (int kk = 0; kk < 9; ++kk) { e[kk] = __expf(e[kk] - mx); ssum += e[kk]; }
    float inv = 1.f / ssum;
#pragma unroll
    for (int kk = 0; kk < 9; ++kk) e[kk] = e[kk] * inv * msk[kk];

    __syncthreads();                     // all k reads done
    // ---- phase 2: restage with v rows ----
    for (int r = 0; r < nr; ++r) {
        int gy = min(max(wlo + r, 0), kH - 1);
        *(uint4*)((char*)kvs + r * 8192 + dstc) = *(const uint4*)(vb + (size_t)gy * 4096 + tid * 8);
    }
    __syncthreads();

    float acc[16];
#pragma unroll
    for (int j = 0; j < 16; ++j) acc[j] = 0.f;
#pragma unroll
    for (int kk = 0; kk < 9; ++kk) {
        s8v v0v = *(const s8v*)((const char*)kvs + a0s[kk]);
        s8v v1v = *(const s8v*)((const char*)kvs + a1s[kk]);
        float w = e[kk];
#pragma unroll
        for (int j = 0; j < 8; ++j) {
            acc[j] += w * bfu(v0v[j]);
            acc[8 + j] += w * bfu(v1v[j]);
        }
    }
    unsigned u[8];
#pragma unroll
    for (int i = 0; i < 8; ++i)
        u[i] = cvtpk(acc[2 * i], acc[2 * i + 1]);
    ushort_t* ob = aopx + (pbase + p) * kC + zb * 64 + cg * 16;
    *(uint4*)ob = make_uint4(u[0], u[1], u[2], u[3]);
    *(uint4*)(ob + 8) = make_uint4(u[4], u[5], u[6], u[7]);
}

// ---------------------------------------------------------------------------
// Kernel 5 (verified): output projection, LDS-staged GEMM. UNCHANGED.
// ---------------------------------------------------------------------------
__global__ __launch_bounds__(256) void proj_mfma3(const ushort_t* __restrict__ aopx,
                                                  const ushort_t* __restrict__ pwbp,
                                                  const float* __restrict__ pb,
                                                  float* __restrict__ out) {
    __shared__ ushort_t xs[64 * kC];            // 24576 B, swizzled rows of 384 B

    const int tid = threadIdx.x;
    const int bx  = blockIdx.x;
    const int lb  = (bx & 7) * 64 + (bx >> 3);  // XCD swizzle (G=512)
    const int m0  = lb * 64;

#pragma unroll
    for (int i = 0; i < 6; ++i) {
        int il = i * 256 + tid;                 // 16B chunk id, 0..1535
        int p  = il / 24;                       // pixel row in strip
        int cc = il % 24;                       // 16B chunk within row
        uint4 v = *(const uint4*)(aopx + (size_t)(m0 + p) * kC + cc * 8);
        int dst = p * 384 + ((cc * 16) ^ ((p & 7) << 4));
        *(uint4*)((char*)xs + dst) = v;
    }
    __syncthreads();

    const int lane = tid & 63;
    const int wave = tid >> 6;
    const int l15  = lane & 15;
    const int q    = lane >> 4;
    const int sbase = wave * 3;                 // strips 0..11, 3 per wave

    f4v acc[3][4];
#pragma unroll
    for (int i = 0; i < 3; ++i)
#pragma unroll
        for (int m = 0; m < 4; ++m) acc[i][m] = (f4v){0.f, 0.f, 0.f, 0.f};

    const ushort_t* ap = pwbp + ((size_t)sbase * 6 * 64 + lane) * 8;

#pragma unroll
    for (int kc = 0; kc < 6; ++kc) {
        s8v bfr[4];
#pragma unroll
        for (int m = 0; m < 4; ++m) {
            int row = m * 16 + l15;
            int col = (kc * 64 + q * 16) ^ ((l15 & 7) << 4);
            bfr[m] = *(const s8v*)((const char*)xs + row * 384 + col);
        }
#pragma unroll
        for (int i = 0; i < 3; ++i) {
            s8v a = *(const s8v*)(ap + (size_t)(i * 6 + kc) * 64 * 8);
#pragma unroll
            for (int m = 0; m < 4; ++m)
                acc[i][m] = __builtin_amdgcn_mfma_f32_16x16x32_bf16(a, bfr[m], acc[i][m], 0, 0, 0);
        }
    }

#pragma unroll
    for (int i = 0; i < 3; ++i) {
        int s  = sbase + i;
        int n0 = s * 16 + q * 4;
        float4 bias = *(const float4*)&pb[n0];
#pragma unroll
        for (int m = 0; m < 4; ++m) {
            f4v v = acc[i][m];
            v.x += bias.x; v.y += bias.y; v.z += bias.z; v.w += bias.w;
            *(f4v*)&out[(size_t)(m0 + m * 16 + l15) * kC + n0] = v;
        }
    }
}

// ---------------------------------------------------------------------------
// Host launcher.  Workspace ~72 MB.
// 6 dispatches: prep_all, qkv(fused cvt), off_fused, deform_big, attn_fused, proj.
// ---------------------------------------------------------------------------
extern "C" void kernel_launch(void* const* d_in, const int* in_sizes, int n_in,
                              void* d_out, int out_size, void* d_ws, size_t ws_size,
                              hipStream_t stream) {
    const float* x      = (const float*)d_in[0];
    const float* qkv_w  = (const float*)d_in[1];
    const float* proj_w = (const float*)d_in[2];
    const float* proj_b = (const float*)d_in[3];
    const float* off_w2 = (const float*)d_in[4];
    const float* off_b2 = (const float*)d_in[5];
    const float* def_w2 = (const float*)d_in[6];
    const float* def_b2 = (const float*)d_in[7];
    const float* off_w3 = (const float*)d_in[8];
    const float* off_b3 = (const float*)d_in[9];
    const float* def_w3 = (const float*)d_in[10];
    const float* def_b3 = (const float*)d_in[11];
    float* out = (float*)d_out;

    float* ws    = (float*)d_ws;
    float* offb2 = ws;                              // 18 * M
    float* offb3 = offb2 + (size_t)18 * kM;         // 18 * M
    ushort_t* us = (ushort_t*)(offb3 + (size_t)18 * kM);
    ushort_t* qkvpx  = us;  us += (size_t)9 * kM * 64;
    ushort_t* kd2    = us;  us += (size_t)kM * 64;
    ushort_t* vd2    = us;  us += (size_t)kM * 64;
    ushort_t* kd3    = us;  us += (size_t)kM * 64;
    ushort_t* vd3    = us;  us += (size_t)kM * 64;
    ushort_t* aopx   = us;  us += (size_t)kM * kC;
    ushort_t* awb    = us;  us += (size_t)kNQKV * kC;   // 36*6*64*8 == 576*192
    ushort_t* pwbp   = us;  us += (size_t)kC * kC;      // 12*6*64*8 == 192*192
    ushort_t* dwtb2  = us;  us += kD * kD * 9;
    ushort_t* dwtb3  = us;  us += kD * kD * 9;
    ushort_t* owtb2  = us;  us += 9 * 32 * 64;
    ushort_t* owtb3  = us;  us += 9 * 32 * 64;

    // 0. weight packs only (x conversion fused into qkv)
    prep_all<<<504, 256, 0, stream>>>(qkv_w, proj_w, def_w2, def_w3, off_w2, off_w3,
                                      awb, pwbp, dwtb2, dwtb3, owtb2, owtb3);

    // per-tensor pixel-major slices
    ushort_t* q0 = qkvpx;
    ushort_t* q1 = qkvpx + (size_t)1 * kM * 64;
    ushort_t* q2 = qkvpx + (size_t)2 * kM * 64;
    ushort_t* k0 = qkvpx + (size_t)3 * kM * 64;
    ushort_t* k1 = qkvpx + (size_t)4 * kM * 64;
    ushort_t* k2 = qkvpx + (size_t)5 * kM * 64;
    ushort_t* v0 = qkvpx + (size_t)6 * kM * 64;
    ushort_t* v1 = qkvpx + (size_t)7 * kM * 64;
    ushort_t* v2 = qkvpx + (size_t)8 * kM * 64;

    // 1. QKV projection with fused f32->bf16 staging
    qkv_mfma4<<<dim3(kM / 64, 3), 256, 0, stream>>>(x, awb, qkvpx);

    // 2. offsets conv, both branches, LDS-staged (one dispatch)
    off_conv_fused<<<1024, 256, 0, stream>>>(k1, k2, owtb2, owtb3,
                                             off_b2, off_b3, offb2, offb3);

    // 3. deformable conv, both branches, 16-wave blocks (one dispatch)
    deform_big<<<512, 1024, 0, stream>>>(k1, v1, k2, v2, offb2, offb3,
                                         dwtb2, dwtb3, def_b2, def_b3,
                                         kd2, vd2, kd3, vd3);

    // 4. attention, all three branches, two-phase k/v staging (one dispatch)
    attn_fused<<<768, 512, 0, stream>>>(q0, k0, v0, q1, kd2, vd2, q2, kd3, vd3, aopx);

    // 5. output projection (LDS-staged bf16 MFMA, fp32 out)
    proj_mfma3<<<512, 256, 0, stream>>>(aopx, pwbp, proj_b, out);
}